// Round 1
// baseline (1230.902 us; speedup 1.0000x reference)
//
#include <hip/hip_runtime.h>
#include <cfloat>
#include <cstdint>

// ---------------------------------------------------------------------------
// GATv2 x3 + global max/mean pool + linear head, all fp32.
// Round 0: correctness-first. GEMMs are classic 64x64-tile LDS SGEMM (no fp32
// MFMA on CDNA4). Edge softmax via CSR built per-call (stateless).
// ---------------------------------------------------------------------------

// C[m][n] = sum_k A[m][k] * W[n][k]   (A: MxK row-major, W: NoutxK row-major)
__global__ __launch_bounds__(256) void gemm_xwT(
    const float* __restrict__ A, const float* __restrict__ W,
    float* __restrict__ C, int M, int K, int Nout)
{
    __shared__ float As[16][65];
    __shared__ float Bs[16][65];
    const int t  = threadIdx.x;
    const int tx = t & 15, ty = t >> 4;
    const int m0 = blockIdx.x * 64, n0 = blockIdx.y * 64;
    const int lr = t >> 2;           // 0..63
    const int lk = (t & 3) << 2;     // 0,4,8,12
    float acc[4][4] = {};
    for (int k0 = 0; k0 < K; k0 += 16) {
        int gm = m0 + lr;
        float4 va = make_float4(0.f, 0.f, 0.f, 0.f);
        if (gm < M) va = *(const float4*)(A + (size_t)gm * K + k0 + lk);
        As[lk + 0][lr] = va.x; As[lk + 1][lr] = va.y;
        As[lk + 2][lr] = va.z; As[lk + 3][lr] = va.w;
        float4 vb = *(const float4*)(W + (size_t)(n0 + lr) * K + k0 + lk);
        Bs[lk + 0][lr] = vb.x; Bs[lk + 1][lr] = vb.y;
        Bs[lk + 2][lr] = vb.z; Bs[lk + 3][lr] = vb.w;
        __syncthreads();
        #pragma unroll
        for (int k = 0; k < 16; ++k) {
            float a[4], b[4];
            #pragma unroll
            for (int i = 0; i < 4; ++i) a[i] = As[k][ty * 4 + i];
            #pragma unroll
            for (int j = 0; j < 4; ++j) b[j] = Bs[k][tx * 4 + j];
            #pragma unroll
            for (int i = 0; i < 4; ++i)
                #pragma unroll
                for (int j = 0; j < 4; ++j)
                    acc[i][j] += a[i] * b[j];
        }
        __syncthreads();
    }
    #pragma unroll
    for (int i = 0; i < 4; ++i) {
        int gm = m0 + ty * 4 + i;
        if (gm < M) {
            float4 v = make_float4(acc[i][0], acc[i][1], acc[i][2], acc[i][3]);
            *(float4*)(C + (size_t)gm * Nout + n0 + tx * 4) = v;
        }
    }
}

// ---------------------------------------------------------------------------
// CSR build (grouped by dst). Edge id e < E: (src[e], dst[e]); e >= E: self loop.
// ---------------------------------------------------------------------------
__global__ void hist_k(const int* __restrict__ dst, int E, int N, int* __restrict__ deg)
{
    int e = blockIdx.x * blockDim.x + threadIdx.x;
    if (e >= E + N) return;
    int i = (e < E) ? dst[e] : (e - E);
    atomicAdd(&deg[i], 1);
}

__global__ __launch_bounds__(1024) void scan_k(const int* __restrict__ deg,
                                               int* __restrict__ rowptr, int N)
{
    __shared__ int tile[1024];
    __shared__ int carryS;
    int t = threadIdx.x;
    if (t == 0) { carryS = 0; rowptr[0] = 0; }
    __syncthreads();
    for (int base = 0; base < N; base += 8192) {
        int v[8];
        int run = 0;
        #pragma unroll
        for (int i = 0; i < 8; ++i) {
            int idx = base + t * 8 + i;
            run += (idx < N) ? deg[idx] : 0;
            v[i] = run;                       // thread-local inclusive scan
        }
        tile[t] = run;
        __syncthreads();
        for (int off = 1; off < 1024; off <<= 1) {
            int add = (t >= off) ? tile[t - off] : 0;
            __syncthreads();
            tile[t] += add;
            __syncthreads();
        }
        int pre = carryS + (t > 0 ? tile[t - 1] : 0);
        #pragma unroll
        for (int i = 0; i < 8; ++i) {
            int idx = base + t * 8 + i;
            if (idx < N) rowptr[idx + 1] = pre + v[i];
        }
        __syncthreads();
        if (t == 0) carryS += tile[1023];
        __syncthreads();
    }
}

__global__ void scatter_k(const int* __restrict__ src, const int* __restrict__ dst,
                          int E, int N, const int* __restrict__ rowptr,
                          int* __restrict__ cursor, int* __restrict__ eid,
                          int* __restrict__ esrc)
{
    int e = blockIdx.x * blockDim.x + threadIdx.x;
    if (e >= E + N) return;
    int i = (e < E) ? dst[e] : (e - E);
    int j = (e < E) ? src[e] : (e - E);
    int pos = atomicAdd(&cursor[i], 1);
    int idx = rowptr[i] + pos;
    eid[idx] = e;
    esrc[idx] = j;
}

// ---------------------------------------------------------------------------
// Edge logits: one wave per edge. D = 64 == wave width.
// e[h] = sum_d att[h][d] * leaky_relu(xl[src][h*64+d] + xr[dst][h*64+d], 0.2)
// ---------------------------------------------------------------------------
template<int H>
__global__ __launch_bounds__(256) void edge_logits_k(
    const float* __restrict__ xl, const float* __restrict__ xr,
    const int* __restrict__ src, const int* __restrict__ dst,
    int E, int N, const float* __restrict__ att, float* __restrict__ elog)
{
    const int wid  = (blockIdx.x * blockDim.x + threadIdx.x) >> 6;
    const int lane = threadIdx.x & 63;
    const int E2 = E + N;
    if (wid >= E2) return;
    const int j = (wid < E) ? src[wid] : (wid - E);
    const int i = (wid < E) ? dst[wid] : (wid - E);
    const int HD = H * 64;
    float p[H];
    #pragma unroll
    for (int h = 0; h < H; ++h) {
        float v = xl[(size_t)j * HD + h * 64 + lane] + xr[(size_t)i * HD + h * 64 + lane];
        float z = (v > 0.f) ? v : 0.2f * v;
        p[h] = z * att[h * 64 + lane];
    }
    #pragma unroll
    for (int off = 32; off >= 1; off >>= 1)
        #pragma unroll
        for (int h = 0; h < H; ++h)
            p[h] += __shfl_xor(p[h], off, 64);
    if (lane == 0) {
        #pragma unroll
        for (int h = 0; h < H; ++h)
            elog[(size_t)wid * H + h] = p[h];
    }
}

// ---------------------------------------------------------------------------
// Node softmax + aggregation: one wave per node, lane = feature dim within head.
// ---------------------------------------------------------------------------
template<int H>
__global__ __launch_bounds__(256) void node_agg_k(
    const float* __restrict__ xl, const float* __restrict__ elog,
    const int* __restrict__ rowptr, const int* __restrict__ eid,
    const int* __restrict__ esrc, const float* __restrict__ bias,
    float* __restrict__ out, int N, float oslope)
{
    const int wid  = (blockIdx.x * blockDim.x + threadIdx.x) >> 6;
    const int lane = threadIdx.x & 63;
    if (wid >= N) return;
    const int r0 = rowptr[wid], r1 = rowptr[wid + 1];
    const int HD = H * 64;

    float m[H];
    #pragma unroll
    for (int h = 0; h < H; ++h) m[h] = -3.4e38f;
    for (int k = r0 + lane; k < r1; k += 64) {
        int e = eid[k];
        #pragma unroll
        for (int h = 0; h < H; ++h) m[h] = fmaxf(m[h], elog[(size_t)e * H + h]);
    }
    #pragma unroll
    for (int off = 32; off >= 1; off >>= 1)
        #pragma unroll
        for (int h = 0; h < H; ++h)
            m[h] = fmaxf(m[h], __shfl_xor(m[h], off, 64));

    float s[H] = {};
    for (int k = r0 + lane; k < r1; k += 64) {
        int e = eid[k];
        #pragma unroll
        for (int h = 0; h < H; ++h) s[h] += __expf(elog[(size_t)e * H + h] - m[h]);
    }
    #pragma unroll
    for (int off = 32; off >= 1; off >>= 1)
        #pragma unroll
        for (int h = 0; h < H; ++h)
            s[h] += __shfl_xor(s[h], off, 64);

    float rs[H];
    #pragma unroll
    for (int h = 0; h < H; ++h) rs[h] = 1.f / (s[h] + 1e-16f);

    float acc[H] = {};
    for (int k = r0; k < r1; ++k) {
        int e = eid[k];
        int j = esrc[k];
        #pragma unroll
        for (int h = 0; h < H; ++h) {
            float a = __expf(elog[(size_t)e * H + h] - m[h]) * rs[h];
            acc[h] += a * xl[(size_t)j * HD + h * 64 + lane];
        }
    }
    #pragma unroll
    for (int h = 0; h < H; ++h) {
        float v = acc[h] + bias[h * 64 + lane];
        out[(size_t)wid * HD + h * 64 + lane] = (v > 0.f) ? v : oslope * v;
    }
}

// ---------------------------------------------------------------------------
// Pooling
// ---------------------------------------------------------------------------
__device__ __forceinline__ unsigned fenc(float f) {
    unsigned u = __float_as_uint(f);
    return (u & 0x80000000u) ? ~u : (u | 0x80000000u);
}
__device__ __forceinline__ float fdec(unsigned u) {
    return __uint_as_float((u & 0x80000000u) ? (u & 0x7fffffffu) : ~u);
}

__global__ void fillu_k(unsigned* __restrict__ p, unsigned v, int n)
{
    int i = blockIdx.x * blockDim.x + threadIdx.x;
    if (i < n) p[i] = v;
}

__global__ __launch_bounds__(256) void pool_k(
    const float* __restrict__ h, const int* __restrict__ batch, int N,
    unsigned* __restrict__ gmaxu, float* __restrict__ gsum, float* __restrict__ gcnt)
{
    const int wid  = (blockIdx.x * blockDim.x + threadIdx.x) >> 6;
    const int lane = threadIdx.x & 63;
    if (wid >= N) return;
    int g = batch[wid];
    float v = h[(size_t)wid * 64 + lane];
    atomicMax(&gmaxu[g * 64 + lane], fenc(v));
    atomicAdd(&gsum[g * 64 + lane], v);
    if (lane == 0) atomicAdd(&gcnt[g], 1.f);
}

__global__ __launch_bounds__(128) void final_k(
    const unsigned* __restrict__ gmaxu, const float* __restrict__ gsum,
    const float* __restrict__ gcnt, const float* __restrict__ out_w,
    const float* __restrict__ out_b, float* __restrict__ out,
    float* __restrict__ hid_out)
{
    const int g = blockIdx.x;
    const int t = threadIdx.x;       // 128 threads
    __shared__ float hid[128];
    float v;
    if (t < 64) {
        v = fdec(gmaxu[g * 64 + t]);
    } else {
        float c = fmaxf(gcnt[g], 1.f);
        v = gsum[g * 64 + (t - 64)] / c;
    }
    hid[t] = v;
    hid_out[(size_t)g * 128 + t] = v;
    __syncthreads();
    const int w = t >> 6, lane = t & 63;
    float p = hid[lane] * out_w[w * 128 + lane] + hid[lane + 64] * out_w[w * 128 + 64 + lane];
    #pragma unroll
    for (int off = 32; off >= 1; off >>= 1) p += __shfl_xor(p, off, 64);
    if (lane == 0) out[g * 2 + w] = p + out_b[w];
}

// ---------------------------------------------------------------------------
extern "C" void kernel_launch(void* const* d_in, const int* in_sizes, int n_in,
                              void* d_out, int out_size, void* d_ws, size_t ws_size,
                              hipStream_t stream)
{
    const float* x    = (const float*)d_in[0];
    const int*   ei   = (const int*)d_in[1];
    const int*   batch= (const int*)d_in[2];
    const float* w1l  = (const float*)d_in[3];
    const float* w1r  = (const float*)d_in[4];
    const float* att1 = (const float*)d_in[5];
    const float* b1   = (const float*)d_in[6];
    const float* w2l  = (const float*)d_in[7];
    const float* w2r  = (const float*)d_in[8];
    const float* att2 = (const float*)d_in[9];
    const float* b2   = (const float*)d_in[10];
    const float* w3l  = (const float*)d_in[11];
    const float* w3r  = (const float*)d_in[12];
    const float* att3 = (const float*)d_in[13];
    const float* b3   = (const float*)d_in[14];
    const float* outw = (const float*)d_in[15];
    const float* outb = (const float*)d_in[16];

    const int N   = in_sizes[2];
    const int E   = in_sizes[1] / 2;
    const int E2  = E + N;
    const int G   = 256;
    const int FIN = in_sizes[0] / N;    // 128
    const int* src = ei;
    const int* dst = ei + E;

    char* ws = (char*)d_ws;
    size_t off = 0;
    auto alloc = [&](size_t bytes) -> void* {
        void* p = ws + off;
        off = (off + bytes + 255) & ~(size_t)255;
        return p;
    };
    float*    xl     = (float*)alloc((size_t)N * 256 * 4);
    float*    xr     = (float*)alloc((size_t)N * 256 * 4);
    float*    hA     = (float*)alloc((size_t)N * 256 * 4);
    float*    hB     = (float*)alloc((size_t)N * 128 * 4);
    float*    elog   = (float*)alloc((size_t)E2 * 4 * 4);
    int*      rowptr = (int*)alloc((size_t)(N + 1) * 4);
    int*      deg    = (int*)alloc((size_t)N * 4);
    int*      cursor = (int*)alloc((size_t)N * 4);
    int*      eid    = (int*)alloc((size_t)E2 * 4);
    int*      esrc   = (int*)alloc((size_t)E2 * 4);
    unsigned* gmaxu  = (unsigned*)alloc((size_t)G * 64 * 4);
    float*    gsum   = (float*)alloc((size_t)G * 64 * 4);
    float*    gcnt   = (float*)alloc((size_t)G * 4);

    hipMemsetAsync(deg,    0, (size_t)N * 4, stream);
    hipMemsetAsync(cursor, 0, (size_t)N * 4, stream);
    hipMemsetAsync(gsum,   0, (size_t)G * 64 * 4, stream);
    hipMemsetAsync(gcnt,   0, (size_t)G * 4, stream);
    fillu_k<<<(G * 64 + 255) / 256, 256, 0, stream>>>(gmaxu, 0x00800000u, G * 64);

    const int eb = (E2 + 255) / 256;
    hist_k<<<eb, 256, 0, stream>>>(dst, E, N, deg);
    scan_k<<<1, 1024, 0, stream>>>(deg, rowptr, N);
    scatter_k<<<eb, 256, 0, stream>>>(src, dst, E, N, rowptr, cursor, eid, esrc);

    const int mb  = (N + 63) / 64;
    const int ewb = (E2 * 64 + 255) / 256;   // one wave per edge
    const int nwb = (N * 64 + 255) / 256;    // one wave per node

    // ---- layer 1: FIN=128 -> H=4, HD=256
    gemm_xwT<<<dim3(mb, 4), 256, 0, stream>>>(x, w1l, xl, N, FIN, 256);
    gemm_xwT<<<dim3(mb, 4), 256, 0, stream>>>(x, w1r, xr, N, FIN, 256);
    edge_logits_k<4><<<ewb, 256, 0, stream>>>(xl, xr, src, dst, E, N, att1, elog);
    node_agg_k<4><<<nwb, 256, 0, stream>>>(xl, elog, rowptr, eid, esrc, b1, hA, N, 0.01f);

    // ---- layer 2: 256 -> H=2, HD=128
    gemm_xwT<<<dim3(mb, 2), 256, 0, stream>>>(hA, w2l, xl, N, 256, 128);
    gemm_xwT<<<dim3(mb, 2), 256, 0, stream>>>(hA, w2r, xr, N, 256, 128);
    edge_logits_k<2><<<ewb, 256, 0, stream>>>(xl, xr, src, dst, E, N, att2, elog);
    node_agg_k<2><<<nwb, 256, 0, stream>>>(xl, elog, rowptr, eid, esrc, b2, hB, N, 0.01f);

    // ---- layer 3: 128 -> H=1, HD=64
    gemm_xwT<<<dim3(mb, 1), 256, 0, stream>>>(hB, w3l, xl, N, 128, 64);
    gemm_xwT<<<dim3(mb, 1), 256, 0, stream>>>(hB, w3r, xr, N, 128, 64);
    edge_logits_k<1><<<ewb, 256, 0, stream>>>(xl, xr, src, dst, E, N, att3, elog);
    node_agg_k<1><<<nwb, 256, 0, stream>>>(xl, elog, rowptr, eid, esrc, b3, hA, N, 0.01f);

    // ---- pooling + head
    pool_k<<<nwb, 256, 0, stream>>>(hA, batch, N, gmaxu, gsum, gcnt);
    final_k<<<G, 128, 0, stream>>>(gmaxu, gsum, gcnt, outw, outb,
                                   (float*)d_out, (float*)d_out + G * 2);
}

// Round 2
// 876.905 us; speedup vs baseline: 1.4037x; 1.4037x over previous
//
#include <hip/hip_runtime.h>
#include <hip/hip_bf16.h>
#include <cfloat>
#include <cstdint>

// ---------------------------------------------------------------------------
// GATv2 x3 + global max/mean pool + linear head.
// Round 1: (a) bf16 MFMA GEMMs (16x16x32), intermediates carried in bf16;
//          (b) pool rewritten to exploit sorted batch_index (run-aggregation
//              in registers, atomics only at graph boundaries).
// ---------------------------------------------------------------------------

typedef __attribute__((ext_vector_type(8))) short bf16x8;
typedef __attribute__((ext_vector_type(4))) float f32x4;

// ---------------------------------------------------------------------------
// fp32 -> bf16 conversion
// ---------------------------------------------------------------------------
__global__ void f2b_k(const float* __restrict__ src, __hip_bfloat16* __restrict__ dst, int n)
{
    int i = (blockIdx.x * blockDim.x + threadIdx.x) * 4;
    if (i >= n) return;
    float4 v = *(const float4*)(src + i);
    dst[i + 0] = __float2bfloat16(v.x);
    dst[i + 1] = __float2bfloat16(v.y);
    dst[i + 2] = __float2bfloat16(v.z);
    dst[i + 3] = __float2bfloat16(v.w);
}

// convert all six weight matrices in one launch (sizes passed cumulative)
__global__ void f2b6_k(const float* p0, const float* p1, const float* p2,
                       const float* p3, const float* p4, const float* p5,
                       __hip_bfloat16* d0, __hip_bfloat16* d1, __hip_bfloat16* d2,
                       __hip_bfloat16* d3, __hip_bfloat16* d4, __hip_bfloat16* d5,
                       int s01, int s23, int s45)   // per-array sizes: p0,p1 have s01...
{
    int i = (blockIdx.x * blockDim.x + threadIdx.x) * 4;
    const float* s; __hip_bfloat16* d; int off;
    int t0 = 2 * s01, t1 = t0 + 2 * s23, t2 = t1 + 2 * s45;
    if (i < t0)      { int j = i;        s = (j < s01) ? p0 : p1; d = (j < s01) ? d0 : d1; off = j % s01; }
    else if (i < t1) { int j = i - t0;   s = (j < s23) ? p2 : p3; d = (j < s23) ? d2 : d3; off = j % s23; }
    else if (i < t2) { int j = i - t1;   s = (j < s45) ? p4 : p5; d = (j < s45) ? d4 : d5; off = j % s45; }
    else return;
    float4 v = *(const float4*)(s + off);
    d[off + 0] = __float2bfloat16(v.x);
    d[off + 1] = __float2bfloat16(v.y);
    d[off + 2] = __float2bfloat16(v.z);
    d[off + 3] = __float2bfloat16(v.w);
}

// ---------------------------------------------------------------------------
// bf16 MFMA GEMM: C = A @ W^T.  A: MxK bf16 row-major, W: (NT*16)xK bf16
// row-major.  One wave computes a 16 x (NT*16) strip of C.
// blockIdx.y in {0,1} selects (Wl,Cl) or (Wr,Cr) so both transforms share
// one dispatch.
// ---------------------------------------------------------------------------
template<int NT>
__global__ __launch_bounds__(256) void gemm_mfma(
    const __hip_bfloat16* __restrict__ A,
    const __hip_bfloat16* __restrict__ Wl, const __hip_bfloat16* __restrict__ Wr,
    float* __restrict__ Cl, float* __restrict__ Cr,
    int M, int K)
{
    const int wave = threadIdx.x >> 6, lane = threadIdx.x & 63;
    const int m0 = (blockIdx.x * 4 + wave) * 16;
    if (m0 >= M) return;
    const __hip_bfloat16* W = blockIdx.y ? Wr : Wl;
    float* C = blockIdx.y ? Cr : Cl;
    const int r16  = lane & 15;     // row within 16-tile (A) / col (C) / n-row (W)
    const int quad = lane >> 4;     // selects k-offset group of 8
    const __hip_bfloat16* Aptr = A + (size_t)(m0 + r16) * K + quad * 8;

    f32x4 acc[NT];
    #pragma unroll
    for (int n = 0; n < NT; ++n) acc[n] = (f32x4){0.f, 0.f, 0.f, 0.f};

    for (int k0 = 0; k0 < K; k0 += 32) {
        bf16x8 a = *(const bf16x8*)(Aptr + k0);
        #pragma unroll
        for (int n = 0; n < NT; ++n) {
            bf16x8 b = *(const bf16x8*)(W + (size_t)(n * 16 + r16) * K + k0 + quad * 8);
            acc[n] = __builtin_amdgcn_mfma_f32_16x16x32_bf16(a, b, acc[n], 0, 0, 0);
        }
    }
    const int Nout = NT * 16;
    #pragma unroll
    for (int n = 0; n < NT; ++n)
        #pragma unroll
        for (int r = 0; r < 4; ++r) {
            int row = m0 + quad * 4 + r;          // C/D: col=lane&15, row=quad*4+reg
            C[(size_t)row * Nout + n * 16 + r16] = acc[n][r];
        }
}

// ---------------------------------------------------------------------------
// CSR build (grouped by dst). Edge id e < E: (src[e], dst[e]); e >= E: self loop.
// ---------------------------------------------------------------------------
__global__ void hist_k(const int* __restrict__ dst, int E, int N, int* __restrict__ deg)
{
    int e = blockIdx.x * blockDim.x + threadIdx.x;
    if (e >= E + N) return;
    int i = (e < E) ? dst[e] : (e - E);
    atomicAdd(&deg[i], 1);
}

__global__ __launch_bounds__(1024) void scan_k(const int* __restrict__ deg,
                                               int* __restrict__ rowptr, int N)
{
    __shared__ int tile[1024];
    __shared__ int carryS;
    int t = threadIdx.x;
    if (t == 0) { carryS = 0; rowptr[0] = 0; }
    __syncthreads();
    for (int base = 0; base < N; base += 8192) {
        int v[8];
        int run = 0;
        #pragma unroll
        for (int i = 0; i < 8; ++i) {
            int idx = base + t * 8 + i;
            run += (idx < N) ? deg[idx] : 0;
            v[i] = run;
        }
        tile[t] = run;
        __syncthreads();
        for (int off = 1; off < 1024; off <<= 1) {
            int add = (t >= off) ? tile[t - off] : 0;
            __syncthreads();
            tile[t] += add;
            __syncthreads();
        }
        int pre = carryS + (t > 0 ? tile[t - 1] : 0);
        #pragma unroll
        for (int i = 0; i < 8; ++i) {
            int idx = base + t * 8 + i;
            if (idx < N) rowptr[idx + 1] = pre + v[i];
        }
        __syncthreads();
        if (t == 0) carryS += tile[1023];
        __syncthreads();
    }
}

__global__ void scatter_k(const int* __restrict__ src, const int* __restrict__ dst,
                          int E, int N, const int* __restrict__ rowptr,
                          int* __restrict__ cursor, int* __restrict__ eid,
                          int* __restrict__ esrc)
{
    int e = blockIdx.x * blockDim.x + threadIdx.x;
    if (e >= E + N) return;
    int i = (e < E) ? dst[e] : (e - E);
    int j = (e < E) ? src[e] : (e - E);
    int pos = atomicAdd(&cursor[i], 1);
    int idx = rowptr[i] + pos;
    eid[idx] = e;
    esrc[idx] = j;
}

// ---------------------------------------------------------------------------
// Edge logits: one wave per edge. D = 64 == wave width.
// ---------------------------------------------------------------------------
template<int H>
__global__ __launch_bounds__(256) void edge_logits_k(
    const float* __restrict__ xl, const float* __restrict__ xr,
    const int* __restrict__ src, const int* __restrict__ dst,
    int E, int N, const float* __restrict__ att, float* __restrict__ elog)
{
    const int wid  = (blockIdx.x * blockDim.x + threadIdx.x) >> 6;
    const int lane = threadIdx.x & 63;
    const int E2 = E + N;
    if (wid >= E2) return;
    const int j = (wid < E) ? src[wid] : (wid - E);
    const int i = (wid < E) ? dst[wid] : (wid - E);
    const int HD = H * 64;
    float p[H];
    #pragma unroll
    for (int h = 0; h < H; ++h) {
        float v = xl[(size_t)j * HD + h * 64 + lane] + xr[(size_t)i * HD + h * 64 + lane];
        float z = (v > 0.f) ? v : 0.2f * v;
        p[h] = z * att[h * 64 + lane];
    }
    #pragma unroll
    for (int off = 32; off >= 1; off >>= 1)
        #pragma unroll
        for (int h = 0; h < H; ++h)
            p[h] += __shfl_xor(p[h], off, 64);
    if (lane == 0) {
        #pragma unroll
        for (int h = 0; h < H; ++h)
            elog[(size_t)wid * H + h] = p[h];
    }
}

// ---------------------------------------------------------------------------
// Node softmax + aggregation: one wave per node, lane = feature dim in head.
// BF16OUT: write next layer's GEMM input directly as bf16.
// ---------------------------------------------------------------------------
template<int H, bool BF16OUT>
__global__ __launch_bounds__(256) void node_agg_k(
    const float* __restrict__ xl, const float* __restrict__ elog,
    const int* __restrict__ rowptr, const int* __restrict__ eid,
    const int* __restrict__ esrc, const float* __restrict__ bias,
    void* __restrict__ outv, int N, float oslope)
{
    const int wid  = (blockIdx.x * blockDim.x + threadIdx.x) >> 6;
    const int lane = threadIdx.x & 63;
    if (wid >= N) return;
    const int r0 = rowptr[wid], r1 = rowptr[wid + 1];
    const int HD = H * 64;

    float m[H];
    #pragma unroll
    for (int h = 0; h < H; ++h) m[h] = -3.4e38f;
    for (int k = r0 + lane; k < r1; k += 64) {
        int e = eid[k];
        #pragma unroll
        for (int h = 0; h < H; ++h) m[h] = fmaxf(m[h], elog[(size_t)e * H + h]);
    }
    #pragma unroll
    for (int off = 32; off >= 1; off >>= 1)
        #pragma unroll
        for (int h = 0; h < H; ++h)
            m[h] = fmaxf(m[h], __shfl_xor(m[h], off, 64));

    float s[H] = {};
    for (int k = r0 + lane; k < r1; k += 64) {
        int e = eid[k];
        #pragma unroll
        for (int h = 0; h < H; ++h) s[h] += __expf(elog[(size_t)e * H + h] - m[h]);
    }
    #pragma unroll
    for (int off = 32; off >= 1; off >>= 1)
        #pragma unroll
        for (int h = 0; h < H; ++h)
            s[h] += __shfl_xor(s[h], off, 64);

    float rs[H];
    #pragma unroll
    for (int h = 0; h < H; ++h) rs[h] = 1.f / (s[h] + 1e-16f);

    float acc[H] = {};
    for (int k = r0; k < r1; ++k) {
        int e = eid[k];
        int j = esrc[k];
        #pragma unroll
        for (int h = 0; h < H; ++h) {
            float a = __expf(elog[(size_t)e * H + h] - m[h]) * rs[h];
            acc[h] += a * xl[(size_t)j * HD + h * 64 + lane];
        }
    }
    #pragma unroll
    for (int h = 0; h < H; ++h) {
        float v = acc[h] + bias[h * 64 + lane];
        v = (v > 0.f) ? v : oslope * v;
        size_t idx = (size_t)wid * HD + h * 64 + lane;
        if (BF16OUT) ((__hip_bfloat16*)outv)[idx] = __float2bfloat16(v);
        else         ((float*)outv)[idx] = v;
    }
}

// ---------------------------------------------------------------------------
// Pooling: batch_index is SORTED -> run-aggregate in registers, flush atomics
// only at graph boundaries.  One wave handles 16 consecutive nodes.
// ---------------------------------------------------------------------------
__device__ __forceinline__ unsigned fenc(float f) {
    unsigned u = __float_as_uint(f);
    return (u & 0x80000000u) ? ~u : (u | 0x80000000u);
}
__device__ __forceinline__ float fdec(unsigned u) {
    return __uint_as_float((u & 0x80000000u) ? (u & 0x7fffffffu) : ~u);
}

__global__ void fillu_k(unsigned* __restrict__ p, unsigned v, int n)
{
    int i = blockIdx.x * blockDim.x + threadIdx.x;
    if (i < n) p[i] = v;
}

__global__ __launch_bounds__(256) void pool_k(
    const float* __restrict__ h, const int* __restrict__ batch, int N,
    unsigned* __restrict__ gmaxu, float* __restrict__ gsum, float* __restrict__ gcnt)
{
    const int wid  = (blockIdx.x * blockDim.x + threadIdx.x) >> 6;
    const int lane = threadIdx.x & 63;
    const int n0 = wid * 16;
    if (n0 >= N) return;
    int gcur = batch[n0];
    float vmax = -3.4e38f, vsum = 0.f;
    int cnt = 0;
    #pragma unroll 4
    for (int i = 0; i < 16; ++i) {
        int n = n0 + i;
        if (n >= N) break;
        int g = batch[n];
        if (g != gcur) {
            atomicMax(&gmaxu[gcur * 64 + lane], fenc(vmax));
            atomicAdd(&gsum[gcur * 64 + lane], vsum);
            if (lane == 0) atomicAdd(&gcnt[gcur], (float)cnt);
            gcur = g; vmax = -3.4e38f; vsum = 0.f; cnt = 0;
        }
        float v = h[(size_t)n * 64 + lane];
        vmax = fmaxf(vmax, v);
        vsum += v;
        cnt++;
    }
    atomicMax(&gmaxu[gcur * 64 + lane], fenc(vmax));
    atomicAdd(&gsum[gcur * 64 + lane], vsum);
    if (lane == 0) atomicAdd(&gcnt[gcur], (float)cnt);
}

__global__ __launch_bounds__(128) void final_k(
    const unsigned* __restrict__ gmaxu, const float* __restrict__ gsum,
    const float* __restrict__ gcnt, const float* __restrict__ out_w,
    const float* __restrict__ out_b, float* __restrict__ out,
    float* __restrict__ hid_out)
{
    const int g = blockIdx.x;
    const int t = threadIdx.x;
    __shared__ float hid[128];
    float v;
    if (t < 64) {
        v = fdec(gmaxu[g * 64 + t]);
    } else {
        float c = fmaxf(gcnt[g], 1.f);
        v = gsum[g * 64 + (t - 64)] / c;
    }
    hid[t] = v;
    hid_out[(size_t)g * 128 + t] = v;
    __syncthreads();
    const int w = t >> 6, lane = t & 63;
    float p = hid[lane] * out_w[w * 128 + lane] + hid[lane + 64] * out_w[w * 128 + 64 + lane];
    #pragma unroll
    for (int off = 32; off >= 1; off >>= 1) p += __shfl_xor(p, off, 64);
    if (lane == 0) out[g * 2 + w] = p + out_b[w];
}

// ---------------------------------------------------------------------------
extern "C" void kernel_launch(void* const* d_in, const int* in_sizes, int n_in,
                              void* d_out, int out_size, void* d_ws, size_t ws_size,
                              hipStream_t stream)
{
    const float* x    = (const float*)d_in[0];
    const int*   ei   = (const int*)d_in[1];
    const int*   batch= (const int*)d_in[2];
    const float* w1l  = (const float*)d_in[3];
    const float* w1r  = (const float*)d_in[4];
    const float* att1 = (const float*)d_in[5];
    const float* b1   = (const float*)d_in[6];
    const float* w2l  = (const float*)d_in[7];
    const float* w2r  = (const float*)d_in[8];
    const float* att2 = (const float*)d_in[9];
    const float* b2   = (const float*)d_in[10];
    const float* w3l  = (const float*)d_in[11];
    const float* w3r  = (const float*)d_in[12];
    const float* att3 = (const float*)d_in[13];
    const float* b3   = (const float*)d_in[14];
    const float* outw = (const float*)d_in[15];
    const float* outb = (const float*)d_in[16];

    const int N   = in_sizes[2];
    const int E   = in_sizes[1] / 2;
    const int E2  = E + N;
    const int G   = 256;
    const int FIN = in_sizes[0] / N;    // 128
    const int* src = ei;
    const int* dst = ei + E;

    char* ws = (char*)d_ws;
    size_t off = 0;
    auto alloc = [&](size_t bytes) -> void* {
        void* p = ws + off;
        off = (off + bytes + 255) & ~(size_t)255;
        return p;
    };
    float*          xl    = (float*)alloc((size_t)N * 256 * 4);
    float*          xr    = (float*)alloc((size_t)N * 256 * 4);
    __hip_bfloat16* xb    = (__hip_bfloat16*)alloc((size_t)N * 128 * 2);
    __hip_bfloat16* hAb   = (__hip_bfloat16*)alloc((size_t)N * 256 * 2);
    __hip_bfloat16* hBb   = (__hip_bfloat16*)alloc((size_t)N * 128 * 2);
    float*          h3    = (float*)alloc((size_t)N * 64 * 4);
    float*          elog  = (float*)alloc((size_t)E2 * 4 * 4);
    int*            rowptr= (int*)alloc((size_t)(N + 1) * 4);
    int*            deg   = (int*)alloc((size_t)N * 4);
    int*            cursor= (int*)alloc((size_t)N * 4);
    int*            eid   = (int*)alloc((size_t)E2 * 4);
    int*            esrc  = (int*)alloc((size_t)E2 * 4);
    unsigned*       gmaxu = (unsigned*)alloc((size_t)G * 64 * 4);
    float*          gsum  = (float*)alloc((size_t)G * 64 * 4);
    float*          gcnt  = (float*)alloc((size_t)G * 4);
    __hip_bfloat16* w1lb  = (__hip_bfloat16*)alloc(256 * 128 * 2);
    __hip_bfloat16* w1rb  = (__hip_bfloat16*)alloc(256 * 128 * 2);
    __hip_bfloat16* w2lb  = (__hip_bfloat16*)alloc(128 * 256 * 2);
    __hip_bfloat16* w2rb  = (__hip_bfloat16*)alloc(128 * 256 * 2);
    __hip_bfloat16* w3lb  = (__hip_bfloat16*)alloc(64 * 128 * 2);
    __hip_bfloat16* w3rb  = (__hip_bfloat16*)alloc(64 * 128 * 2);

    hipMemsetAsync(deg,    0, (size_t)N * 4, stream);
    hipMemsetAsync(cursor, 0, (size_t)N * 4, stream);
    hipMemsetAsync(gsum,   0, (size_t)G * 64 * 4, stream);
    hipMemsetAsync(gcnt,   0, (size_t)G * 4, stream);
    fillu_k<<<(G * 64 + 255) / 256, 256, 0, stream>>>(gmaxu, 0x00800000u, G * 64);

    // conversions
    const int s1 = 256 * 128, s2 = 128 * 256, s3 = 64 * 128;
    const int wtot = 2 * s1 + 2 * s2 + 2 * s3;
    f2b_k<<<((size_t)N * 128 / 4 + 255) / 256, 256, 0, stream>>>(x, xb, N * 128);
    f2b6_k<<<(wtot / 4 + 255) / 256, 256, 0, stream>>>(
        w1l, w1r, w2l, w2r, w3l, w3r, w1lb, w1rb, w2lb, w2rb, w3lb, w3rb, s1, s2, s3);

    // CSR
    const int eb = (E2 + 255) / 256;
    hist_k<<<eb, 256, 0, stream>>>(dst, E, N, deg);
    scan_k<<<1, 1024, 0, stream>>>(deg, rowptr, N);
    scatter_k<<<eb, 256, 0, stream>>>(src, dst, E, N, rowptr, cursor, eid, esrc);

    const int gx  = (N / 16 + 3) / 4;        // wave-strips of 16 rows, 4 waves/block
    const int ewb = (E2 * 64 + 255) / 256;
    const int nwb = (N * 64 + 255) / 256;

    // ---- layer 1: K=128 -> H=4, HD=256 (NT=16)
    gemm_mfma<16><<<dim3(gx, 2), 256, 0, stream>>>(xb, w1lb, w1rb, xl, xr, N, FIN);
    edge_logits_k<4><<<ewb, 256, 0, stream>>>(xl, xr, src, dst, E, N, att1, elog);
    node_agg_k<4, true><<<nwb, 256, 0, stream>>>(xl, elog, rowptr, eid, esrc, b1, hAb, N, 0.01f);

    // ---- layer 2: K=256 -> H=2, HD=128 (NT=8)
    gemm_mfma<8><<<dim3(gx, 2), 256, 0, stream>>>(hAb, w2lb, w2rb, xl, xr, N, 256);
    edge_logits_k<2><<<ewb, 256, 0, stream>>>(xl, xr, src, dst, E, N, att2, elog);
    node_agg_k<2, true><<<nwb, 256, 0, stream>>>(xl, elog, rowptr, eid, esrc, b2, hBb, N, 0.01f);

    // ---- layer 3: K=128 -> H=1, HD=64 (NT=4)
    gemm_mfma<4><<<dim3(gx, 2), 256, 0, stream>>>(hBb, w3lb, w3rb, xl, xr, N, 128);
    edge_logits_k<1><<<ewb, 256, 0, stream>>>(xl, xr, src, dst, E, N, att3, elog);
    node_agg_k<1, false><<<nwb, 256, 0, stream>>>(xl, elog, rowptr, eid, esrc, b3, h3, N, 0.01f);

    // ---- pooling + head
    const int pb = (N / 16 + 3) / 4;         // one wave per 16 nodes
    pool_k<<<pb, 256, 0, stream>>>(h3, batch, N, gmaxu, gsum, gcnt);
    final_k<<<G, 128, 0, stream>>>(gmaxu, gsum, gcnt, outw, outb,
                                   (float*)d_out, (float*)d_out + G * 2);
}

// Round 3
// 571.086 us; speedup vs baseline: 2.1554x; 1.5355x over previous
//
#include <hip/hip_runtime.h>
#include <hip/hip_bf16.h>
#include <cfloat>
#include <cstdint>

// ---------------------------------------------------------------------------
// GATv2 x3 + global max/mean pool + linear head.
// Round 2: fused edge-logit + online-softmax + aggregation (one wave/node,
// single gather pass over edges); xl/xr carried in bf16 (halved gather bytes).
// ---------------------------------------------------------------------------

typedef __attribute__((ext_vector_type(8))) short bf16x8;
typedef __attribute__((ext_vector_type(4))) float f32x4;
typedef __attribute__((ext_vector_type(4))) unsigned short us4;
typedef __attribute__((ext_vector_type(2))) unsigned short us2;

__device__ __forceinline__ float bf2f(unsigned short u) {
    return __uint_as_float((unsigned)u << 16);
}
__device__ __forceinline__ unsigned short f2bf(float f) {   // RNE
    unsigned u = __float_as_uint(f);
    u += 0x7FFFu + ((u >> 16) & 1u);
    return (unsigned short)(u >> 16);
}

// ---------------------------------------------------------------------------
// fp32 -> bf16 conversion
// ---------------------------------------------------------------------------
__global__ void f2b_k(const float* __restrict__ src, __hip_bfloat16* __restrict__ dst, int n)
{
    int i = (blockIdx.x * blockDim.x + threadIdx.x) * 4;
    if (i >= n) return;
    float4 v = *(const float4*)(src + i);
    unsigned short* d = (unsigned short*)dst;
    us4 o = {f2bf(v.x), f2bf(v.y), f2bf(v.z), f2bf(v.w)};
    *(us4*)(d + i) = o;
}

__global__ void f2b6_k(const float* p0, const float* p1, const float* p2,
                       const float* p3, const float* p4, const float* p5,
                       __hip_bfloat16* d0, __hip_bfloat16* d1, __hip_bfloat16* d2,
                       __hip_bfloat16* d3, __hip_bfloat16* d4, __hip_bfloat16* d5,
                       int s01, int s23, int s45)
{
    int i = (blockIdx.x * blockDim.x + threadIdx.x) * 4;
    const float* s; __hip_bfloat16* d; int off;
    int t0 = 2 * s01, t1 = t0 + 2 * s23, t2 = t1 + 2 * s45;
    if (i < t0)      { int j = i;        s = (j < s01) ? p0 : p1; d = (j < s01) ? d0 : d1; off = j % s01; }
    else if (i < t1) { int j = i - t0;   s = (j < s23) ? p2 : p3; d = (j < s23) ? d2 : d3; off = j % s23; }
    else if (i < t2) { int j = i - t1;   s = (j < s45) ? p4 : p5; d = (j < s45) ? d4 : d5; off = j % s45; }
    else return;
    float4 v = *(const float4*)(s + off);
    us4 o = {f2bf(v.x), f2bf(v.y), f2bf(v.z), f2bf(v.w)};
    *(us4*)((unsigned short*)d + off) = o;
}

// ---------------------------------------------------------------------------
// bf16 MFMA GEMM: C = A @ W^T, C written as bf16.  One wave: 16 x (NT*16).
// blockIdx.y selects (Wl,Cl) vs (Wr,Cr).
// ---------------------------------------------------------------------------
template<int NT>
__global__ __launch_bounds__(256) void gemm_mfma(
    const __hip_bfloat16* __restrict__ A,
    const __hip_bfloat16* __restrict__ Wl, const __hip_bfloat16* __restrict__ Wr,
    __hip_bfloat16* __restrict__ Cl, __hip_bfloat16* __restrict__ Cr,
    int M, int K)
{
    const int wave = threadIdx.x >> 6, lane = threadIdx.x & 63;
    const int m0 = (blockIdx.x * 4 + wave) * 16;
    if (m0 >= M) return;
    const __hip_bfloat16* W = blockIdx.y ? Wr : Wl;
    __hip_bfloat16* C = blockIdx.y ? Cr : Cl;
    const int r16  = lane & 15;
    const int quad = lane >> 4;
    const __hip_bfloat16* Aptr = A + (size_t)(m0 + r16) * K + quad * 8;

    f32x4 acc[NT];
    #pragma unroll
    for (int n = 0; n < NT; ++n) acc[n] = (f32x4){0.f, 0.f, 0.f, 0.f};

    for (int k0 = 0; k0 < K; k0 += 32) {
        bf16x8 a = *(const bf16x8*)(Aptr + k0);
        #pragma unroll
        for (int n = 0; n < NT; ++n) {
            bf16x8 b = *(const bf16x8*)(W + (size_t)(n * 16 + r16) * K + k0 + quad * 8);
            acc[n] = __builtin_amdgcn_mfma_f32_16x16x32_bf16(a, b, acc[n], 0, 0, 0);
        }
    }
    const int Nout = NT * 16;
    unsigned short* Cu = (unsigned short*)C;
    #pragma unroll
    for (int n = 0; n < NT; ++n)
        #pragma unroll
        for (int r = 0; r < 4; ++r) {
            int row = m0 + quad * 4 + r;          // C/D: col=lane&15, row=quad*4+reg
            Cu[(size_t)row * Nout + n * 16 + r16] = f2bf(acc[n][r]);
        }
}

// ---------------------------------------------------------------------------
// CSR build (grouped by dst). e < E: (src[e], dst[e]); e >= E: self loop.
// ---------------------------------------------------------------------------
__global__ void hist_k(const int* __restrict__ dst, int E, int N, int* __restrict__ deg)
{
    int e = blockIdx.x * blockDim.x + threadIdx.x;
    if (e >= E + N) return;
    int i = (e < E) ? dst[e] : (e - E);
    atomicAdd(&deg[i], 1);
}

__global__ __launch_bounds__(1024) void scan_k(const int* __restrict__ deg,
                                               int* __restrict__ rowptr, int N)
{
    __shared__ int tile[1024];
    __shared__ int carryS;
    int t = threadIdx.x;
    if (t == 0) { carryS = 0; rowptr[0] = 0; }
    __syncthreads();
    for (int base = 0; base < N; base += 8192) {
        int v[8];
        int run = 0;
        #pragma unroll
        for (int i = 0; i < 8; ++i) {
            int idx = base + t * 8 + i;
            run += (idx < N) ? deg[idx] : 0;
            v[i] = run;
        }
        tile[t] = run;
        __syncthreads();
        for (int off = 1; off < 1024; off <<= 1) {
            int add = (t >= off) ? tile[t - off] : 0;
            __syncthreads();
            tile[t] += add;
            __syncthreads();
        }
        int pre = carryS + (t > 0 ? tile[t - 1] : 0);
        #pragma unroll
        for (int i = 0; i < 8; ++i) {
            int idx = base + t * 8 + i;
            if (idx < N) rowptr[idx + 1] = pre + v[i];
        }
        __syncthreads();
        if (t == 0) carryS += tile[1023];
        __syncthreads();
    }
}

__global__ void scatter_k(const int* __restrict__ src, const int* __restrict__ dst,
                          int E, int N, const int* __restrict__ rowptr,
                          int* __restrict__ cursor, int* __restrict__ esrc)
{
    int e = blockIdx.x * blockDim.x + threadIdx.x;
    if (e >= E + N) return;
    int i = (e < E) ? dst[e] : (e - E);
    int j = (e < E) ? src[e] : (e - E);
    int pos = atomicAdd(&cursor[i], 1);
    esrc[rowptr[i] + pos] = j;
}

// ---------------------------------------------------------------------------
// Fused GATv2 layer: logits + online softmax + aggregation, one wave per node.
// Lane holds H consecutive features f = lane*H .. lane*H+H-1 (all same head,
// head = lane / (64/H)).  Per edge: one vector load of xl[src], in-lane dot,
// butterfly over the 64/H-lane head group, scalar online-softmax update.
// ---------------------------------------------------------------------------
template<int H, bool BF16OUT>
__global__ __launch_bounds__(256) void fused_agg_k(
    const __hip_bfloat16* __restrict__ xl, const __hip_bfloat16* __restrict__ xr,
    const int* __restrict__ rowptr, const int* __restrict__ esrc,
    const float* __restrict__ att, const float* __restrict__ bias,
    void* __restrict__ outv, int N, float oslope)
{
    const int wid  = (blockIdx.x * blockDim.x + threadIdx.x) >> 6;
    const int lane = threadIdx.x & 63;
    if (wid >= N) return;
    const int HD = H * 64;
    const int GS = 64 / H;              // lanes per head group
    const int f0 = lane * H;            // first flattened feature for this lane

    const unsigned short* xlu = (const unsigned short*)xl;
    const unsigned short* xru = (const unsigned short*)xr;

    float xrv[H], attv[H];
    {
        unsigned short raw[H];
        if constexpr (H == 4) *(us4*)raw = *(const us4*)(xru + (size_t)wid * HD + f0);
        else if constexpr (H == 2) *(us2*)raw = *(const us2*)(xru + (size_t)wid * HD + f0);
        else raw[0] = xru[(size_t)wid * HD + f0];
        #pragma unroll
        for (int i = 0; i < H; ++i) { xrv[i] = bf2f(raw[i]); attv[i] = att[f0 + i]; }
    }

    const int r0 = rowptr[wid], r1 = rowptr[wid + 1];
    float m = -3.0e38f, s = 0.f;
    float acc[H];
    #pragma unroll
    for (int i = 0; i < H; ++i) acc[i] = 0.f;

    for (int k = r0; k < r1; ++k) {
        int j = esrc[k];
        float xlv[H];
        {
            unsigned short raw[H];
            if constexpr (H == 4) *(us4*)raw = *(const us4*)(xlu + (size_t)j * HD + f0);
            else if constexpr (H == 2) *(us2*)raw = *(const us2*)(xlu + (size_t)j * HD + f0);
            else raw[0] = xlu[(size_t)j * HD + f0];
            #pragma unroll
            for (int i = 0; i < H; ++i) xlv[i] = bf2f(raw[i]);
        }
        float p = 0.f;
        #pragma unroll
        for (int i = 0; i < H; ++i) {
            float z = xlv[i] + xrv[i];
            z = (z > 0.f) ? z : 0.2f * z;
            p += z * attv[i];
        }
        #pragma unroll
        for (int off = 1; off < GS; off <<= 1)
            p += __shfl_xor(p, off, 64);
        // online softmax update (scalar per lane; all lanes of a group agree)
        float nm = fmaxf(m, p);
        float sc = __expf(m - nm);
        float w  = __expf(p - nm);
        s = s * sc + w;
        m = nm;
        #pragma unroll
        for (int i = 0; i < H; ++i) acc[i] = acc[i] * sc + w * xlv[i];
    }

    float rs = 1.f / (s + 1e-16f);
    if constexpr (BF16OUT) {
        unsigned short o[H];
        #pragma unroll
        for (int i = 0; i < H; ++i) {
            float v = acc[i] * rs + bias[f0 + i];
            o[i] = f2bf((v > 0.f) ? v : oslope * v);
        }
        unsigned short* ou = (unsigned short*)outv;
        if constexpr (H == 4) *(us4*)(ou + (size_t)wid * HD + f0) = *(us4*)o;
        else if constexpr (H == 2) *(us2*)(ou + (size_t)wid * HD + f0) = *(us2*)o;
        else ou[(size_t)wid * HD + f0] = o[0];
    } else {
        float* of = (float*)outv;
        #pragma unroll
        for (int i = 0; i < H; ++i) {
            float v = acc[i] * rs + bias[f0 + i];
            of[(size_t)wid * HD + f0 + i] = (v > 0.f) ? v : oslope * v;
        }
    }
}

// ---------------------------------------------------------------------------
// Pooling (batch_index sorted -> run aggregation, atomics at boundaries only)
// ---------------------------------------------------------------------------
__device__ __forceinline__ unsigned fenc(float f) {
    unsigned u = __float_as_uint(f);
    return (u & 0x80000000u) ? ~u : (u | 0x80000000u);
}
__device__ __forceinline__ float fdec(unsigned u) {
    return __uint_as_float((u & 0x80000000u) ? (u & 0x7fffffffu) : ~u);
}

__global__ void fillu_k(unsigned* __restrict__ p, unsigned v, int n)
{
    int i = blockIdx.x * blockDim.x + threadIdx.x;
    if (i < n) p[i] = v;
}

__global__ __launch_bounds__(256) void pool_k(
    const float* __restrict__ h, const int* __restrict__ batch, int N,
    unsigned* __restrict__ gmaxu, float* __restrict__ gsum, float* __restrict__ gcnt)
{
    const int wid  = (blockIdx.x * blockDim.x + threadIdx.x) >> 6;
    const int lane = threadIdx.x & 63;
    const int n0 = wid * 16;
    if (n0 >= N) return;
    int gcur = batch[n0];
    float vmax = -3.4e38f, vsum = 0.f;
    int cnt = 0;
    #pragma unroll 4
    for (int i = 0; i < 16; ++i) {
        int n = n0 + i;
        if (n >= N) break;
        int g = batch[n];
        if (g != gcur) {
            atomicMax(&gmaxu[gcur * 64 + lane], fenc(vmax));
            atomicAdd(&gsum[gcur * 64 + lane], vsum);
            if (lane == 0) atomicAdd(&gcnt[gcur], (float)cnt);
            gcur = g; vmax = -3.4e38f; vsum = 0.f; cnt = 0;
        }
        float v = h[(size_t)n * 64 + lane];
        vmax = fmaxf(vmax, v);
        vsum += v;
        cnt++;
    }
    atomicMax(&gmaxu[gcur * 64 + lane], fenc(vmax));
    atomicAdd(&gsum[gcur * 64 + lane], vsum);
    if (lane == 0) atomicAdd(&gcnt[gcur], (float)cnt);
}

__global__ __launch_bounds__(128) void final_k(
    const unsigned* __restrict__ gmaxu, const float* __restrict__ gsum,
    const float* __restrict__ gcnt, const float* __restrict__ out_w,
    const float* __restrict__ out_b, float* __restrict__ out,
    float* __restrict__ hid_out)
{
    const int g = blockIdx.x;
    const int t = threadIdx.x;
    __shared__ float hid[128];
    float v;
    if (t < 64) {
        v = fdec(gmaxu[g * 64 + t]);
    } else {
        float c = fmaxf(gcnt[g], 1.f);
        v = gsum[g * 64 + (t - 64)] / c;
    }
    hid[t] = v;
    hid_out[(size_t)g * 128 + t] = v;
    __syncthreads();
    const int w = t >> 6, lane = t & 63;
    float p = hid[lane] * out_w[w * 128 + lane] + hid[lane + 64] * out_w[w * 128 + 64 + lane];
    #pragma unroll
    for (int off = 32; off >= 1; off >>= 1) p += __shfl_xor(p, off, 64);
    if (lane == 0) out[g * 2 + w] = p + out_b[w];
}

// ---------------------------------------------------------------------------
extern "C" void kernel_launch(void* const* d_in, const int* in_sizes, int n_in,
                              void* d_out, int out_size, void* d_ws, size_t ws_size,
                              hipStream_t stream)
{
    const float* x    = (const float*)d_in[0];
    const int*   ei   = (const int*)d_in[1];
    const int*   batch= (const int*)d_in[2];
    const float* w1l  = (const float*)d_in[3];
    const float* w1r  = (const float*)d_in[4];
    const float* att1 = (const float*)d_in[5];
    const float* b1   = (const float*)d_in[6];
    const float* w2l  = (const float*)d_in[7];
    const float* w2r  = (const float*)d_in[8];
    const float* att2 = (const float*)d_in[9];
    const float* b2   = (const float*)d_in[10];
    const float* w3l  = (const float*)d_in[11];
    const float* w3r  = (const float*)d_in[12];
    const float* att3 = (const float*)d_in[13];
    const float* b3   = (const float*)d_in[14];
    const float* outw = (const float*)d_in[15];
    const float* outb = (const float*)d_in[16];

    const int N   = in_sizes[2];
    const int E   = in_sizes[1] / 2;
    const int E2  = E + N;
    const int G   = 256;
    const int FIN = in_sizes[0] / N;    // 128
    const int* src = ei;
    const int* dst = ei + E;

    char* ws = (char*)d_ws;
    size_t off = 0;
    auto alloc = [&](size_t bytes) -> void* {
        void* p = ws + off;
        off = (off + bytes + 255) & ~(size_t)255;
        return p;
    };
    __hip_bfloat16* xlb   = (__hip_bfloat16*)alloc((size_t)N * 256 * 2);
    __hip_bfloat16* xrb   = (__hip_bfloat16*)alloc((size_t)N * 256 * 2);
    __hip_bfloat16* xb    = (__hip_bfloat16*)alloc((size_t)N * 128 * 2);
    __hip_bfloat16* hAb   = (__hip_bfloat16*)alloc((size_t)N * 256 * 2);
    __hip_bfloat16* hBb   = (__hip_bfloat16*)alloc((size_t)N * 128 * 2);
    float*          h3    = (float*)alloc((size_t)N * 64 * 4);
    int*            rowptr= (int*)alloc((size_t)(N + 1) * 4);
    int*            deg   = (int*)alloc((size_t)N * 4);
    int*            cursor= (int*)alloc((size_t)N * 4);
    int*            esrc  = (int*)alloc((size_t)E2 * 4);
    unsigned*       gmaxu = (unsigned*)alloc((size_t)G * 64 * 4);
    float*          gsum  = (float*)alloc((size_t)G * 64 * 4);
    float*          gcnt  = (float*)alloc((size_t)G * 4);
    __hip_bfloat16* w1lb  = (__hip_bfloat16*)alloc(256 * 128 * 2);
    __hip_bfloat16* w1rb  = (__hip_bfloat16*)alloc(256 * 128 * 2);
    __hip_bfloat16* w2lb  = (__hip_bfloat16*)alloc(128 * 256 * 2);
    __hip_bfloat16* w2rb  = (__hip_bfloat16*)alloc(128 * 256 * 2);
    __hip_bfloat16* w3lb  = (__hip_bfloat16*)alloc(64 * 128 * 2);
    __hip_bfloat16* w3rb  = (__hip_bfloat16*)alloc(64 * 128 * 2);

    hipMemsetAsync(deg,    0, (size_t)N * 4, stream);
    hipMemsetAsync(cursor, 0, (size_t)N * 4, stream);
    hipMemsetAsync(gsum,   0, (size_t)G * 64 * 4, stream);
    hipMemsetAsync(gcnt,   0, (size_t)G * 4, stream);
    fillu_k<<<(G * 64 + 255) / 256, 256, 0, stream>>>(gmaxu, 0x00800000u, G * 64);

    // conversions
    const int s1 = 256 * 128, s2 = 128 * 256, s3 = 64 * 128;
    const int wtot = 2 * s1 + 2 * s2 + 2 * s3;
    f2b_k<<<((size_t)N * 128 / 4 + 255) / 256, 256, 0, stream>>>(x, xb, N * 128);
    f2b6_k<<<(wtot / 4 + 255) / 256, 256, 0, stream>>>(
        w1l, w1r, w2l, w2r, w3l, w3r, w1lb, w1rb, w2lb, w2rb, w3lb, w3rb, s1, s2, s3);

    // CSR
    const int eb = (E2 + 255) / 256;
    hist_k<<<eb, 256, 0, stream>>>(dst, E, N, deg);
    scan_k<<<1, 1024, 0, stream>>>(deg, rowptr, N);
    scatter_k<<<eb, 256, 0, stream>>>(src, dst, E, N, rowptr, cursor, esrc);

    const int gx  = (N / 16 + 3) / 4;        // 16-row wave strips, 4 waves/block
    const int nwb = (N * 64 + 255) / 256;    // one wave per node

    // ---- layer 1: K=128 -> H=4, HD=256
    gemm_mfma<16><<<dim3(gx, 2), 256, 0, stream>>>(xb, w1lb, w1rb, xlb, xrb, N, FIN);
    fused_agg_k<4, true><<<nwb, 256, 0, stream>>>(xlb, xrb, rowptr, esrc, att1, b1, hAb, N, 0.01f);

    // ---- layer 2: K=256 -> H=2, HD=128
    gemm_mfma<8><<<dim3(gx, 2), 256, 0, stream>>>(hAb, w2lb, w2rb, xlb, xrb, N, 256);
    fused_agg_k<2, true><<<nwb, 256, 0, stream>>>(xlb, xrb, rowptr, esrc, att2, b2, hBb, N, 0.01f);

    // ---- layer 3: K=128 -> H=1, HD=64
    gemm_mfma<4><<<dim3(gx, 2), 256, 0, stream>>>(hBb, w3lb, w3rb, xlb, xrb, N, 128);
    fused_agg_k<1, false><<<nwb, 256, 0, stream>>>(xlb, xrb, rowptr, esrc, att3, b3, h3, N, 0.01f);

    // ---- pooling + head
    const int pb = (N / 16 + 3) / 4;
    pool_k<<<pb, 256, 0, stream>>>(h3, batch, N, gmaxu, gsum, gcnt);
    final_k<<<G, 128, 0, stream>>>(gmaxu, gsum, gcnt, outw, outb,
                                   (float*)d_out, (float*)d_out + G * 2);
}

// Round 4
// 496.440 us; speedup vs baseline: 2.4795x; 1.1504x over previous
//
#include <hip/hip_runtime.h>
#include <hip/hip_bf16.h>
#include <cfloat>
#include <cstdint>

// ---------------------------------------------------------------------------
// GATv2 x3 + global max/mean pool + linear head.
// Round 3: no-max softmax (logits bounded; exp-overflow impossible) ->
// loop-carried chain removed, unroll-2 gathers; packed-f32 (v_pk_*) edge math;
// one init kernel; cursor-free scatter; wave-shuffle scan.
// ---------------------------------------------------------------------------

typedef __attribute__((ext_vector_type(8))) short bf16x8;
typedef __attribute__((ext_vector_type(4))) float f32x4;
typedef __attribute__((ext_vector_type(2))) float v2f;
typedef __attribute__((ext_vector_type(4))) unsigned short us4;
typedef __attribute__((ext_vector_type(2))) unsigned short us2;

__device__ __forceinline__ float bf2f(unsigned short u) {
    return __uint_as_float((unsigned)u << 16);
}
__device__ __forceinline__ unsigned short f2bf(float f) {   // RNE
    unsigned u = __float_as_uint(f);
    u += 0x7FFFu + ((u >> 16) & 1u);
    return (unsigned short)(u >> 16);
}
__device__ __forceinline__ v2f unpack2(unsigned d) {        // [lo,hi] bf16 -> f32
    v2f r;
    r.x = __uint_as_float(d << 16);
    r.y = __uint_as_float(d & 0xffff0000u);
    return r;
}

// ---------------------------------------------------------------------------
// fp32 -> bf16 conversion
// ---------------------------------------------------------------------------
__global__ void f2b_k(const float* __restrict__ src, __hip_bfloat16* __restrict__ dst, int n)
{
    int i = (blockIdx.x * blockDim.x + threadIdx.x) * 4;
    if (i >= n) return;
    float4 v = *(const float4*)(src + i);
    us4 o = {f2bf(v.x), f2bf(v.y), f2bf(v.z), f2bf(v.w)};
    *(us4*)((unsigned short*)dst + i) = o;
}

__global__ void f2b6_k(const float* p0, const float* p1, const float* p2,
                       const float* p3, const float* p4, const float* p5,
                       __hip_bfloat16* d0, __hip_bfloat16* d1, __hip_bfloat16* d2,
                       __hip_bfloat16* d3, __hip_bfloat16* d4, __hip_bfloat16* d5,
                       int s01, int s23, int s45)
{
    int i = (blockIdx.x * blockDim.x + threadIdx.x) * 4;
    const float* s; __hip_bfloat16* d; int off;
    int t0 = 2 * s01, t1 = t0 + 2 * s23, t2 = t1 + 2 * s45;
    if (i < t0)      { int j = i;        s = (j < s01) ? p0 : p1; d = (j < s01) ? d0 : d1; off = j % s01; }
    else if (i < t1) { int j = i - t0;   s = (j < s23) ? p2 : p3; d = (j < s23) ? d2 : d3; off = j % s23; }
    else if (i < t2) { int j = i - t1;   s = (j < s45) ? p4 : p5; d = (j < s45) ? d4 : d5; off = j % s45; }
    else return;
    float4 v = *(const float4*)(s + off);
    us4 o = {f2bf(v.x), f2bf(v.y), f2bf(v.z), f2bf(v.w)};
    *(us4*)((unsigned short*)d + off) = o;
}

// ---------------------------------------------------------------------------
// init: deg=0, gsum=0, gcnt=0, gmaxu=enc(-FLT_MAX)
// ---------------------------------------------------------------------------
__global__ void init_k(int* __restrict__ deg, float* __restrict__ gsum,
                       float* __restrict__ gcnt, unsigned* __restrict__ gmaxu,
                       int N, int G)
{
    int i = blockIdx.x * blockDim.x + threadIdx.x;
    int stride = gridDim.x * blockDim.x;
    for (int k = i; k < N; k += stride) deg[k] = 0;
    for (int k = i; k < G * 64; k += stride) { gsum[k] = 0.f; gmaxu[k] = 0x00800000u; }
    for (int k = i; k < G; k += stride) gcnt[k] = 0.f;
}

// ---------------------------------------------------------------------------
// bf16 MFMA GEMM: C = A @ W^T, C written as bf16.  One wave: 16 x (NT*16).
// blockIdx.y selects (Wl,Cl) vs (Wr,Cr).
// ---------------------------------------------------------------------------
template<int NT>
__global__ __launch_bounds__(256) void gemm_mfma(
    const __hip_bfloat16* __restrict__ A,
    const __hip_bfloat16* __restrict__ Wl, const __hip_bfloat16* __restrict__ Wr,
    __hip_bfloat16* __restrict__ Cl, __hip_bfloat16* __restrict__ Cr,
    int M, int K)
{
    const int wave = threadIdx.x >> 6, lane = threadIdx.x & 63;
    const int m0 = (blockIdx.x * 4 + wave) * 16;
    if (m0 >= M) return;
    const __hip_bfloat16* W = blockIdx.y ? Wr : Wl;
    __hip_bfloat16* C = blockIdx.y ? Cr : Cl;
    const int r16  = lane & 15;
    const int quad = lane >> 4;
    const __hip_bfloat16* Aptr = A + (size_t)(m0 + r16) * K + quad * 8;

    f32x4 acc[NT];
    #pragma unroll
    for (int n = 0; n < NT; ++n) acc[n] = (f32x4){0.f, 0.f, 0.f, 0.f};

    for (int k0 = 0; k0 < K; k0 += 32) {
        bf16x8 a = *(const bf16x8*)(Aptr + k0);
        #pragma unroll
        for (int n = 0; n < NT; ++n) {
            bf16x8 b = *(const bf16x8*)(W + (size_t)(n * 16 + r16) * K + k0 + quad * 8);
            acc[n] = __builtin_amdgcn_mfma_f32_16x16x32_bf16(a, b, acc[n], 0, 0, 0);
        }
    }
    const int Nout = NT * 16;
    unsigned short* Cu = (unsigned short*)C;
    #pragma unroll
    for (int n = 0; n < NT; ++n)
        #pragma unroll
        for (int r = 0; r < 4; ++r) {
            int row = m0 + quad * 4 + r;          // C/D: col=lane&15, row=quad*4+reg
            Cu[(size_t)row * Nout + n * 16 + r16] = f2bf(acc[n][r]);
        }
}

// ---------------------------------------------------------------------------
// CSR build (grouped by dst). e < E: (src[e], dst[e]); e >= E: self loop.
// ---------------------------------------------------------------------------
__global__ void hist_k(const int* __restrict__ dst, int E, int N, int* __restrict__ deg)
{
    int e = blockIdx.x * blockDim.x + threadIdx.x;
    if (e >= E + N) return;
    int i = (e < E) ? dst[e] : (e - E);
    atomicAdd(&deg[i], 1);
}

// wave-shuffle scan: 1024 threads, 16 waves, 8 elems/thread per tile
__global__ __launch_bounds__(1024) void scan_k(const int* __restrict__ deg,
                                               int* __restrict__ rowptr, int N)
{
    __shared__ int parts[16];
    __shared__ int carryS;
    const int t = threadIdx.x, lane = t & 63, wv = t >> 6;
    if (t == 0) { carryS = 0; rowptr[0] = 0; }
    __syncthreads();
    for (int base = 0; base < N; base += 8192) {
        int v[8];
        int run = 0;
        #pragma unroll
        for (int i = 0; i < 8; ++i) {
            int idx = base + t * 8 + i;
            run += (idx < N) ? deg[idx] : 0;
            v[i] = run;
        }
        // wave-inclusive scan of run
        int x = run;
        #pragma unroll
        for (int off = 1; off < 64; off <<= 1) {
            int y = __shfl_up(x, off, 64);
            if (lane >= off) x += y;
        }
        int excl = x - run;
        if (lane == 63) parts[wv] = x;
        __syncthreads();
        if (wv == 0 && lane < 16) {
            int p = parts[lane];
            int xx = p;
            #pragma unroll
            for (int off = 1; off < 16; off <<= 1) {
                int y = __shfl_up(xx, off, 64);
                if (lane >= off) xx += y;
            }
            parts[lane] = xx - p;   // exclusive
        }
        __syncthreads();
        int wexcl = parts[wv];
        int pre = carryS + wexcl + excl;
        #pragma unroll
        for (int i = 0; i < 8; ++i) {
            int idx = base + t * 8 + i;
            if (idx < N) rowptr[idx + 1] = pre + v[i];
        }
        __syncthreads();
        if (t == 1023) carryS += wexcl + x;
        __syncthreads();
    }
}

// scatter consumes deg (atomic countdown) -> no cursor buffer
__global__ void scatter_k(const int* __restrict__ src, const int* __restrict__ dst,
                          int E, int N, const int* __restrict__ rowptr,
                          int* __restrict__ deg, int* __restrict__ esrc)
{
    int e = blockIdx.x * blockDim.x + threadIdx.x;
    if (e >= E + N) return;
    int i = (e < E) ? dst[e] : (e - E);
    int j = (e < E) ? src[e] : (e - E);
    int old = atomicAdd(&deg[i], -1);
    esrc[rowptr[i] + old - 1] = j;
}

// ---------------------------------------------------------------------------
// Fused GATv2 layer, no-max softmax (logits bounded: sigma~1.3, |e|<<88).
// One wave per dst node; lane holds H consecutive features. Unroll-2 edges.
// ---------------------------------------------------------------------------
template<int P>
__device__ __forceinline__ float edge_logit(const v2f* xv, const v2f* xrv, const v2f* attv)
{
    v2f d = {0.f, 0.f};
    #pragma unroll
    for (int p = 0; p < P; ++p) {
        v2f z = xv[p] + xrv[p];
        v2f l = __builtin_elementwise_max(z, (v2f){0.f, 0.f});
        l += (v2f){0.2f, 0.2f} * __builtin_elementwise_min(z, (v2f){0.f, 0.f});
        d += l * attv[p];
    }
    return d.x + d.y;
}

template<int H, bool BF16OUT>
__global__ __launch_bounds__(256) void fused_agg_k(
    const unsigned short* __restrict__ xl, const unsigned short* __restrict__ xr,
    const int* __restrict__ rowptr, const int* __restrict__ esrc,
    const float* __restrict__ att, const float* __restrict__ bias,
    void* __restrict__ outv, int N, float oslope)
{
    const int wid  = (blockIdx.x * blockDim.x + threadIdx.x) >> 6;
    const int lane = threadIdx.x & 63;
    if (wid >= N) return;
    constexpr int HD = H * 64;
    constexpr int GS = 64 / H;
    const int f0 = lane * H;
    const int r0 = rowptr[wid];
    const int r1 = rowptr[wid + 1];

    if constexpr (H >= 2) {
        constexpr int P = H / 2;
        v2f xrv[P], attv[P], acc[P];
        if constexpr (H == 4) {
            uint2 d = *(const uint2*)(xr + (size_t)wid * HD + f0);
            xrv[0] = unpack2(d.x); xrv[1] = unpack2(d.y);
        } else {
            unsigned d = *(const unsigned*)(xr + (size_t)wid * HD + f0);
            xrv[0] = unpack2(d);
        }
        #pragma unroll
        for (int p = 0; p < P; ++p) {
            attv[p] = *(const v2f*)(att + f0 + 2 * p);
            acc[p] = (v2f){0.f, 0.f};
        }

        float s = 0.f;
        int k = r0;
        for (; k + 2 <= r1; k += 2) {
            int j0 = esrc[k], j1 = esrc[k + 1];
            v2f x0[P], x1[P];
            if constexpr (H == 4) {
                uint2 a = *(const uint2*)(xl + (size_t)j0 * HD + f0);
                uint2 b = *(const uint2*)(xl + (size_t)j1 * HD + f0);
                x0[0] = unpack2(a.x); x0[1] = unpack2(a.y);
                x1[0] = unpack2(b.x); x1[1] = unpack2(b.y);
            } else {
                unsigned a = *(const unsigned*)(xl + (size_t)j0 * HD + f0);
                unsigned b = *(const unsigned*)(xl + (size_t)j1 * HD + f0);
                x0[0] = unpack2(a); x1[0] = unpack2(b);
            }
            float p0 = edge_logit<P>(x0, xrv, attv);
            float p1 = edge_logit<P>(x1, xrv, attv);
            #pragma unroll
            for (int off = 1; off < GS; off <<= 1) {
                p0 += __shfl_xor(p0, off, 64);
                p1 += __shfl_xor(p1, off, 64);
            }
            float w0 = __expf(p0), w1 = __expf(p1);
            s += w0 + w1;
            #pragma unroll
            for (int p = 0; p < P; ++p) {
                acc[p] += w0 * x0[p];
                acc[p] += w1 * x1[p];
            }
        }
        if (k < r1) {
            int j0 = esrc[k];
            v2f x0[P];
            if constexpr (H == 4) {
                uint2 a = *(const uint2*)(xl + (size_t)j0 * HD + f0);
                x0[0] = unpack2(a.x); x0[1] = unpack2(a.y);
            } else {
                unsigned a = *(const unsigned*)(xl + (size_t)j0 * HD + f0);
                x0[0] = unpack2(a);
            }
            float p0 = edge_logit<P>(x0, xrv, attv);
            #pragma unroll
            for (int off = 1; off < GS; off <<= 1)
                p0 += __shfl_xor(p0, off, 64);
            float w0 = __expf(p0);
            s += w0;
            #pragma unroll
            for (int p = 0; p < P; ++p) acc[p] += w0 * x0[p];
        }

        float rs = 1.f / (s + 1e-16f);
        unsigned short o[H];
        float of[H];
        #pragma unroll
        for (int p = 0; p < P; ++p) {
            v2f b2 = *(const v2f*)(bias + f0 + 2 * p);
            v2f v = acc[p] * rs + b2;
            float vx = (v.x > 0.f) ? v.x : oslope * v.x;
            float vy = (v.y > 0.f) ? v.y : oslope * v.y;
            if constexpr (BF16OUT) { o[2 * p] = f2bf(vx); o[2 * p + 1] = f2bf(vy); }
            else                   { of[2 * p] = vx; of[2 * p + 1] = vy; }
        }
        if constexpr (BF16OUT) {
            unsigned short* ou = (unsigned short*)outv;
            if constexpr (H == 4) *(us4*)(ou + (size_t)wid * HD + f0) = *(us4*)o;
            else                  *(us2*)(ou + (size_t)wid * HD + f0) = *(us2*)o;
        } else {
            float* off_ = (float*)outv;
            #pragma unroll
            for (int i = 0; i < H; ++i) off_[(size_t)wid * HD + f0 + i] = of[i];
        }
    } else {
        // H == 1: scalar path, GS = 64
        float xrv  = bf2f(xr[(size_t)wid * 64 + lane]);
        float attv = att[lane];
        float s = 0.f, acc = 0.f;
        int k = r0;
        for (; k + 2 <= r1; k += 2) {
            int j0 = esrc[k], j1 = esrc[k + 1];
            float x0 = bf2f(xl[(size_t)j0 * 64 + lane]);
            float x1 = bf2f(xl[(size_t)j1 * 64 + lane]);
            float z0 = x0 + xrv, z1 = x1 + xrv;
            float l0 = fmaxf(z0, 0.f) + 0.2f * fminf(z0, 0.f);
            float l1 = fmaxf(z1, 0.f) + 0.2f * fminf(z1, 0.f);
            float p0 = l0 * attv, p1 = l1 * attv;
            #pragma unroll
            for (int off = 1; off < 64; off <<= 1) {
                p0 += __shfl_xor(p0, off, 64);
                p1 += __shfl_xor(p1, off, 64);
            }
            float w0 = __expf(p0), w1 = __expf(p1);
            s += w0 + w1;
            acc += w0 * x0 + w1 * x1;
        }
        if (k < r1) {
            int j0 = esrc[k];
            float x0 = bf2f(xl[(size_t)j0 * 64 + lane]);
            float z0 = x0 + xrv;
            float l0 = fmaxf(z0, 0.f) + 0.2f * fminf(z0, 0.f);
            float p0 = l0 * attv;
            #pragma unroll
            for (int off = 1; off < 64; off <<= 1)
                p0 += __shfl_xor(p0, off, 64);
            float w0 = __expf(p0);
            s += w0;
            acc += w0 * x0;
        }
        float rs = 1.f / (s + 1e-16f);
        float v = acc * rs + bias[lane];
        v = (v > 0.f) ? v : oslope * v;
        if constexpr (BF16OUT)
            ((unsigned short*)outv)[(size_t)wid * 64 + lane] = f2bf(v);
        else
            ((float*)outv)[(size_t)wid * 64 + lane] = v;
    }
}

// ---------------------------------------------------------------------------
// Pooling (batch_index sorted -> run aggregation, atomics at boundaries only)
// ---------------------------------------------------------------------------
__device__ __forceinline__ unsigned fenc(float f) {
    unsigned u = __float_as_uint(f);
    return (u & 0x80000000u) ? ~u : (u | 0x80000000u);
}
__device__ __forceinline__ float fdec(unsigned u) {
    return __uint_as_float((u & 0x80000000u) ? (u & 0x7fffffffu) : ~u);
}

__global__ __launch_bounds__(256) void pool_k(
    const float* __restrict__ h, const int* __restrict__ batch, int N,
    unsigned* __restrict__ gmaxu, float* __restrict__ gsum, float* __restrict__ gcnt)
{
    const int wid  = (blockIdx.x * blockDim.x + threadIdx.x) >> 6;
    const int lane = threadIdx.x & 63;
    const int n0 = wid * 16;
    if (n0 >= N) return;
    int gcur = batch[n0];
    float vmax = -3.4e38f, vsum = 0.f;
    int cnt = 0;
    #pragma unroll 4
    for (int i = 0; i < 16; ++i) {
        int n = n0 + i;
        if (n >= N) break;
        int g = batch[n];
        if (g != gcur) {
            atomicMax(&gmaxu[gcur * 64 + lane], fenc(vmax));
            atomicAdd(&gsum[gcur * 64 + lane], vsum);
            if (lane == 0) atomicAdd(&gcnt[gcur], (float)cnt);
            gcur = g; vmax = -3.4e38f; vsum = 0.f; cnt = 0;
        }
        float v = h[(size_t)n * 64 + lane];
        vmax = fmaxf(vmax, v);
        vsum += v;
        cnt++;
    }
    atomicMax(&gmaxu[gcur * 64 + lane], fenc(vmax));
    atomicAdd(&gsum[gcur * 64 + lane], vsum);
    if (lane == 0) atomicAdd(&gcnt[gcur], (float)cnt);
}

__global__ __launch_bounds__(128) void final_k(
    const unsigned* __restrict__ gmaxu, const float* __restrict__ gsum,
    const float* __restrict__ gcnt, const float* __restrict__ out_w,
    const float* __restrict__ out_b, float* __restrict__ out,
    float* __restrict__ hid_out)
{
    const int g = blockIdx.x;
    const int t = threadIdx.x;
    __shared__ float hid[128];
    float v;
    if (t < 64) {
        v = fdec(gmaxu[g * 64 + t]);
    } else {
        float c = fmaxf(gcnt[g], 1.f);
        v = gsum[g * 64 + (t - 64)] / c;
    }
    hid[t] = v;
    hid_out[(size_t)g * 128 + t] = v;
    __syncthreads();
    const int w = t >> 6, lane = t & 63;
    float p = hid[lane] * out_w[w * 128 + lane] + hid[lane + 64] * out_w[w * 128 + 64 + lane];
    #pragma unroll
    for (int off = 32; off >= 1; off >>= 1) p += __shfl_xor(p, off, 64);
    if (lane == 0) out[g * 2 + w] = p + out_b[w];
}

// ---------------------------------------------------------------------------
extern "C" void kernel_launch(void* const* d_in, const int* in_sizes, int n_in,
                              void* d_out, int out_size, void* d_ws, size_t ws_size,
                              hipStream_t stream)
{
    const float* x    = (const float*)d_in[0];
    const int*   ei   = (const int*)d_in[1];
    const int*   batch= (const int*)d_in[2];
    const float* w1l  = (const float*)d_in[3];
    const float* w1r  = (const float*)d_in[4];
    const float* att1 = (const float*)d_in[5];
    const float* b1   = (const float*)d_in[6];
    const float* w2l  = (const float*)d_in[7];
    const float* w2r  = (const float*)d_in[8];
    const float* att2 = (const float*)d_in[9];
    const float* b2   = (const float*)d_in[10];
    const float* w3l  = (const float*)d_in[11];
    const float* w3r  = (const float*)d_in[12];
    const float* att3 = (const float*)d_in[13];
    const float* b3   = (const float*)d_in[14];
    const float* outw = (const float*)d_in[15];
    const float* outb = (const float*)d_in[16];

    const int N   = in_sizes[2];
    const int E   = in_sizes[1] / 2;
    const int E2  = E + N;
    const int G   = 256;
    const int FIN = in_sizes[0] / N;    // 128
    const int* src = ei;
    const int* dst = ei + E;

    char* ws = (char*)d_ws;
    size_t off = 0;
    auto alloc = [&](size_t bytes) -> void* {
        void* p = ws + off;
        off = (off + bytes + 255) & ~(size_t)255;
        return p;
    };
    unsigned short* xlb   = (unsigned short*)alloc((size_t)N * 256 * 2);
    unsigned short* xrb   = (unsigned short*)alloc((size_t)N * 256 * 2);
    __hip_bfloat16* xb    = (__hip_bfloat16*)alloc((size_t)N * 128 * 2);
    __hip_bfloat16* hAb   = (__hip_bfloat16*)alloc((size_t)N * 256 * 2);
    __hip_bfloat16* hBb   = (__hip_bfloat16*)alloc((size_t)N * 128 * 2);
    float*          h3    = (float*)alloc((size_t)N * 64 * 4);
    int*            rowptr= (int*)alloc((size_t)(N + 1) * 4);
    int*            deg   = (int*)alloc((size_t)N * 4);
    int*            esrc  = (int*)alloc((size_t)E2 * 4);
    unsigned*       gmaxu = (unsigned*)alloc((size_t)G * 64 * 4);
    float*          gsum  = (float*)alloc((size_t)G * 64 * 4);
    float*          gcnt  = (float*)alloc((size_t)G * 4);
    __hip_bfloat16* w1lb  = (__hip_bfloat16*)alloc(256 * 128 * 2);
    __hip_bfloat16* w1rb  = (__hip_bfloat16*)alloc(256 * 128 * 2);
    __hip_bfloat16* w2lb  = (__hip_bfloat16*)alloc(128 * 256 * 2);
    __hip_bfloat16* w2rb  = (__hip_bfloat16*)alloc(128 * 256 * 2);
    __hip_bfloat16* w3lb  = (__hip_bfloat16*)alloc(64 * 128 * 2);
    __hip_bfloat16* w3rb  = (__hip_bfloat16*)alloc(64 * 128 * 2);

    init_k<<<(N + 255) / 256, 256, 0, stream>>>(deg, gsum, gcnt, gmaxu, N, G);

    // conversions
    const int s1 = 256 * 128, s2 = 128 * 256, s3 = 64 * 128;
    const int wtot = 2 * s1 + 2 * s2 + 2 * s3;
    f2b_k<<<((size_t)N * 128 / 4 + 255) / 256, 256, 0, stream>>>(x, xb, N * 128);
    f2b6_k<<<(wtot / 4 + 255) / 256, 256, 0, stream>>>(
        w1l, w1r, w2l, w2r, w3l, w3r, w1lb, w1rb, w2lb, w2rb, w3lb, w3rb, s1, s2, s3);

    // CSR
    const int eb = (E2 + 255) / 256;
    hist_k<<<eb, 256, 0, stream>>>(dst, E, N, deg);
    scan_k<<<1, 1024, 0, stream>>>(deg, rowptr, N);
    scatter_k<<<eb, 256, 0, stream>>>(src, dst, E, N, rowptr, deg, esrc);

    const int gx  = (N / 16 + 3) / 4;        // 16-row wave strips, 4 waves/block
    const int nwb = (N * 64 + 255) / 256;    // one wave per node

    // ---- layer 1: K=128 -> H=4, HD=256
    gemm_mfma<16><<<dim3(gx, 2), 256, 0, stream>>>(xb, w1lb, w1rb,
        (__hip_bfloat16*)xlb, (__hip_bfloat16*)xrb, N, FIN);
    fused_agg_k<4, true><<<nwb, 256, 0, stream>>>(xlb, xrb, rowptr, esrc, att1, b1, hAb, N, 0.01f);

    // ---- layer 2: K=256 -> H=2, HD=128
    gemm_mfma<8><<<dim3(gx, 2), 256, 0, stream>>>(hAb, w2lb, w2rb,
        (__hip_bfloat16*)xlb, (__hip_bfloat16*)xrb, N, 256);
    fused_agg_k<2, true><<<nwb, 256, 0, stream>>>(xlb, xrb, rowptr, esrc, att2, b2, hBb, N, 0.01f);

    // ---- layer 3: K=128 -> H=1, HD=64
    gemm_mfma<4><<<dim3(gx, 2), 256, 0, stream>>>(hBb, w3lb, w3rb,
        (__hip_bfloat16*)xlb, (__hip_bfloat16*)xrb, N, 128);
    fused_agg_k<1, false><<<nwb, 256, 0, stream>>>(xlb, xrb, rowptr, esrc, att3, b3, h3, N, 0.01f);

    // ---- pooling + head
    const int pb = (N / 16 + 3) / 4;
    pool_k<<<pb, 256, 0, stream>>>(h3, batch, N, gmaxu, gsum, gcnt);
    final_k<<<G, 128, 0, stream>>>(gmaxu, gsum, gcnt, outw, outb,
                                   (float*)d_out, (float*)d_out + G * 2);
}

// Round 5
// 446.615 us; speedup vs baseline: 2.7561x; 1.1116x over previous
//
#include <hip/hip_runtime.h>
#include <hip/hip_bf16.h>
#include <cfloat>
#include <cstdint>

// ---------------------------------------------------------------------------
// GATv2 x3 + global max/mean pool + linear head.
// Round 4: GEMM restructured for arithmetic intensity — each wave computes a
// 64-row x (NT*16)-col tile (4 m-tiles reuse every B fragment), compile-time
// K fully known, unroll-2 k-loop for load overlap. Fixes the 3.5%-MfmaUtil
// latency-bound GEMM of round 3.
// ---------------------------------------------------------------------------

typedef __attribute__((ext_vector_type(8))) short bf16x8;
typedef __attribute__((ext_vector_type(4))) float f32x4;
typedef __attribute__((ext_vector_type(2))) float v2f;
typedef __attribute__((ext_vector_type(4))) unsigned short us4;
typedef __attribute__((ext_vector_type(2))) unsigned short us2;

__device__ __forceinline__ float bf2f(unsigned short u) {
    return __uint_as_float((unsigned)u << 16);
}
__device__ __forceinline__ unsigned short f2bf(float f) {   // RNE
    unsigned u = __float_as_uint(f);
    u += 0x7FFFu + ((u >> 16) & 1u);
    return (unsigned short)(u >> 16);
}
__device__ __forceinline__ v2f unpack2(unsigned d) {        // [lo,hi] bf16 -> f32
    v2f r;
    r.x = __uint_as_float(d << 16);
    r.y = __uint_as_float(d & 0xffff0000u);
    return r;
}

// ---------------------------------------------------------------------------
// fp32 -> bf16 conversion
// ---------------------------------------------------------------------------
__global__ void f2b_k(const float* __restrict__ src, __hip_bfloat16* __restrict__ dst, int n)
{
    int i = (blockIdx.x * blockDim.x + threadIdx.x) * 4;
    if (i >= n) return;
    float4 v = *(const float4*)(src + i);
    us4 o = {f2bf(v.x), f2bf(v.y), f2bf(v.z), f2bf(v.w)};
    *(us4*)((unsigned short*)dst + i) = o;
}

__global__ void f2b6_k(const float* p0, const float* p1, const float* p2,
                       const float* p3, const float* p4, const float* p5,
                       __hip_bfloat16* d0, __hip_bfloat16* d1, __hip_bfloat16* d2,
                       __hip_bfloat16* d3, __hip_bfloat16* d4, __hip_bfloat16* d5,
                       int s01, int s23, int s45)
{
    int i = (blockIdx.x * blockDim.x + threadIdx.x) * 4;
    const float* s; __hip_bfloat16* d; int off;
    int t0 = 2 * s01, t1 = t0 + 2 * s23, t2 = t1 + 2 * s45;
    if (i < t0)      { int j = i;        s = (j < s01) ? p0 : p1; d = (j < s01) ? d0 : d1; off = j % s01; }
    else if (i < t1) { int j = i - t0;   s = (j < s23) ? p2 : p3; d = (j < s23) ? d2 : d3; off = j % s23; }
    else if (i < t2) { int j = i - t1;   s = (j < s45) ? p4 : p5; d = (j < s45) ? d4 : d5; off = j % s45; }
    else return;
    float4 v = *(const float4*)(s + off);
    us4 o = {f2bf(v.x), f2bf(v.y), f2bf(v.z), f2bf(v.w)};
    *(us4*)((unsigned short*)d + off) = o;
}

// ---------------------------------------------------------------------------
// init: deg=0, gsum=0, gcnt=0, gmaxu=enc(-FLT_MAX)
// ---------------------------------------------------------------------------
__global__ void init_k(int* __restrict__ deg, float* __restrict__ gsum,
                       float* __restrict__ gcnt, unsigned* __restrict__ gmaxu,
                       int N, int G)
{
    int i = blockIdx.x * blockDim.x + threadIdx.x;
    int stride = gridDim.x * blockDim.x;
    for (int k = i; k < N; k += stride) deg[k] = 0;
    for (int k = i; k < G * 64; k += stride) { gsum[k] = 0.f; gmaxu[k] = 0x00800000u; }
    for (int k = i; k < G; k += stride) gcnt[k] = 0.f;
}

// ---------------------------------------------------------------------------
// bf16 MFMA GEMM: C = A @ W^T, C written as bf16.
// One wave: 64 rows x (NT*16) cols; 4 m-tiles reuse each B fragment (MFMA:
// load = 32:12 per k-step).  K = KT*32 compile-time.  grid = (m-blocks of
// 256 rows, {l,r}, n-blocks of NT*16 cols).
// ---------------------------------------------------------------------------
template<int NT, int KT>
__global__ __launch_bounds__(256) void gemm_mfma(
    const __hip_bfloat16* __restrict__ A,
    const __hip_bfloat16* __restrict__ Wl, const __hip_bfloat16* __restrict__ Wr,
    __hip_bfloat16* __restrict__ Cl, __hip_bfloat16* __restrict__ Cr,
    int M, int Nout)
{
    constexpr int K = KT * 32;
    const int wave = threadIdx.x >> 6, lane = threadIdx.x & 63;
    const int m0 = (blockIdx.x * 4 + wave) * 64;
    if (m0 >= M) return;
    const __hip_bfloat16* W = blockIdx.y ? Wr : Wl;
    __hip_bfloat16* C = blockIdx.y ? Cr : Cl;
    const int nbase = blockIdx.z * NT * 16;
    const int r16  = lane & 15;
    const int quad = lane >> 4;
    const int kq = quad * 8;

    f32x4 acc[4][NT];
    #pragma unroll
    for (int mt = 0; mt < 4; ++mt)
        #pragma unroll
        for (int n = 0; n < NT; ++n) acc[mt][n] = (f32x4){0.f, 0.f, 0.f, 0.f};

    // row addresses (clamped for the ragged final strip; stores are guarded)
    const __hip_bfloat16* Arow[4];
    #pragma unroll
    for (int mt = 0; mt < 4; ++mt) {
        int r = m0 + mt * 16 + r16;
        r = (r < M) ? r : (M - 1);
        Arow[mt] = A + (size_t)r * K + kq;
    }
    const __hip_bfloat16* Wbase = W + (size_t)(nbase + r16) * K + kq;

    #pragma unroll 2
    for (int kt = 0; kt < KT; ++kt) {
        const int k0 = kt * 32;
        bf16x8 a[4];
        #pragma unroll
        for (int mt = 0; mt < 4; ++mt)
            a[mt] = *(const bf16x8*)(Arow[mt] + k0);
        #pragma unroll
        for (int n = 0; n < NT; ++n) {
            bf16x8 b = *(const bf16x8*)(Wbase + (size_t)n * 16 * K + k0);
            #pragma unroll
            for (int mt = 0; mt < 4; ++mt)
                acc[mt][n] = __builtin_amdgcn_mfma_f32_16x16x32_bf16(a[mt], b, acc[mt][n], 0, 0, 0);
        }
    }

    unsigned short* Cu = (unsigned short*)C;
    #pragma unroll
    for (int mt = 0; mt < 4; ++mt)
        #pragma unroll
        for (int n = 0; n < NT; ++n)
            #pragma unroll
            for (int r = 0; r < 4; ++r) {
                int row = m0 + mt * 16 + quad * 4 + r;   // C/D: col=lane&15, row=quad*4+reg
                if (row < M)
                    Cu[(size_t)row * Nout + nbase + n * 16 + r16] = f2bf(acc[mt][n][r]);
            }
}

// ---------------------------------------------------------------------------
// CSR build (grouped by dst). e < E: (src[e], dst[e]); e >= E: self loop.
// ---------------------------------------------------------------------------
__global__ void hist_k(const int* __restrict__ dst, int E, int N, int* __restrict__ deg)
{
    int e = blockIdx.x * blockDim.x + threadIdx.x;
    if (e >= E + N) return;
    int i = (e < E) ? dst[e] : (e - E);
    atomicAdd(&deg[i], 1);
}

// wave-shuffle scan: 1024 threads, 16 waves, 8 elems/thread per tile
__global__ __launch_bounds__(1024) void scan_k(const int* __restrict__ deg,
                                               int* __restrict__ rowptr, int N)
{
    __shared__ int parts[16];
    __shared__ int carryS;
    const int t = threadIdx.x, lane = t & 63, wv = t >> 6;
    if (t == 0) { carryS = 0; rowptr[0] = 0; }
    __syncthreads();
    for (int base = 0; base < N; base += 8192) {
        int v[8];
        int run = 0;
        #pragma unroll
        for (int i = 0; i < 8; ++i) {
            int idx = base + t * 8 + i;
            run += (idx < N) ? deg[idx] : 0;
            v[i] = run;
        }
        int x = run;
        #pragma unroll
        for (int off = 1; off < 64; off <<= 1) {
            int y = __shfl_up(x, off, 64);
            if (lane >= off) x += y;
        }
        int excl = x - run;
        if (lane == 63) parts[wv] = x;
        __syncthreads();
        if (wv == 0 && lane < 16) {
            int p = parts[lane];
            int xx = p;
            #pragma unroll
            for (int off = 1; off < 16; off <<= 1) {
                int y = __shfl_up(xx, off, 64);
                if (lane >= off) xx += y;
            }
            parts[lane] = xx - p;   // exclusive
        }
        __syncthreads();
        int wexcl = parts[wv];
        int pre = carryS + wexcl + excl;
        #pragma unroll
        for (int i = 0; i < 8; ++i) {
            int idx = base + t * 8 + i;
            if (idx < N) rowptr[idx + 1] = pre + v[i];
        }
        __syncthreads();
        if (t == 1023) carryS += wexcl + x;
        __syncthreads();
    }
}

// scatter consumes deg (atomic countdown) -> no cursor buffer
__global__ void scatter_k(const int* __restrict__ src, const int* __restrict__ dst,
                          int E, int N, const int* __restrict__ rowptr,
                          int* __restrict__ deg, int* __restrict__ esrc)
{
    int e = blockIdx.x * blockDim.x + threadIdx.x;
    if (e >= E + N) return;
    int i = (e < E) ? dst[e] : (e - E);
    int j = (e < E) ? src[e] : (e - E);
    int old = atomicAdd(&deg[i], -1);
    esrc[rowptr[i] + old - 1] = j;
}

// ---------------------------------------------------------------------------
// Fused GATv2 layer, no-max softmax (logits bounded: sigma~1.3, |e|<<88).
// One wave per dst node; lane holds H consecutive features. Unroll-2 edges.
// ---------------------------------------------------------------------------
template<int P>
__device__ __forceinline__ float edge_logit(const v2f* xv, const v2f* xrv, const v2f* attv)
{
    v2f d = {0.f, 0.f};
    #pragma unroll
    for (int p = 0; p < P; ++p) {
        v2f z = xv[p] + xrv[p];
        v2f l = __builtin_elementwise_max(z, (v2f){0.f, 0.f});
        l += (v2f){0.2f, 0.2f} * __builtin_elementwise_min(z, (v2f){0.f, 0.f});
        d += l * attv[p];
    }
    return d.x + d.y;
}

template<int H, bool BF16OUT>
__global__ __launch_bounds__(256) void fused_agg_k(
    const unsigned short* __restrict__ xl, const unsigned short* __restrict__ xr,
    const int* __restrict__ rowptr, const int* __restrict__ esrc,
    const float* __restrict__ att, const float* __restrict__ bias,
    void* __restrict__ outv, int N, float oslope)
{
    const int wid  = (blockIdx.x * blockDim.x + threadIdx.x) >> 6;
    const int lane = threadIdx.x & 63;
    if (wid >= N) return;
    constexpr int HD = H * 64;
    constexpr int GS = 64 / H;
    const int f0 = lane * H;
    const int r0 = rowptr[wid];
    const int r1 = rowptr[wid + 1];

    if constexpr (H >= 2) {
        constexpr int P = H / 2;
        v2f xrv[P], attv[P], acc[P];
        if constexpr (H == 4) {
            uint2 d = *(const uint2*)(xr + (size_t)wid * HD + f0);
            xrv[0] = unpack2(d.x); xrv[1] = unpack2(d.y);
        } else {
            unsigned d = *(const unsigned*)(xr + (size_t)wid * HD + f0);
            xrv[0] = unpack2(d);
        }
        #pragma unroll
        for (int p = 0; p < P; ++p) {
            attv[p] = *(const v2f*)(att + f0 + 2 * p);
            acc[p] = (v2f){0.f, 0.f};
        }

        float s = 0.f;
        int k = r0;
        for (; k + 2 <= r1; k += 2) {
            int j0 = esrc[k], j1 = esrc[k + 1];
            v2f x0[P], x1[P];
            if constexpr (H == 4) {
                uint2 a = *(const uint2*)(xl + (size_t)j0 * HD + f0);
                uint2 b = *(const uint2*)(xl + (size_t)j1 * HD + f0);
                x0[0] = unpack2(a.x); x0[1] = unpack2(a.y);
                x1[0] = unpack2(b.x); x1[1] = unpack2(b.y);
            } else {
                unsigned a = *(const unsigned*)(xl + (size_t)j0 * HD + f0);
                unsigned b = *(const unsigned*)(xl + (size_t)j1 * HD + f0);
                x0[0] = unpack2(a); x1[0] = unpack2(b);
            }
            float p0 = edge_logit<P>(x0, xrv, attv);
            float p1 = edge_logit<P>(x1, xrv, attv);
            #pragma unroll
            for (int off = 1; off < GS; off <<= 1) {
                p0 += __shfl_xor(p0, off, 64);
                p1 += __shfl_xor(p1, off, 64);
            }
            float w0 = __expf(p0), w1 = __expf(p1);
            s += w0 + w1;
            #pragma unroll
            for (int p = 0; p < P; ++p) {
                acc[p] += w0 * x0[p];
                acc[p] += w1 * x1[p];
            }
        }
        if (k < r1) {
            int j0 = esrc[k];
            v2f x0[P];
            if constexpr (H == 4) {
                uint2 a = *(const uint2*)(xl + (size_t)j0 * HD + f0);
                x0[0] = unpack2(a.x); x0[1] = unpack2(a.y);
            } else {
                unsigned a = *(const unsigned*)(xl + (size_t)j0 * HD + f0);
                x0[0] = unpack2(a);
            }
            float p0 = edge_logit<P>(x0, xrv, attv);
            #pragma unroll
            for (int off = 1; off < GS; off <<= 1)
                p0 += __shfl_xor(p0, off, 64);
            float w0 = __expf(p0);
            s += w0;
            #pragma unroll
            for (int p = 0; p < P; ++p) acc[p] += w0 * x0[p];
        }

        float rs = 1.f / (s + 1e-16f);
        unsigned short o[H];
        float of[H];
        #pragma unroll
        for (int p = 0; p < P; ++p) {
            v2f b2 = *(const v2f*)(bias + f0 + 2 * p);
            v2f v = acc[p] * rs + b2;
            float vx = (v.x > 0.f) ? v.x : oslope * v.x;
            float vy = (v.y > 0.f) ? v.y : oslope * v.y;
            if constexpr (BF16OUT) { o[2 * p] = f2bf(vx); o[2 * p + 1] = f2bf(vy); }
            else                   { of[2 * p] = vx; of[2 * p + 1] = vy; }
        }
        if constexpr (BF16OUT) {
            unsigned short* ou = (unsigned short*)outv;
            if constexpr (H == 4) *(us4*)(ou + (size_t)wid * HD + f0) = *(us4*)o;
            else                  *(us2*)(ou + (size_t)wid * HD + f0) = *(us2*)o;
        } else {
            float* off_ = (float*)outv;
            #pragma unroll
            for (int i = 0; i < H; ++i) off_[(size_t)wid * HD + f0 + i] = of[i];
        }
    } else {
        float xrv  = bf2f(xr[(size_t)wid * 64 + lane]);
        float attv = att[lane];
        float s = 0.f, acc = 0.f;
        int k = r0;
        for (; k + 2 <= r1; k += 2) {
            int j0 = esrc[k], j1 = esrc[k + 1];
            float x0 = bf2f(xl[(size_t)j0 * 64 + lane]);
            float x1 = bf2f(xl[(size_t)j1 * 64 + lane]);
            float z0 = x0 + xrv, z1 = x1 + xrv;
            float l0 = fmaxf(z0, 0.f) + 0.2f * fminf(z0, 0.f);
            float l1 = fmaxf(z1, 0.f) + 0.2f * fminf(z1, 0.f);
            float p0 = l0 * attv, p1 = l1 * attv;
            #pragma unroll
            for (int off = 1; off < 64; off <<= 1) {
                p0 += __shfl_xor(p0, off, 64);
                p1 += __shfl_xor(p1, off, 64);
            }
            float w0 = __expf(p0), w1 = __expf(p1);
            s += w0 + w1;
            acc += w0 * x0 + w1 * x1;
        }
        if (k < r1) {
            int j0 = esrc[k];
            float x0 = bf2f(xl[(size_t)j0 * 64 + lane]);
            float z0 = x0 + xrv;
            float l0 = fmaxf(z0, 0.f) + 0.2f * fminf(z0, 0.f);
            float p0 = l0 * attv;
            #pragma unroll
            for (int off = 1; off < 64; off <<= 1)
                p0 += __shfl_xor(p0, off, 64);
            float w0 = __expf(p0);
            s += w0;
            acc += w0 * x0;
        }
        float rs = 1.f / (s + 1e-16f);
        float v = acc * rs + bias[lane];
        v = (v > 0.f) ? v : oslope * v;
        if constexpr (BF16OUT)
            ((unsigned short*)outv)[(size_t)wid * 64 + lane] = f2bf(v);
        else
            ((float*)outv)[(size_t)wid * 64 + lane] = v;
    }
}

// ---------------------------------------------------------------------------
// Pooling (batch_index sorted -> run aggregation, atomics at boundaries only)
// ---------------------------------------------------------------------------
__device__ __forceinline__ unsigned fenc(float f) {
    unsigned u = __float_as_uint(f);
    return (u & 0x80000000u) ? ~u : (u | 0x80000000u);
}
__device__ __forceinline__ float fdec(unsigned u) {
    return __uint_as_float((u & 0x80000000u) ? (u & 0x7fffffffu) : ~u);
}

__global__ __launch_bounds__(256) void pool_k(
    const float* __restrict__ h, const int* __restrict__ batch, int N,
    unsigned* __restrict__ gmaxu, float* __restrict__ gsum, float* __restrict__ gcnt)
{
    const int wid  = (blockIdx.x * blockDim.x + threadIdx.x) >> 6;
    const int lane = threadIdx.x & 63;
    const int n0 = wid * 16;
    if (n0 >= N) return;
    int gcur = batch[n0];
    float vmax = -3.4e38f, vsum = 0.f;
    int cnt = 0;
    #pragma unroll 4
    for (int i = 0; i < 16; ++i) {
        int n = n0 + i;
        if (n >= N) break;
        int g = batch[n];
        if (g != gcur) {
            atomicMax(&gmaxu[gcur * 64 + lane], fenc(vmax));
            atomicAdd(&gsum[gcur * 64 + lane], vsum);
            if (lane == 0) atomicAdd(&gcnt[gcur], (float)cnt);
            gcur = g; vmax = -3.4e38f; vsum = 0.f; cnt = 0;
        }
        float v = h[(size_t)n * 64 + lane];
        vmax = fmaxf(vmax, v);
        vsum += v;
        cnt++;
    }
    atomicMax(&gmaxu[gcur * 64 + lane], fenc(vmax));
    atomicAdd(&gsum[gcur * 64 + lane], vsum);
    if (lane == 0) atomicAdd(&gcnt[gcur], (float)cnt);
}

__global__ __launch_bounds__(128) void final_k(
    const unsigned* __restrict__ gmaxu, const float* __restrict__ gsum,
    const float* __restrict__ gcnt, const float* __restrict__ out_w,
    const float* __restrict__ out_b, float* __restrict__ out,
    float* __restrict__ hid_out)
{
    const int g = blockIdx.x;
    const int t = threadIdx.x;
    __shared__ float hid[128];
    float v;
    if (t < 64) {
        v = fdec(gmaxu[g * 64 + t]);
    } else {
        float c = fmaxf(gcnt[g], 1.f);
        v = gsum[g * 64 + (t - 64)] / c;
    }
    hid[t] = v;
    hid_out[(size_t)g * 128 + t] = v;
    __syncthreads();
    const int w = t >> 6, lane = t & 63;
    float p = hid[lane] * out_w[w * 128 + lane] + hid[lane + 64] * out_w[w * 128 + 64 + lane];
    #pragma unroll
    for (int off = 32; off >= 1; off >>= 1) p += __shfl_xor(p, off, 64);
    if (lane == 0) out[g * 2 + w] = p + out_b[w];
}

// ---------------------------------------------------------------------------
extern "C" void kernel_launch(void* const* d_in, const int* in_sizes, int n_in,
                              void* d_out, int out_size, void* d_ws, size_t ws_size,
                              hipStream_t stream)
{
    const float* x    = (const float*)d_in[0];
    const int*   ei   = (const int*)d_in[1];
    const int*   batch= (const int*)d_in[2];
    const float* w1l  = (const float*)d_in[3];
    const float* w1r  = (const float*)d_in[4];
    const float* att1 = (const float*)d_in[5];
    const float* b1   = (const float*)d_in[6];
    const float* w2l  = (const float*)d_in[7];
    const float* w2r  = (const float*)d_in[8];
    const float* att2 = (const float*)d_in[9];
    const float* b2   = (const float*)d_in[10];
    const float* w3l  = (const float*)d_in[11];
    const float* w3r  = (const float*)d_in[12];
    const float* att3 = (const float*)d_in[13];
    const float* b3   = (const float*)d_in[14];
    const float* outw = (const float*)d_in[15];
    const float* outb = (const float*)d_in[16];

    const int N   = in_sizes[2];
    const int E   = in_sizes[1] / 2;
    const int E2  = E + N;
    const int G   = 256;
    const int FIN = in_sizes[0] / N;    // 128
    const int* src = ei;
    const int* dst = ei + E;

    char* ws = (char*)d_ws;
    size_t off = 0;
    auto alloc = [&](size_t bytes) -> void* {
        void* p = ws + off;
        off = (off + bytes + 255) & ~(size_t)255;
        return p;
    };
    unsigned short* xlb   = (unsigned short*)alloc((size_t)N * 256 * 2);
    unsigned short* xrb   = (unsigned short*)alloc((size_t)N * 256 * 2);
    __hip_bfloat16* xb    = (__hip_bfloat16*)alloc((size_t)N * 128 * 2);
    __hip_bfloat16* hAb   = (__hip_bfloat16*)alloc((size_t)N * 256 * 2);
    __hip_bfloat16* hBb   = (__hip_bfloat16*)alloc((size_t)N * 128 * 2);
    float*          h3    = (float*)alloc((size_t)N * 64 * 4);
    int*            rowptr= (int*)alloc((size_t)(N + 1) * 4);
    int*            deg   = (int*)alloc((size_t)N * 4);
    int*            esrc  = (int*)alloc((size_t)E2 * 4);
    unsigned*       gmaxu = (unsigned*)alloc((size_t)G * 64 * 4);
    float*          gsum  = (float*)alloc((size_t)G * 64 * 4);
    float*          gcnt  = (float*)alloc((size_t)G * 4);
    __hip_bfloat16* w1lb  = (__hip_bfloat16*)alloc(256 * 128 * 2);
    __hip_bfloat16* w1rb  = (__hip_bfloat16*)alloc(256 * 128 * 2);
    __hip_bfloat16* w2lb  = (__hip_bfloat16*)alloc(128 * 256 * 2);
    __hip_bfloat16* w2rb  = (__hip_bfloat16*)alloc(128 * 256 * 2);
    __hip_bfloat16* w3lb  = (__hip_bfloat16*)alloc(64 * 128 * 2);
    __hip_bfloat16* w3rb  = (__hip_bfloat16*)alloc(64 * 128 * 2);

    init_k<<<(N + 255) / 256, 256, 0, stream>>>(deg, gsum, gcnt, gmaxu, N, G);

    // conversions
    const int s1 = 256 * 128, s2 = 128 * 256, s3 = 64 * 128;
    const int wtot = 2 * s1 + 2 * s2 + 2 * s3;
    f2b_k<<<((size_t)N * 128 / 4 + 255) / 256, 256, 0, stream>>>(x, xb, N * 128);
    f2b6_k<<<(wtot / 4 + 255) / 256, 256, 0, stream>>>(
        w1l, w1r, w2l, w2r, w3l, w3r, w1lb, w1rb, w2lb, w2rb, w3lb, w3rb, s1, s2, s3);

    // CSR
    const int eb = (E2 + 255) / 256;
    hist_k<<<eb, 256, 0, stream>>>(dst, E, N, deg);
    scan_k<<<1, 1024, 0, stream>>>(deg, rowptr, N);
    scatter_k<<<eb, 256, 0, stream>>>(src, dst, E, N, rowptr, deg, esrc);

    const int gx  = (N + 255) / 256;         // 64-row wave strips, 4 waves/block
    const int nwb = (N * 64 + 255) / 256;    // one wave per node

    // ---- layer 1: K=128 -> H=4, HD=256 (2 n-blocks of 128)
    gemm_mfma<8, 4><<<dim3(gx, 2, 2), 256, 0, stream>>>(xb, w1lb, w1rb,
        (__hip_bfloat16*)xlb, (__hip_bfloat16*)xrb, N, 256);
    fused_agg_k<4, true><<<nwb, 256, 0, stream>>>(xlb, xrb, rowptr, esrc, att1, b1, hAb, N, 0.01f);

    // ---- layer 2: K=256 -> H=2, HD=128
    gemm_mfma<8, 8><<<dim3(gx, 2, 1), 256, 0, stream>>>(hAb, w2lb, w2rb,
        (__hip_bfloat16*)xlb, (__hip_bfloat16*)xrb, N, 128);
    fused_agg_k<2, true><<<nwb, 256, 0, stream>>>(xlb, xrb, rowptr, esrc, att2, b2, hBb, N, 0.01f);

    // ---- layer 3: K=128 -> H=1, HD=64
    gemm_mfma<4, 4><<<dim3(gx, 2, 1), 256, 0, stream>>>(hBb, w3lb, w3rb,
        (__hip_bfloat16*)xlb, (__hip_bfloat16*)xrb, N, 64);
    fused_agg_k<1, false><<<nwb, 256, 0, stream>>>(xlb, xrb, rowptr, esrc, att3, b3, h3, N, 0.01f);

    // ---- pooling + head
    const int pb = (N / 16 + 3) / 4;
    pool_k<<<pb, 256, 0, stream>>>(h3, batch, N, gmaxu, gsum, gcnt);
    final_k<<<G, 128, 0, stream>>>(gmaxu, gsum, gcnt, outw, outb,
                                   (float*)d_out, (float*)d_out + G * 2);
}

// Round 6
// 423.942 us; speedup vs baseline: 2.9035x; 1.0535x over previous
//
#include <hip/hip_runtime.h>
#include <hip/hip_bf16.h>
#include <cfloat>
#include <cstdint>

// ---------------------------------------------------------------------------
// GATv2 x3 + global max/mean pool + linear head.
// Round 5: fused_agg re-mapped — 8 lanes per edge (16B/lane dwordx4 loads),
// EPW = 512/HD edges processed concurrently per wave, 3 shuffles per round
// shared across EPW edges, cross-slot combine once per node. Kernel count
// 17 -> 12 (init merged; f2b/f2b6/hist merged into prep_k).
// ---------------------------------------------------------------------------

typedef __attribute__((ext_vector_type(8))) short bf16x8;
typedef __attribute__((ext_vector_type(4))) float f32x4;
typedef __attribute__((ext_vector_type(2))) float v2f;

__device__ __forceinline__ float bf2f(unsigned short u) {
    return __uint_as_float((unsigned)u << 16);
}
__device__ __forceinline__ unsigned short f2bf(float f) {   // RNE
    unsigned u = __float_as_uint(f);
    u += 0x7FFFu + ((u >> 16) & 1u);
    return (unsigned short)(u >> 16);
}
__device__ __forceinline__ v2f unpack2(unsigned d) {        // [lo,hi] bf16 -> f32
    v2f r;
    r.x = __uint_as_float(d << 16);
    r.y = __uint_as_float(d & 0xffff0000u);
    return r;
}
__device__ __forceinline__ unsigned pack2(float a, float b) {
    return (unsigned)f2bf(a) | ((unsigned)f2bf(b) << 16);
}

// ---------------------------------------------------------------------------
// init: deg=0, gsum=0, gcnt=0, gmaxu=enc(-FLT_MAX)
// ---------------------------------------------------------------------------
__global__ void init_k(int* __restrict__ deg, float* __restrict__ gsum,
                       float* __restrict__ gcnt, unsigned* __restrict__ gmaxu,
                       int N, int G)
{
    int i = blockIdx.x * blockDim.x + threadIdx.x;
    int stride = gridDim.x * blockDim.x;
    for (int k = i; k < N; k += stride) deg[k] = 0;
    for (int k = i; k < G * 64; k += stride) { gsum[k] = 0.f; gmaxu[k] = 0x00800000u; }
    for (int k = i; k < G; k += stride) gcnt[k] = 0.f;
}

// ---------------------------------------------------------------------------
// prep: x->bf16, 6 weights->bf16, dst histogram. (deg zeroed by init_k, which
// must complete first — separate dispatch guarantees ordering.)
// ---------------------------------------------------------------------------
__global__ void prep_k(const float* __restrict__ x, unsigned short* __restrict__ xb, int nx,
                       const float* p0, const float* p1, const float* p2,
                       const float* p3, const float* p4, const float* p5,
                       unsigned short* d0, unsigned short* d1, unsigned short* d2,
                       unsigned short* d3, unsigned short* d4, unsigned short* d5,
                       int s01, int s23, int s45,
                       const int* __restrict__ dste, int E, int N, int* __restrict__ deg)
{
    const int tid = blockIdx.x * blockDim.x + threadIdx.x;
    const int stride = gridDim.x * blockDim.x;

    // x conversion, 4 elems/thread
    for (int i = tid; i < nx / 4; i += stride) {
        int idx = i * 4;
        float4 v = *(const float4*)(x + idx);
        uint2 o = { pack2(v.x, v.y), pack2(v.z, v.w) };
        *(uint2*)(xb + idx) = o;
    }
    // weight conversions
    const int wtot4 = (2 * s01 + 2 * s23 + 2 * s45) / 4;
    const int t0 = 2 * s01, t1 = t0 + 2 * s23;
    for (int i = tid; i < wtot4; i += stride) {
        int e = i * 4;
        const float* s; unsigned short* d; int off;
        if (e < t0)      { int j = e;      s = (j < s01) ? p0 : p1; d = (j < s01) ? d0 : d1; off = j % s01; }
        else if (e < t1) { int j = e - t0; s = (j < s23) ? p2 : p3; d = (j < s23) ? d2 : d3; off = j % s23; }
        else             { int j = e - t1; s = (j < s45) ? p4 : p5; d = (j < s45) ? d4 : d5; off = j % s45; }
        float4 v = *(const float4*)(s + off);
        uint2 o = { pack2(v.x, v.y), pack2(v.z, v.w) };
        *(uint2*)(d + off) = o;
    }
    // dst histogram (incl. self loops)
    for (int e = tid; e < E + N; e += stride) {
        int i = (e < E) ? dste[e] : (e - E);
        atomicAdd(&deg[i], 1);
    }
}

// ---------------------------------------------------------------------------
// bf16 MFMA GEMM: C = A @ W^T, C written as bf16.  One wave: 64 rows x
// (NT*16) cols; 4 m-tiles reuse each B fragment.  K = KT*32 compile-time.
// ---------------------------------------------------------------------------
template<int NT, int KT>
__global__ __launch_bounds__(256) void gemm_mfma(
    const __hip_bfloat16* __restrict__ A,
    const __hip_bfloat16* __restrict__ Wl, const __hip_bfloat16* __restrict__ Wr,
    __hip_bfloat16* __restrict__ Cl, __hip_bfloat16* __restrict__ Cr,
    int M, int Nout)
{
    constexpr int K = KT * 32;
    const int wave = threadIdx.x >> 6, lane = threadIdx.x & 63;
    const int m0 = (blockIdx.x * 4 + wave) * 64;
    if (m0 >= M) return;
    const __hip_bfloat16* W = blockIdx.y ? Wr : Wl;
    __hip_bfloat16* C = blockIdx.y ? Cr : Cl;
    const int nbase = blockIdx.z * NT * 16;
    const int r16  = lane & 15;
    const int quad = lane >> 4;
    const int kq = quad * 8;

    f32x4 acc[4][NT];
    #pragma unroll
    for (int mt = 0; mt < 4; ++mt)
        #pragma unroll
        for (int n = 0; n < NT; ++n) acc[mt][n] = (f32x4){0.f, 0.f, 0.f, 0.f};

    const __hip_bfloat16* Arow[4];
    #pragma unroll
    for (int mt = 0; mt < 4; ++mt) {
        int r = m0 + mt * 16 + r16;
        r = (r < M) ? r : (M - 1);
        Arow[mt] = A + (size_t)r * K + kq;
    }
    const __hip_bfloat16* Wbase = W + (size_t)(nbase + r16) * K + kq;

    #pragma unroll 2
    for (int kt = 0; kt < KT; ++kt) {
        const int k0 = kt * 32;
        bf16x8 a[4];
        #pragma unroll
        for (int mt = 0; mt < 4; ++mt)
            a[mt] = *(const bf16x8*)(Arow[mt] + k0);
        #pragma unroll
        for (int n = 0; n < NT; ++n) {
            bf16x8 b = *(const bf16x8*)(Wbase + (size_t)n * 16 * K + k0);
            #pragma unroll
            for (int mt = 0; mt < 4; ++mt)
                acc[mt][n] = __builtin_amdgcn_mfma_f32_16x16x32_bf16(a[mt], b, acc[mt][n], 0, 0, 0);
        }
    }

    unsigned short* Cu = (unsigned short*)C;
    #pragma unroll
    for (int mt = 0; mt < 4; ++mt)
        #pragma unroll
        for (int n = 0; n < NT; ++n)
            #pragma unroll
            for (int r = 0; r < 4; ++r) {
                int row = m0 + mt * 16 + quad * 4 + r;
                if (row < M)
                    Cu[(size_t)row * Nout + nbase + n * 16 + r16] = f2bf(acc[mt][n][r]);
            }
}

// ---------------------------------------------------------------------------
// wave-shuffle scan: 1024 threads, 16 waves, 8 elems/thread per tile
// ---------------------------------------------------------------------------
__global__ __launch_bounds__(1024) void scan_k(const int* __restrict__ deg,
                                               int* __restrict__ rowptr, int N)
{
    __shared__ int parts[16];
    __shared__ int carryS;
    const int t = threadIdx.x, lane = t & 63, wv = t >> 6;
    if (t == 0) { carryS = 0; rowptr[0] = 0; }
    __syncthreads();
    for (int base = 0; base < N; base += 8192) {
        int v[8];
        int run = 0;
        #pragma unroll
        for (int i = 0; i < 8; ++i) {
            int idx = base + t * 8 + i;
            run += (idx < N) ? deg[idx] : 0;
            v[i] = run;
        }
        int x = run;
        #pragma unroll
        for (int off = 1; off < 64; off <<= 1) {
            int y = __shfl_up(x, off, 64);
            if (lane >= off) x += y;
        }
        int excl = x - run;
        if (lane == 63) parts[wv] = x;
        __syncthreads();
        if (wv == 0 && lane < 16) {
            int p = parts[lane];
            int xx = p;
            #pragma unroll
            for (int off = 1; off < 16; off <<= 1) {
                int y = __shfl_up(xx, off, 64);
                if (lane >= off) xx += y;
            }
            parts[lane] = xx - p;   // exclusive
        }
        __syncthreads();
        int wexcl = parts[wv];
        int pre = carryS + wexcl + excl;
        #pragma unroll
        for (int i = 0; i < 8; ++i) {
            int idx = base + t * 8 + i;
            if (idx < N) rowptr[idx + 1] = pre + v[i];
        }
        __syncthreads();
        if (t == 1023) carryS += wexcl + x;
        __syncthreads();
    }
}

// scatter consumes deg (atomic countdown) -> no cursor buffer
__global__ void scatter_k(const int* __restrict__ src, const int* __restrict__ dst,
                          int E, int N, const int* __restrict__ rowptr,
                          int* __restrict__ deg, int* __restrict__ esrc)
{
    int e = blockIdx.x * blockDim.x + threadIdx.x;
    if (e >= E + N) return;
    int i = (e < E) ? dst[e] : (e - E);
    int j = (e < E) ? src[e] : (e - E);
    int old = atomicAdd(&deg[i], -1);
    esrc[rowptr[i] + old - 1] = j;
}

// ---------------------------------------------------------------------------
// Fused GATv2 layer, no-max softmax (logits bounded: sigma~1.3, |e|<<88).
// One wave per dst node.  LPE = HD/8 lanes own one edge (16B dwordx4 load,
// 8 feats/lane); EPW = 64/LPE edges processed per round.  Head = 64 feats =
// 8 lanes -> logit reduce is 3 shuffles for ALL concurrent edges.  Per-head
// softmax state (s) and acc combined across slots once per node at the end.
// ---------------------------------------------------------------------------
template<int H, bool BF16OUT>
__global__ __launch_bounds__(256) void fused_agg_k(
    const unsigned short* __restrict__ xl, const unsigned short* __restrict__ xr,
    const int* __restrict__ rowptr, const int* __restrict__ esrc,
    const float* __restrict__ att, const float* __restrict__ bias,
    void* __restrict__ outv, int N, float oslope)
{
    constexpr int HD  = H * 64;
    constexpr int LPE = HD / 8;        // lanes per edge (32/16/8)
    constexpr int EPW = 64 / LPE;      // edges per round (2/4/8)
    const int wid  = (blockIdx.x * blockDim.x + threadIdx.x) >> 6;
    const int lane = threadIdx.x & 63;
    if (wid >= N) return;
    const int slot = lane / LPE;
    const int il   = lane & (LPE - 1);
    const int fl   = il * 8;           // first feature for this lane

    // dst-node slice (8 feats), attention weights
    v2f xrv[4], attv[4], acc[4];
    {
        uint4 a = *(const uint4*)(xr + (size_t)wid * HD + fl);
        xrv[0] = unpack2(a.x); xrv[1] = unpack2(a.y);
        xrv[2] = unpack2(a.z); xrv[3] = unpack2(a.w);
    }
    #pragma unroll
    for (int p = 0; p < 4; ++p) {
        attv[p] = *(const v2f*)(att + fl + 2 * p);
        acc[p] = (v2f){0.f, 0.f};
    }

    const int r0 = rowptr[wid], r1 = rowptr[wid + 1];
    float s = 0.f;

    #pragma unroll 2
    for (int kb = r0; kb < r1; kb += EPW) {
        int k = kb + slot;
        bool valid = (k < r1);
        int kc = valid ? k : (r1 - 1);
        int j = esrc[kc];
        uint4 a = *(const uint4*)(xl + (size_t)j * HD + fl);
        v2f xv[4];
        xv[0] = unpack2(a.x); xv[1] = unpack2(a.y);
        xv[2] = unpack2(a.z); xv[3] = unpack2(a.w);
        v2f d = {0.f, 0.f};
        #pragma unroll
        for (int p = 0; p < 4; ++p) {
            v2f z = xv[p] + xrv[p];
            v2f l = __builtin_elementwise_max(z, (v2f){0.f, 0.f});
            l += (v2f){0.2f, 0.2f} * __builtin_elementwise_min(z, (v2f){0.f, 0.f});
            d += l * attv[p];
        }
        float pl = d.x + d.y;
        pl += __shfl_xor(pl, 1, 64);
        pl += __shfl_xor(pl, 2, 64);
        pl += __shfl_xor(pl, 4, 64);    // per-head logit, shared by 8-lane group
        float w = valid ? __expf(pl) : 0.f;
        s += w;
        #pragma unroll
        for (int p = 0; p < 4; ++p) acc[p] += w * xv[p];
    }

    // combine slots (same features, same head at distance >= LPE)
    #pragma unroll
    for (int off = LPE; off < 64; off <<= 1) {
        s += __shfl_xor(s, off, 64);
        #pragma unroll
        for (int p = 0; p < 4; ++p) {
            acc[p].x += __shfl_xor(acc[p].x, off, 64);
            acc[p].y += __shfl_xor(acc[p].y, off, 64);
        }
    }

    if (slot == 0) {
        float rs = 1.f / (s + 1e-16f);
        float o[8];
        #pragma unroll
        for (int p = 0; p < 4; ++p) {
            v2f b2 = *(const v2f*)(bias + fl + 2 * p);
            v2f v = acc[p] * rs + b2;
            o[2 * p]     = (v.x > 0.f) ? v.x : oslope * v.x;
            o[2 * p + 1] = (v.y > 0.f) ? v.y : oslope * v.y;
        }
        if constexpr (BF16OUT) {
            uint4 ov = { pack2(o[0], o[1]), pack2(o[2], o[3]),
                         pack2(o[4], o[5]), pack2(o[6], o[7]) };
            *(uint4*)((unsigned short*)outv + (size_t)wid * HD + fl) = ov;
        } else {
            float* of = (float*)outv + (size_t)wid * HD + fl;
            *(float4*)(of)     = make_float4(o[0], o[1], o[2], o[3]);
            *(float4*)(of + 4) = make_float4(o[4], o[5], o[6], o[7]);
        }
    }
}

// ---------------------------------------------------------------------------
// Pooling (batch_index sorted -> run aggregation, atomics at boundaries only)
// ---------------------------------------------------------------------------
__device__ __forceinline__ unsigned fenc(float f) {
    unsigned u = __float_as_uint(f);
    return (u & 0x80000000u) ? ~u : (u | 0x80000000u);
}
__device__ __forceinline__ float fdec(unsigned u) {
    return __uint_as_float((u & 0x80000000u) ? (u & 0x7fffffffu) : ~u);
}

__global__ __launch_bounds__(256) void pool_k(
    const float* __restrict__ h, const int* __restrict__ batch, int N,
    unsigned* __restrict__ gmaxu, float* __restrict__ gsum, float* __restrict__ gcnt)
{
    const int wid  = (blockIdx.x * blockDim.x + threadIdx.x) >> 6;
    const int lane = threadIdx.x & 63;
    const int n0 = wid * 16;
    if (n0 >= N) return;
    int gcur = batch[n0];
    float vmax = -3.4e38f, vsum = 0.f;
    int cnt = 0;
    #pragma unroll 4
    for (int i = 0; i < 16; ++i) {
        int n = n0 + i;
        if (n >= N) break;
        int g = batch[n];
        if (g != gcur) {
            atomicMax(&gmaxu[gcur * 64 + lane], fenc(vmax));
            atomicAdd(&gsum[gcur * 64 + lane], vsum);
            if (lane == 0) atomicAdd(&gcnt[gcur], (float)cnt);
            gcur = g; vmax = -3.4e38f; vsum = 0.f; cnt = 0;
        }
        float v = h[(size_t)n * 64 + lane];
        vmax = fmaxf(vmax, v);
        vsum += v;
        cnt++;
    }
    atomicMax(&gmaxu[gcur * 64 + lane], fenc(vmax));
    atomicAdd(&gsum[gcur * 64 + lane], vsum);
    if (lane == 0) atomicAdd(&gcnt[gcur], (float)cnt);
}

__global__ __launch_bounds__(128) void final_k(
    const unsigned* __restrict__ gmaxu, const float* __restrict__ gsum,
    const float* __restrict__ gcnt, const float* __restrict__ out_w,
    const float* __restrict__ out_b, float* __restrict__ out,
    float* __restrict__ hid_out)
{
    const int g = blockIdx.x;
    const int t = threadIdx.x;
    __shared__ float hid[128];
    float v;
    if (t < 64) {
        v = fdec(gmaxu[g * 64 + t]);
    } else {
        float c = fmaxf(gcnt[g], 1.f);
        v = gsum[g * 64 + (t - 64)] / c;
    }
    hid[t] = v;
    hid_out[(size_t)g * 128 + t] = v;
    __syncthreads();
    const int w = t >> 6, lane = t & 63;
    float p = hid[lane] * out_w[w * 128 + lane] + hid[lane + 64] * out_w[w * 128 + 64 + lane];
    #pragma unroll
    for (int off = 32; off >= 1; off >>= 1) p += __shfl_xor(p, off, 64);
    if (lane == 0) out[g * 2 + w] = p + out_b[w];
}

// ---------------------------------------------------------------------------
extern "C" void kernel_launch(void* const* d_in, const int* in_sizes, int n_in,
                              void* d_out, int out_size, void* d_ws, size_t ws_size,
                              hipStream_t stream)
{
    const float* x    = (const float*)d_in[0];
    const int*   ei   = (const int*)d_in[1];
    const int*   batch= (const int*)d_in[2];
    const float* w1l  = (const float*)d_in[3];
    const float* w1r  = (const float*)d_in[4];
    const float* att1 = (const float*)d_in[5];
    const float* b1   = (const float*)d_in[6];
    const float* w2l  = (const float*)d_in[7];
    const float* w2r  = (const float*)d_in[8];
    const float* att2 = (const float*)d_in[9];
    const float* b2   = (const float*)d_in[10];
    const float* w3l  = (const float*)d_in[11];
    const float* w3r  = (const float*)d_in[12];
    const float* att3 = (const float*)d_in[13];
    const float* b3   = (const float*)d_in[14];
    const float* outw = (const float*)d_in[15];
    const float* outb = (const float*)d_in[16];

    const int N   = in_sizes[2];
    const int E   = in_sizes[1] / 2;
    const int E2  = E + N;
    const int G   = 256;
    const int FIN = in_sizes[0] / N;    // 128
    const int* src = ei;
    const int* dst = ei + E;

    char* ws = (char*)d_ws;
    size_t off = 0;
    auto alloc = [&](size_t bytes) -> void* {
        void* p = ws + off;
        off = (off + bytes + 255) & ~(size_t)255;
        return p;
    };
    unsigned short* xlb   = (unsigned short*)alloc((size_t)N * 256 * 2);
    unsigned short* xrb   = (unsigned short*)alloc((size_t)N * 256 * 2);
    unsigned short* xb    = (unsigned short*)alloc((size_t)N * 128 * 2);
    unsigned short* hAb   = (unsigned short*)alloc((size_t)N * 256 * 2);
    unsigned short* hBb   = (unsigned short*)alloc((size_t)N * 128 * 2);
    float*          h3    = (float*)alloc((size_t)N * 64 * 4);
    int*            rowptr= (int*)alloc((size_t)(N + 1) * 4);
    int*            deg   = (int*)alloc((size_t)N * 4);
    int*            esrc  = (int*)alloc((size_t)E2 * 4);
    unsigned*       gmaxu = (unsigned*)alloc((size_t)G * 64 * 4);
    float*          gsum  = (float*)alloc((size_t)G * 64 * 4);
    float*          gcnt  = (float*)alloc((size_t)G * 4);
    unsigned short* w1lb  = (unsigned short*)alloc(256 * 128 * 2);
    unsigned short* w1rb  = (unsigned short*)alloc(256 * 128 * 2);
    unsigned short* w2lb  = (unsigned short*)alloc(128 * 256 * 2);
    unsigned short* w2rb  = (unsigned short*)alloc(128 * 256 * 2);
    unsigned short* w3lb  = (unsigned short*)alloc(64 * 128 * 2);
    unsigned short* w3rb  = (unsigned short*)alloc(64 * 128 * 2);

    // 1) zero deg + pool bufs (must complete before prep's histogram)
    init_k<<<(N + 255) / 256, 256, 0, stream>>>(deg, gsum, gcnt, gmaxu, N, G);

    // 2) conversions + histogram in one grid-stride kernel
    const int s1 = 256 * 128, s2 = 128 * 256, s3 = 64 * 128;
    prep_k<<<1024, 256, 0, stream>>>(x, xb, N * FIN,
        w1l, w1r, w2l, w2r, w3l, w3r, w1lb, w1rb, w2lb, w2rb, w3lb, w3rb,
        s1, s2, s3, dst, E, N, deg);

    // 3-4) CSR
    scan_k<<<1, 1024, 0, stream>>>(deg, rowptr, N);
    scatter_k<<<(E2 + 255) / 256, 256, 0, stream>>>(src, dst, E, N, rowptr, deg, esrc);

    const int gx  = (N + 255) / 256;         // 64-row wave strips, 4 waves/block
    const int nwb = (N * 64 + 255) / 256;    // one wave per node

    // ---- layer 1: K=128 -> H=4, HD=256 (2 n-blocks of 128)
    gemm_mfma<8, 4><<<dim3(gx, 2, 2), 256, 0, stream>>>(
        (const __hip_bfloat16*)xb, (const __hip_bfloat16*)w1lb, (const __hip_bfloat16*)w1rb,
        (__hip_bfloat16*)xlb, (__hip_bfloat16*)xrb, N, 256);
    fused_agg_k<4, true><<<nwb, 256, 0, stream>>>(xlb, xrb, rowptr, esrc, att1, b1, hAb, N, 0.01f);

    // ---- layer 2: K=256 -> H=2, HD=128
    gemm_mfma<8, 8><<<dim3(gx, 2, 1), 256, 0, stream>>>(
        (const __hip_bfloat16*)hAb, (const __hip_bfloat16*)w2lb, (const __hip_bfloat16*)w2rb,
        (__hip_bfloat16*)xlb, (__hip_bfloat16*)xrb, N, 128);
    fused_agg_k<2, true><<<nwb, 256, 0, stream>>>(xlb, xrb, rowptr, esrc, att2, b2, hBb, N, 0.01f);

    // ---- layer 3: K=128 -> H=1, HD=64
    gemm_mfma<4, 4><<<dim3(gx, 2, 1), 256, 0, stream>>>(
        (const __hip_bfloat16*)hBb, (const __hip_bfloat16*)w3lb, (const __hip_bfloat16*)w3rb,
        (__hip_bfloat16*)xlb, (__hip_bfloat16*)xrb, N, 64);
    fused_agg_k<1, false><<<nwb, 256, 0, stream>>>(xlb, xrb, rowptr, esrc, att3, b3, h3, N, 0.01f);

    // ---- pooling + head
    const int pb = (N / 16 + 3) / 4;
    pool_k<<<pb, 256, 0, stream>>>(h3, batch, N, gmaxu, gsum, gcnt);
    final_k<<<G, 128, 0, stream>>>(gmaxu, gsum, gcnt, outw, outb,
                                   (float*)d_out, (float*)d_out + G * 2);
}

// Round 7
// 385.110 us; speedup vs baseline: 3.1962x; 1.1008x over previous
//
#include <hip/hip_runtime.h>
#include <hip/hip_bf16.h>
#include <cfloat>
#include <cstdint>

// ---------------------------------------------------------------------------
// GATv2 x3 + global max/mean pool + linear head.
// Round 6: fused_agg back to round-4 mapping (lane holds H feats, 1 edge per
// wave-round — measured better than the 8-lane-slot remap) with:
//   - DPP row_ror rotate-reduce for the head-group sum (VALU, no LDS pipe)
//   - leaky(z) = max(z, 0.2z)  (2 ops instead of 3)
//   - att pre-scaled by log2(e) -> per-edge exp is a single v_exp_f32
//   - manual 4-edge unrolled gather loop (4 loads in flight, uniform k)
// CSR scan split into 3 parallel phases.
// ---------------------------------------------------------------------------

typedef __attribute__((ext_vector_type(8))) short bf16x8;
typedef __attribute__((ext_vector_type(4))) float f32x4;
typedef __attribute__((ext_vector_type(2))) float v2f;
typedef __attribute__((ext_vector_type(4))) unsigned short us4;
typedef __attribute__((ext_vector_type(2))) unsigned short us2;

#define L2E 1.4426950408889634f

__device__ __forceinline__ float bf2f(unsigned short u) {
    return __uint_as_float((unsigned)u << 16);
}
__device__ __forceinline__ unsigned short f2bf(float f) {   // RNE
    unsigned u = __float_as_uint(f);
    u += 0x7FFFu + ((u >> 16) & 1u);
    return (unsigned short)(u >> 16);
}
__device__ __forceinline__ v2f unpack2(unsigned d) {        // [lo,hi] bf16 -> f32
    v2f r;
    r.x = __uint_as_float(d << 16);
    r.y = __uint_as_float(d & 0xffff0000u);
    return r;
}
__device__ __forceinline__ unsigned pack2(float a, float b) {
    return (unsigned)f2bf(a) | ((unsigned)f2bf(b) << 16);
}

// ---- cross-lane sum helpers -------------------------------------------------
// dpp row_ror:n add (rotate within 16-lane rows); after ror 1,2,4,8 every lane
// of a 16-row holds the row sum.
template<int CTRL>
__device__ __forceinline__ float dpp_add_f(float x) {
    int xi = __float_as_int(x);
    int yi = __builtin_amdgcn_update_dpp(xi, xi, CTRL, 0xF, 0xF, false);
    return x + __int_as_float(yi);
}
template<int PAT>
__device__ __forceinline__ float swz_add_f(float x) {
    int yi = __builtin_amdgcn_ds_swizzle(__float_as_int(x), PAT);
    return x + __int_as_float(yi);
}
template<int GS>
__device__ __forceinline__ float group_sum(float p) {
    p = dpp_add_f<0x121>(p);   // row_ror:1
    p = dpp_add_f<0x122>(p);   // row_ror:2
    p = dpp_add_f<0x124>(p);   // row_ror:4
    p = dpp_add_f<0x128>(p);   // row_ror:8
    if constexpr (GS >= 32) p = swz_add_f<0x401F>(p);   // xor 16
    if constexpr (GS >= 64) p += __shfl_xor(p, 32, 64); // cross-half
    return p;
}

// ---------------------------------------------------------------------------
// init: deg=0, gsum=0, gcnt=0, gmaxu=enc(-FLT_MAX)
// ---------------------------------------------------------------------------
__global__ void init_k(int* __restrict__ deg, float* __restrict__ gsum,
                       float* __restrict__ gcnt, unsigned* __restrict__ gmaxu,
                       int N, int G)
{
    int i = blockIdx.x * blockDim.x + threadIdx.x;
    int stride = gridDim.x * blockDim.x;
    for (int k = i; k < N; k += stride) deg[k] = 0;
    for (int k = i; k < G * 64; k += stride) { gsum[k] = 0.f; gmaxu[k] = 0x00800000u; }
    for (int k = i; k < G; k += stride) gcnt[k] = 0.f;
}

// ---------------------------------------------------------------------------
// prep: x->bf16, 6 weights->bf16, dst histogram (deg zeroed by init_k).
// ---------------------------------------------------------------------------
__global__ void prep_k(const float* __restrict__ x, unsigned short* __restrict__ xb, int nx,
                       const float* p0, const float* p1, const float* p2,
                       const float* p3, const float* p4, const float* p5,
                       unsigned short* d0, unsigned short* d1, unsigned short* d2,
                       unsigned short* d3, unsigned short* d4, unsigned short* d5,
                       int s01, int s23, int s45,
                       const int* __restrict__ dste, int E, int N, int* __restrict__ deg)
{
    const int tid = blockIdx.x * blockDim.x + threadIdx.x;
    const int stride = gridDim.x * blockDim.x;

    for (int i = tid; i < nx / 4; i += stride) {
        int idx = i * 4;
        float4 v = *(const float4*)(x + idx);
        uint2 o = { pack2(v.x, v.y), pack2(v.z, v.w) };
        *(uint2*)(xb + idx) = o;
    }
    const int wtot4 = (2 * s01 + 2 * s23 + 2 * s45) / 4;
    const int t0 = 2 * s01, t1 = t0 + 2 * s23;
    for (int i = tid; i < wtot4; i += stride) {
        int e = i * 4;
        const float* s; unsigned short* d; int off;
        if (e < t0)      { int j = e;      s = (j < s01) ? p0 : p1; d = (j < s01) ? d0 : d1; off = j % s01; }
        else if (e < t1) { int j = e - t0; s = (j < s23) ? p2 : p3; d = (j < s23) ? d2 : d3; off = j % s23; }
        else             { int j = e - t1; s = (j < s45) ? p4 : p5; d = (j < s45) ? d4 : d5; off = j % s45; }
        float4 v = *(const float4*)(s + off);
        uint2 o = { pack2(v.x, v.y), pack2(v.z, v.w) };
        *(uint2*)(d + off) = o;
    }
    for (int e = tid; e < E + N; e += stride) {
        int i = (e < E) ? dste[e] : (e - E);
        atomicAdd(&deg[i], 1);
    }
}

// ---------------------------------------------------------------------------
// bf16 MFMA GEMM: C = A @ W^T, bf16 out.  One wave: 64 rows x (NT*16) cols.
// ---------------------------------------------------------------------------
template<int NT, int KT>
__global__ __launch_bounds__(256) void gemm_mfma(
    const __hip_bfloat16* __restrict__ A,
    const __hip_bfloat16* __restrict__ Wl, const __hip_bfloat16* __restrict__ Wr,
    __hip_bfloat16* __restrict__ Cl, __hip_bfloat16* __restrict__ Cr,
    int M, int Nout)
{
    constexpr int K = KT * 32;
    const int wave = threadIdx.x >> 6, lane = threadIdx.x & 63;
    const int m0 = (blockIdx.x * 4 + wave) * 64;
    if (m0 >= M) return;
    const __hip_bfloat16* W = blockIdx.y ? Wr : Wl;
    __hip_bfloat16* C = blockIdx.y ? Cr : Cl;
    const int nbase = blockIdx.z * NT * 16;
    const int r16  = lane & 15;
    const int quad = lane >> 4;
    const int kq = quad * 8;

    f32x4 acc[4][NT];
    #pragma unroll
    for (int mt = 0; mt < 4; ++mt)
        #pragma unroll
        for (int n = 0; n < NT; ++n) acc[mt][n] = (f32x4){0.f, 0.f, 0.f, 0.f};

    const __hip_bfloat16* Arow[4];
    #pragma unroll
    for (int mt = 0; mt < 4; ++mt) {
        int r = m0 + mt * 16 + r16;
        r = (r < M) ? r : (M - 1);
        Arow[mt] = A + (size_t)r * K + kq;
    }
    const __hip_bfloat16* Wbase = W + (size_t)(nbase + r16) * K + kq;

    #pragma unroll 2
    for (int kt = 0; kt < KT; ++kt) {
        const int k0 = kt * 32;
        bf16x8 a[4];
        #pragma unroll
        for (int mt = 0; mt < 4; ++mt)
            a[mt] = *(const bf16x8*)(Arow[mt] + k0);
        #pragma unroll
        for (int n = 0; n < NT; ++n) {
            bf16x8 b = *(const bf16x8*)(Wbase + (size_t)n * 16 * K + k0);
            #pragma unroll
            for (int mt = 0; mt < 4; ++mt)
                acc[mt][n] = __builtin_amdgcn_mfma_f32_16x16x32_bf16(a[mt], b, acc[mt][n], 0, 0, 0);
        }
    }

    unsigned short* Cu = (unsigned short*)C;
    #pragma unroll
    for (int mt = 0; mt < 4; ++mt)
        #pragma unroll
        for (int n = 0; n < NT; ++n)
            #pragma unroll
            for (int r = 0; r < 4; ++r) {
                int row = m0 + mt * 16 + quad * 4 + r;
                if (row < M)
                    Cu[(size_t)row * Nout + nbase + n * 16 + r16] = f2bf(acc[mt][n][r]);
            }
}

// ---------------------------------------------------------------------------
// 3-phase parallel scan: A) per-block local inclusive scan + block sums,
// B) one-wave exclusive scan of block sums, C) add block offsets.
// ---------------------------------------------------------------------------
__global__ __launch_bounds__(1024) void scanA_k(const int* __restrict__ deg,
                                                int* __restrict__ rowptr,
                                                int* __restrict__ bsum, int N)
{
    __shared__ int parts[16];
    const int t = threadIdx.x, lane = t & 63, wv = t >> 6;
    const int base = blockIdx.x * 8192;
    int v[8];
    int run = 0;
    #pragma unroll
    for (int i = 0; i < 8; ++i) {
        int idx = base + t * 8 + i;
        run += (idx < N) ? deg[idx] : 0;
        v[i] = run;
    }
    int x = run;
    #pragma unroll
    for (int off = 1; off < 64; off <<= 1) {
        int y = __shfl_up(x, off, 64);
        if (lane >= off) x += y;
    }
    int excl = x - run;
    if (lane == 63) parts[wv] = x;
    __syncthreads();
    if (wv == 0 && lane < 16) {
        int p = parts[lane];
        int xx = p;
        #pragma unroll
        for (int off = 1; off < 16; off <<= 1) {
            int y = __shfl_up(xx, off, 64);
            if (lane >= off) xx += y;
        }
        parts[lane] = xx - p;   // exclusive
    }
    __syncthreads();
    int pre = parts[wv] + excl;
    #pragma unroll
    for (int i = 0; i < 8; ++i) {
        int idx = base + t * 8 + i;
        if (idx < N) rowptr[idx + 1] = pre + v[i];
    }
    if (t == 1023) bsum[blockIdx.x] = parts[15] + x;   // block total
}

__global__ void scanB_k(int* __restrict__ bsum, int B)
{
    int lane = threadIdx.x;
    int v = (lane < B) ? bsum[lane] : 0;
    int x = v;
    #pragma unroll
    for (int off = 1; off < 64; off <<= 1) {
        int y = __shfl_up(x, off, 64);
        if (lane >= off) x += y;
    }
    if (lane < B) bsum[lane] = x - v;   // exclusive
}

__global__ __launch_bounds__(1024) void scanC_k(int* __restrict__ rowptr,
                                                const int* __restrict__ bsum, int N)
{
    const int b = blockIdx.x, t = threadIdx.x;
    if (b == 0) { if (t == 0) rowptr[0] = 0; return; }
    const int off = bsum[b];
    const int base = b * 8192;
    #pragma unroll
    for (int i = 0; i < 8; ++i) {
        int idx = base + t * 8 + i;
        if (idx < N) rowptr[idx + 1] += off;
    }
}

// scatter consumes deg (atomic countdown) -> no cursor buffer
__global__ void scatter_k(const int* __restrict__ src, const int* __restrict__ dst,
                          int E, int N, const int* __restrict__ rowptr,
                          int* __restrict__ deg, int* __restrict__ esrc)
{
    int e = blockIdx.x * blockDim.x + threadIdx.x;
    if (e >= E + N) return;
    int i = (e < E) ? dst[e] : (e - E);
    int j = (e < E) ? src[e] : (e - E);
    int old = atomicAdd(&deg[i], -1);
    esrc[rowptr[i] + old - 1] = j;
}

// ---------------------------------------------------------------------------
// Fused GATv2 layer, no-max softmax.  One wave per dst node; lane holds H
// consecutive features (head = lane/(64/H)).  4-edge unrolled gather loop.
// att pre-scaled by log2(e) so w = exp2(logit') = exp(logit).
// ---------------------------------------------------------------------------
template<int P>
__device__ __forceinline__ float edge_logit(const v2f* xv, const v2f* xrv, const v2f* attv)
{
    v2f d = {0.f, 0.f};
    #pragma unroll
    for (int p = 0; p < P; ++p) {
        v2f z = xv[p] + xrv[p];
        v2f l = __builtin_elementwise_max(z, z * 0.2f);   // leaky = max(z, 0.2z)
        d += l * attv[p];
    }
    return d.x + d.y;
}

template<int P>
__device__ __forceinline__ void load_edge(const unsigned short* __restrict__ xl,
                                          size_t base, v2f* xv)
{
    if constexpr (P == 2) {
        uint2 a = *(const uint2*)(xl + base);
        xv[0] = unpack2(a.x); xv[1] = unpack2(a.y);
    } else {
        unsigned a = *(const unsigned*)(xl + base);
        xv[0] = unpack2(a);
    }
}

template<int H, bool BF16OUT>
__global__ __launch_bounds__(256) void fused_agg_k(
    const unsigned short* __restrict__ xl, const unsigned short* __restrict__ xr,
    const int* __restrict__ rowptr, const int* __restrict__ esrc,
    const float* __restrict__ att, const float* __restrict__ bias,
    void* __restrict__ outv, int N, float oslope)
{
    const int wid  = (blockIdx.x * blockDim.x + threadIdx.x) >> 6;
    const int lane = threadIdx.x & 63;
    if (wid >= N) return;
    constexpr int HD = H * 64;
    constexpr int GS = 64 / H;
    const int f0 = lane * H;
    const int r0 = rowptr[wid];
    const int r1 = rowptr[wid + 1];

    if constexpr (H >= 2) {
        constexpr int P = H / 2;
        v2f xrv[P], attv[P], acc[P];
        load_edge<P>(xr, (size_t)wid * HD + f0, xrv);
        #pragma unroll
        for (int p = 0; p < P; ++p) {
            attv[p] = *(const v2f*)(att + f0 + 2 * p) * L2E;
            acc[p] = (v2f){0.f, 0.f};
        }

        float s = 0.f;
        int k = r0;
        for (; k + 4 <= r1; k += 4) {
            int j[4];
            #pragma unroll
            for (int i = 0; i < 4; ++i) j[i] = esrc[k + i];
            v2f xv[4][P];
            #pragma unroll
            for (int i = 0; i < 4; ++i)
                load_edge<P>(xl, (size_t)j[i] * HD + f0, xv[i]);
            float pl[4];
            #pragma unroll
            for (int i = 0; i < 4; ++i) pl[i] = edge_logit<P>(xv[i], xrv, attv);
            #pragma unroll
            for (int i = 0; i < 4; ++i) pl[i] = group_sum<GS>(pl[i]);
            float w[4];
            #pragma unroll
            for (int i = 0; i < 4; ++i) w[i] = __builtin_amdgcn_exp2f(pl[i]);
            s += (w[0] + w[1]) + (w[2] + w[3]);
            #pragma unroll
            for (int p = 0; p < P; ++p) {
                v2f t = xv[0][p] * w[0] + xv[1][p] * w[1];
                t += xv[2][p] * w[2] + xv[3][p] * w[3];
                acc[p] += t;
            }
        }
        for (; k < r1; ++k) {
            int j0 = esrc[k];
            v2f xv[P];
            load_edge<P>(xl, (size_t)j0 * HD + f0, xv);
            float pl = group_sum<GS>(edge_logit<P>(xv, xrv, attv));
            float w = __builtin_amdgcn_exp2f(pl);
            s += w;
            #pragma unroll
            for (int p = 0; p < P; ++p) acc[p] += xv[p] * w;
        }

        float rs = 1.f / (s + 1e-16f);
        unsigned short o[H];
        float of[H];
        #pragma unroll
        for (int p = 0; p < P; ++p) {
            v2f b2 = *(const v2f*)(bias + f0 + 2 * p);
            v2f v = acc[p] * rs + b2;
            v = __builtin_elementwise_max(v, v * oslope);
            if constexpr (BF16OUT) { o[2 * p] = f2bf(v.x); o[2 * p + 1] = f2bf(v.y); }
            else                   { of[2 * p] = v.x; of[2 * p + 1] = v.y; }
        }
        if constexpr (BF16OUT) {
            unsigned short* ou = (unsigned short*)outv;
            if constexpr (H == 4) *(us4*)(ou + (size_t)wid * HD + f0) = *(us4*)o;
            else                  *(us2*)(ou + (size_t)wid * HD + f0) = *(us2*)o;
        } else {
            float* off_ = (float*)outv;
            #pragma unroll
            for (int i = 0; i < H; ++i) off_[(size_t)wid * HD + f0 + i] = of[i];
        }
    } else {
        // H == 1: scalar feats, GS = 64
        float xrv  = bf2f(xr[(size_t)wid * 64 + lane]);
        float attv = att[lane] * L2E;
        float s = 0.f, acc = 0.f;
        int k = r0;
        for (; k + 4 <= r1; k += 4) {
            int j[4];
            #pragma unroll
            for (int i = 0; i < 4; ++i) j[i] = esrc[k + i];
            float xv[4], pl[4], w[4];
            #pragma unroll
            for (int i = 0; i < 4; ++i) xv[i] = bf2f(xl[(size_t)j[i] * 64 + lane]);
            #pragma unroll
            for (int i = 0; i < 4; ++i) {
                float z = xv[i] + xrv;
                pl[i] = fmaxf(z, 0.2f * z) * attv;
            }
            #pragma unroll
            for (int i = 0; i < 4; ++i) pl[i] = group_sum<64>(pl[i]);
            #pragma unroll
            for (int i = 0; i < 4; ++i) w[i] = __builtin_amdgcn_exp2f(pl[i]);
            s += (w[0] + w[1]) + (w[2] + w[3]);
            acc += (xv[0] * w[0] + xv[1] * w[1]) + (xv[2] * w[2] + xv[3] * w[3]);
        }
        for (; k < r1; ++k) {
            float x0 = bf2f(xl[(size_t)esrc[k] * 64 + lane]);
            float z = x0 + xrv;
            float pl = group_sum<64>(fmaxf(z, 0.2f * z) * attv);
            float w = __builtin_amdgcn_exp2f(pl);
            s += w;
            acc += x0 * w;
        }
        float rs = 1.f / (s + 1e-16f);
        float v = acc * rs + bias[lane];
        v = fmaxf(v, oslope * v);
        if constexpr (BF16OUT)
            ((unsigned short*)outv)[(size_t)wid * 64 + lane] = f2bf(v);
        else
            ((float*)outv)[(size_t)wid * 64 + lane] = v;
    }
}

// ---------------------------------------------------------------------------
// Pooling (batch_index sorted -> run aggregation, atomics at boundaries only)
// ---------------------------------------------------------------------------
__device__ __forceinline__ unsigned fenc(float f) {
    unsigned u = __float_as_uint(f);
    return (u & 0x80000000u) ? ~u : (u | 0x80000000u);
}
__device__ __forceinline__ float fdec(unsigned u) {
    return __uint_as_float((u & 0x80000000u) ? (u & 0x7fffffffu) : ~u);
}

__global__ __launch_bounds__(256) void pool_k(
    const float* __restrict__ h, const int* __restrict__ batch, int N,
    unsigned* __restrict__ gmaxu, float* __restrict__ gsum, float* __restrict__ gcnt)
{
    const int wid  = (blockIdx.x * blockDim.x + threadIdx.x) >> 6;
    const int lane = threadIdx.x & 63;
    const int n0 = wid * 16;
    if (n0 >= N) return;
    int gcur = batch[n0];
    float vmax = -3.4e38f, vsum = 0.f;
    int cnt = 0;
    #pragma unroll 4
    for (int i = 0; i < 16; ++i) {
        int n = n0 + i;
        if (n >= N) break;
        int g = batch[n];
        if (g != gcur) {
            atomicMax(&gmaxu[gcur * 64 + lane], fenc(vmax));
            atomicAdd(&gsum[gcur * 64 + lane], vsum);
            if (lane == 0) atomicAdd(&gcnt[gcur], (float)cnt);
            gcur = g; vmax = -3.4e38f; vsum = 0.f; cnt = 0;
        }
        float v = h[(size_t)n * 64 + lane];
        vmax = fmaxf(vmax, v);
        vsum += v;
        cnt++;
    }
    atomicMax(&gmaxu[gcur * 64 + lane], fenc(vmax));
    atomicAdd(&gsum[gcur * 64 + lane], vsum);
    if (lane == 0) atomicAdd(&gcnt[gcur], (float)cnt);
}

__global__ __launch_bounds__(128) void final_k(
    const unsigned* __restrict__ gmaxu, const float* __restrict__ gsum,
    const float* __restrict__ gcnt, const float* __restrict__ out_w,
    const float* __restrict__ out_b, float* __restrict__ out,
    float* __restrict__ hid_out)
{
    const int g = blockIdx.x;
    const int t = threadIdx.x;
    __shared__ float hid[128];
    float v;
    if (t < 64) {
        v = fdec(gmaxu[g * 64 + t]);
    } else {
        float c = fmaxf(gcnt[g], 1.f);
        v = gsum[g * 64 + (t - 64)] / c;
    }
    hid[t] = v;
    hid_out[(size_t)g * 128 + t] = v;
    __syncthreads();
    const int w = t >> 6, lane = t & 63;
    float p = hid[lane] * out_w[w * 128 + lane] + hid[lane + 64] * out_w[w * 128 + 64 + lane];
    #pragma unroll
    for (int off = 32; off >= 1; off >>= 1) p += __shfl_xor(p, off, 64);
    if (lane == 0) out[g * 2 + w] = p + out_b[w];
}

// ---------------------------------------------------------------------------
extern "C" void kernel_launch(void* const* d_in, const int* in_sizes, int n_in,
                              void* d_out, int out_size, void* d_ws, size_t ws_size,
                              hipStream_t stream)
{
    const float* x    = (const float*)d_in[0];
    const int*   ei   = (const int*)d_in[1];
    const int*   batch= (const int*)d_in[2];
    const float* w1l  = (const float*)d_in[3];
    const float* w1r  = (const float*)d_in[4];
    const float* att1 = (const float*)d_in[5];
    const float* b1   = (const float*)d_in[6];
    const float* w2l  = (const float*)d_in[7];
    const float* w2r  = (const float*)d_in[8];
    const float* att2 = (const float*)d_in[9];
    const float* b2   = (const float*)d_in[10];
    const float* w3l  = (const float*)d_in[11];
    const float* w3r  = (const float*)d_in[12];
    const float* att3 = (const float*)d_in[13];
    const float* b3   = (const float*)d_in[14];
    const float* outw = (const float*)d_in[15];
    const float* outb = (const float*)d_in[16];

    const int N   = in_sizes[2];
    const int E   = in_sizes[1] / 2;
    const int E2  = E + N;
    const int G   = 256;
    const int FIN = in_sizes[0] / N;    // 128
    const int* src = ei;
    const int* dst = ei + E;

    char* ws = (char*)d_ws;
    size_t off = 0;
    auto alloc = [&](size_t bytes) -> void* {
        void* p = ws + off;
        off = (off + bytes + 255) & ~(size_t)255;
        return p;
    };
    unsigned short* xlb   = (unsigned short*)alloc((size_t)N * 256 * 2);
    unsigned short* xrb   = (unsigned short*)alloc((size_t)N * 256 * 2);
    unsigned short* xb    = (unsigned short*)alloc((size_t)N * 128 * 2);
    unsigned short* hAb   = (unsigned short*)alloc((size_t)N * 256 * 2);
    unsigned short* hBb   = (unsigned short*)alloc((size_t)N * 128 * 2);
    float*          h3    = (float*)alloc((size_t)N * 64 * 4);
    int*            rowptr= (int*)alloc((size_t)(N + 1) * 4);
    int*            deg   = (int*)alloc((size_t)N * 4);
    int*            esrc  = (int*)alloc((size_t)E2 * 4);
    int*            bsum  = (int*)alloc(64 * 4);
    unsigned*       gmaxu = (unsigned*)alloc((size_t)G * 64 * 4);
    float*          gsum  = (float*)alloc((size_t)G * 64 * 4);
    float*          gcnt  = (float*)alloc((size_t)G * 4);
    unsigned short* w1lb  = (unsigned short*)alloc(256 * 128 * 2);
    unsigned short* w1rb  = (unsigned short*)alloc(256 * 128 * 2);
    unsigned short* w2lb  = (unsigned short*)alloc(128 * 256 * 2);
    unsigned short* w2rb  = (unsigned short*)alloc(128 * 256 * 2);
    unsigned short* w3lb  = (unsigned short*)alloc(64 * 128 * 2);
    unsigned short* w3rb  = (unsigned short*)alloc(64 * 128 * 2);

    init_k<<<(N + 255) / 256, 256, 0, stream>>>(deg, gsum, gcnt, gmaxu, N, G);

    const int s1 = 256 * 128, s2 = 128 * 256, s3 = 64 * 128;
    prep_k<<<1024, 256, 0, stream>>>(x, xb, N * FIN,
        w1l, w1r, w2l, w2r, w3l, w3r, w1lb, w1rb, w2lb, w2rb, w3lb, w3rb,
        s1, s2, s3, dst, E, N, deg);

    // CSR: 3-phase scan + scatter
    const int nblk = (N + 8191) / 8192;
    scanA_k<<<nblk, 1024, 0, stream>>>(deg, rowptr, bsum, N);
    scanB_k<<<1, 64, 0, stream>>>(bsum, nblk);
    scanC_k<<<nblk, 1024, 0, stream>>>(rowptr, bsum, N);
    scatter_k<<<(E2 + 255) / 256, 256, 0, stream>>>(src, dst, E, N, rowptr, deg, esrc);

    const int gx  = (N + 255) / 256;
    const int nwb = (N * 64 + 255) / 256;

    // ---- layer 1: K=128 -> H=4, HD=256 (2 n-blocks of 128)
    gemm_mfma<8, 4><<<dim3(gx, 2, 2), 256, 0, stream>>>(
        (const __hip_bfloat16*)xb, (const __hip_bfloat16*)w1lb, (const __hip_bfloat16*)w1rb,
        (__hip_bfloat16*)xlb, (__hip_bfloat16*)xrb, N, 256);
    fused_agg_k<4, true><<<nwb, 256, 0, stream>>>(xlb, xrb, rowptr, esrc, att1, b1, hAb, N, 0.01f);

    // ---- layer 2: K=256 -> H=2, HD=128
    gemm_mfma<8, 8><<<dim3(gx, 2, 1), 256, 0, stream>>>(
        (const __hip_bfloat16*)hAb, (const __hip_bfloat16*)w2lb, (const __hip_bfloat16*)w2rb,
        (__hip_bfloat16*)xlb, (__hip_bfloat16*)xrb, N, 128);
    fused_agg_k<2, true><<<nwb, 256, 0, stream>>>(xlb, xrb, rowptr, esrc, att2, b2, hBb, N, 0.01f);

    // ---- layer 3: K=128 -> H=1, HD=64
    gemm_mfma<4, 4><<<dim3(gx, 2, 1), 256, 0, stream>>>(
        (const __hip_bfloat16*)hBb, (const __hip_bfloat16*)w3lb, (const __hip_bfloat16*)w3rb,
        (__hip_bfloat16*)xlb, (__hip_bfloat16*)xrb, N, 64);
    fused_agg_k<1, false><<<nwb, 256, 0, stream>>>(xlb, xrb, rowptr, esrc, att3, b3, h3, N, 0.01f);

    // ---- pooling + head
    const int pb = (N / 16 + 3) / 4;
    pool_k<<<pb, 256, 0, stream>>>(h3, batch, N, gmaxu, gsum, gcnt);
    final_k<<<G, 128, 0, stream>>>(gmaxu, gsum, gcnt, outw, outb,
                                   (float*)d_out, (float*)d_out + G * 2);
}

// Round 8
// 384.498 us; speedup vs baseline: 3.2013x; 1.0016x over previous
//
#include <hip/hip_runtime.h>
#include <hip/hip_bf16.h>
#include <cfloat>
#include <cstdint>

// ---------------------------------------------------------------------------
// GATv2 x3 + global max/mean pool + linear head.
// Round 7: GEMM wave tile 64x128 -> 32x64. Round-6's acc[4][8] = 128 AGPR +
// 140 VGPR = 268 unified regs -> 1 wave/SIMD (occupancy 7.5%, MfmaUtil 4.5%).
// acc[2][4] = 32 AGPR keeps ~4 waves/SIMD for latency hiding while retaining
// an 8-MFMA : 6-load k-step.
// ---------------------------------------------------------------------------

typedef __attribute__((ext_vector_type(8))) short bf16x8;
typedef __attribute__((ext_vector_type(4))) float f32x4;
typedef __attribute__((ext_vector_type(2))) float v2f;
typedef __attribute__((ext_vector_type(4))) unsigned short us4;
typedef __attribute__((ext_vector_type(2))) unsigned short us2;

#define L2E 1.4426950408889634f

__device__ __forceinline__ float bf2f(unsigned short u) {
    return __uint_as_float((unsigned)u << 16);
}
__device__ __forceinline__ unsigned short f2bf(float f) {   // RNE
    unsigned u = __float_as_uint(f);
    u += 0x7FFFu + ((u >> 16) & 1u);
    return (unsigned short)(u >> 16);
}
__device__ __forceinline__ v2f unpack2(unsigned d) {        // [lo,hi] bf16 -> f32
    v2f r;
    r.x = __uint_as_float(d << 16);
    r.y = __uint_as_float(d & 0xffff0000u);
    return r;
}
__device__ __forceinline__ unsigned pack2(float a, float b) {
    return (unsigned)f2bf(a) | ((unsigned)f2bf(b) << 16);
}

// ---- cross-lane sum helpers -------------------------------------------------
template<int CTRL>
__device__ __forceinline__ float dpp_add_f(float x) {
    int xi = __float_as_int(x);
    int yi = __builtin_amdgcn_update_dpp(xi, xi, CTRL, 0xF, 0xF, false);
    return x + __int_as_float(yi);
}
template<int PAT>
__device__ __forceinline__ float swz_add_f(float x) {
    int yi = __builtin_amdgcn_ds_swizzle(__float_as_int(x), PAT);
    return x + __int_as_float(yi);
}
template<int GS>
__device__ __forceinline__ float group_sum(float p) {
    p = dpp_add_f<0x121>(p);   // row_ror:1
    p = dpp_add_f<0x122>(p);   // row_ror:2
    p = dpp_add_f<0x124>(p);   // row_ror:4
    p = dpp_add_f<0x128>(p);   // row_ror:8
    if constexpr (GS >= 32) p = swz_add_f<0x401F>(p);   // xor 16
    if constexpr (GS >= 64) p += __shfl_xor(p, 32, 64); // cross-half
    return p;
}

// ---------------------------------------------------------------------------
// init: deg=0, gsum=0, gcnt=0, gmaxu=enc(-FLT_MAX)
// ---------------------------------------------------------------------------
__global__ void init_k(int* __restrict__ deg, float* __restrict__ gsum,
                       float* __restrict__ gcnt, unsigned* __restrict__ gmaxu,
                       int N, int G)
{
    int i = blockIdx.x * blockDim.x + threadIdx.x;
    int stride = gridDim.x * blockDim.x;
    for (int k = i; k < N; k += stride) deg[k] = 0;
    for (int k = i; k < G * 64; k += stride) { gsum[k] = 0.f; gmaxu[k] = 0x00800000u; }
    for (int k = i; k < G; k += stride) gcnt[k] = 0.f;
}

// ---------------------------------------------------------------------------
// prep: x->bf16, 6 weights->bf16, dst histogram (deg zeroed by init_k).
// ---------------------------------------------------------------------------
__global__ void prep_k(const float* __restrict__ x, unsigned short* __restrict__ xb, int nx,
                       const float* p0, const float* p1, const float* p2,
                       const float* p3, const float* p4, const float* p5,
                       unsigned short* d0, unsigned short* d1, unsigned short* d2,
                       unsigned short* d3, unsigned short* d4, unsigned short* d5,
                       int s01, int s23, int s45,
                       const int* __restrict__ dste, int E, int N, int* __restrict__ deg)
{
    const int tid = blockIdx.x * blockDim.x + threadIdx.x;
    const int stride = gridDim.x * blockDim.x;

    for (int i = tid; i < nx / 4; i += stride) {
        int idx = i * 4;
        float4 v = *(const float4*)(x + idx);
        uint2 o = { pack2(v.x, v.y), pack2(v.z, v.w) };
        *(uint2*)(xb + idx) = o;
    }
    const int wtot4 = (2 * s01 + 2 * s23 + 2 * s45) / 4;
    const int t0 = 2 * s01, t1 = t0 + 2 * s23;
    for (int i = tid; i < wtot4; i += stride) {
        int e = i * 4;
        const float* s; unsigned short* d; int off;
        if (e < t0)      { int j = e;      s = (j < s01) ? p0 : p1; d = (j < s01) ? d0 : d1; off = j % s01; }
        else if (e < t1) { int j = e - t0; s = (j < s23) ? p2 : p3; d = (j < s23) ? d2 : d3; off = j % s23; }
        else             { int j = e - t1; s = (j < s45) ? p4 : p5; d = (j < s45) ? d4 : d5; off = j % s45; }
        float4 v = *(const float4*)(s + off);
        uint2 o = { pack2(v.x, v.y), pack2(v.z, v.w) };
        *(uint2*)(d + off) = o;
    }
    for (int e = tid; e < E + N; e += stride) {
        int i = (e < E) ? dste[e] : (e - E);
        atomicAdd(&deg[i], 1);
    }
}

// ---------------------------------------------------------------------------
// bf16 MFMA GEMM: C = A @ W^T, bf16 out.  One wave: 32 rows x (NT*16) cols.
// acc[2][NT] keeps AGPR use at 8*NT (32 for NT=4) -> ~4 waves/SIMD.
// grid = (row-blocks of 128, {l,r}, n-blocks of NT*16).
// ---------------------------------------------------------------------------
template<int NT, int KT>
__global__ __launch_bounds__(256) void gemm_mfma(
    const __hip_bfloat16* __restrict__ A,
    const __hip_bfloat16* __restrict__ Wl, const __hip_bfloat16* __restrict__ Wr,
    __hip_bfloat16* __restrict__ Cl, __hip_bfloat16* __restrict__ Cr,
    int M, int Nout)
{
    constexpr int K = KT * 32;
    const int wave = threadIdx.x >> 6, lane = threadIdx.x & 63;
    const int m0 = (blockIdx.x * 4 + wave) * 32;
    if (m0 >= M) return;
    const __hip_bfloat16* W = blockIdx.y ? Wr : Wl;
    __hip_bfloat16* C = blockIdx.y ? Cr : Cl;
    const int nbase = blockIdx.z * NT * 16;
    const int r16  = lane & 15;
    const int quad = lane >> 4;
    const int kq = quad * 8;

    f32x4 acc[2][NT];
    #pragma unroll
    for (int mt = 0; mt < 2; ++mt)
        #pragma unroll
        for (int n = 0; n < NT; ++n) acc[mt][n] = (f32x4){0.f, 0.f, 0.f, 0.f};

    const __hip_bfloat16* Arow[2];
    #pragma unroll
    for (int mt = 0; mt < 2; ++mt) {
        int r = m0 + mt * 16 + r16;
        r = (r < M) ? r : (M - 1);
        Arow[mt] = A + (size_t)r * K + kq;
    }
    const __hip_bfloat16* Wbase = W + (size_t)(nbase + r16) * K + kq;

    #pragma unroll
    for (int kt = 0; kt < KT; ++kt) {
        const int k0 = kt * 32;
        bf16x8 a[2];
        #pragma unroll
        for (int mt = 0; mt < 2; ++mt)
            a[mt] = *(const bf16x8*)(Arow[mt] + k0);
        #pragma unroll
        for (int n = 0; n < NT; ++n) {
            bf16x8 b = *(const bf16x8*)(Wbase + (size_t)n * 16 * K + k0);
            #pragma unroll
            for (int mt = 0; mt < 2; ++mt)
                acc[mt][n] = __builtin_amdgcn_mfma_f32_16x16x32_bf16(a[mt], b, acc[mt][n], 0, 0, 0);
        }
    }

    unsigned short* Cu = (unsigned short*)C;
    #pragma unroll
    for (int mt = 0; mt < 2; ++mt)
        #pragma unroll
        for (int n = 0; n < NT; ++n)
            #pragma unroll
            for (int r = 0; r < 4; ++r) {
                int row = m0 + mt * 16 + quad * 4 + r;
                if (row < M)
                    Cu[(size_t)row * Nout + nbase + n * 16 + r16] = f2bf(acc[mt][n][r]);
            }
}

// ---------------------------------------------------------------------------
// 3-phase parallel scan
// ---------------------------------------------------------------------------
__global__ __launch_bounds__(1024) void scanA_k(const int* __restrict__ deg,
                                                int* __restrict__ rowptr,
                                                int* __restrict__ bsum, int N)
{
    __shared__ int parts[16];
    const int t = threadIdx.x, lane = t & 63, wv = t >> 6;
    const int base = blockIdx.x * 8192;
    int v[8];
    int run = 0;
    #pragma unroll
    for (int i = 0; i < 8; ++i) {
        int idx = base + t * 8 + i;
        run += (idx < N) ? deg[idx] : 0;
        v[i] = run;
    }
    int x = run;
    #pragma unroll
    for (int off = 1; off < 64; off <<= 1) {
        int y = __shfl_up(x, off, 64);
        if (lane >= off) x += y;
    }
    int excl = x - run;
    if (lane == 63) parts[wv] = x;
    __syncthreads();
    if (wv == 0 && lane < 16) {
        int p = parts[lane];
        int xx = p;
        #pragma unroll
        for (int off = 1; off < 16; off <<= 1) {
            int y = __shfl_up(xx, off, 64);
            if (lane >= off) xx += y;
        }
        parts[lane] = xx - p;   // exclusive
    }
    __syncthreads();
    int pre = parts[wv] + excl;
    #pragma unroll
    for (int i = 0; i < 8; ++i) {
        int idx = base + t * 8 + i;
        if (idx < N) rowptr[idx + 1] = pre + v[i];
    }
    if (t == 1023) bsum[blockIdx.x] = parts[15] + x;   // block total
}

__global__ void scanB_k(int* __restrict__ bsum, int B)
{
    int lane = threadIdx.x;
    int v = (lane < B) ? bsum[lane] : 0;
    int x = v;
    #pragma unroll
    for (int off = 1; off < 64; off <<= 1) {
        int y = __shfl_up(x, off, 64);
        if (lane >= off) x += y;
    }
    if (lane < B) bsum[lane] = x - v;   // exclusive
}

__global__ __launch_bounds__(1024) void scanC_k(int* __restrict__ rowptr,
                                                const int* __restrict__ bsum, int N)
{
    const int b = blockIdx.x, t = threadIdx.x;
    if (b == 0) { if (t == 0) rowptr[0] = 0; return; }
    const int off = bsum[b];
    const int base = b * 8192;
    #pragma unroll
    for (int i = 0; i < 8; ++i) {
        int idx = base + t * 8 + i;
        if (idx < N) rowptr[idx + 1] += off;
    }
}

// scatter consumes deg (atomic countdown) -> no cursor buffer
__global__ void scatter_k(const int* __restrict__ src, const int* __restrict__ dst,
                          int E, int N, const int* __restrict__ rowptr,
                          int* __restrict__ deg, int* __restrict__ esrc)
{
    int e = blockIdx.x * blockDim.x + threadIdx.x;
    if (e >= E + N) return;
    int i = (e < E) ? dst[e] : (e - E);
    int j = (e < E) ? src[e] : (e - E);
    int old = atomicAdd(&deg[i], -1);
    esrc[rowptr[i] + old - 1] = j;
}

// ---------------------------------------------------------------------------
// Fused GATv2 layer (round-6 version: DPP reduce, max-form leaky, exp2).
// ---------------------------------------------------------------------------
template<int P>
__device__ __forceinline__ float edge_logit(const v2f* xv, const v2f* xrv, const v2f* attv)
{
    v2f d = {0.f, 0.f};
    #pragma unroll
    for (int p = 0; p < P; ++p) {
        v2f z = xv[p] + xrv[p];
        v2f l = __builtin_elementwise_max(z, z * 0.2f);   // leaky = max(z, 0.2z)
        d += l * attv[p];
    }
    return d.x + d.y;
}

template<int P>
__device__ __forceinline__ void load_edge(const unsigned short* __restrict__ xl,
                                          size_t base, v2f* xv)
{
    if constexpr (P == 2) {
        uint2 a = *(const uint2*)(xl + base);
        xv[0] = unpack2(a.x); xv[1] = unpack2(a.y);
    } else {
        unsigned a = *(const unsigned*)(xl + base);
        xv[0] = unpack2(a);
    }
}

template<int H, bool BF16OUT>
__global__ __launch_bounds__(256) void fused_agg_k(
    const unsigned short* __restrict__ xl, const unsigned short* __restrict__ xr,
    const int* __restrict__ rowptr, const int* __restrict__ esrc,
    const float* __restrict__ att, const float* __restrict__ bias,
    void* __restrict__ outv, int N, float oslope)
{
    const int wid  = (blockIdx.x * blockDim.x + threadIdx.x) >> 6;
    const int lane = threadIdx.x & 63;
    if (wid >= N) return;
    constexpr int HD = H * 64;
    constexpr int GS = 64 / H;
    const int f0 = lane * H;
    const int r0 = rowptr[wid];
    const int r1 = rowptr[wid + 1];

    if constexpr (H >= 2) {
        constexpr int P = H / 2;
        v2f xrv[P], attv[P], acc[P];
        load_edge<P>(xr, (size_t)wid * HD + f0, xrv);
        #pragma unroll
        for (int p = 0; p < P; ++p) {
            attv[p] = *(const v2f*)(att + f0 + 2 * p) * L2E;
            acc[p] = (v2f){0.f, 0.f};
        }

        float s = 0.f;
        int k = r0;
        for (; k + 4 <= r1; k += 4) {
            int j[4];
            #pragma unroll
            for (int i = 0; i < 4; ++i) j[i] = esrc[k + i];
            v2f xv[4][P];
            #pragma unroll
            for (int i = 0; i < 4; ++i)
                load_edge<P>(xl, (size_t)j[i] * HD + f0, xv[i]);
            float pl[4];
            #pragma unroll
            for (int i = 0; i < 4; ++i) pl[i] = edge_logit<P>(xv[i], xrv, attv);
            #pragma unroll
            for (int i = 0; i < 4; ++i) pl[i] = group_sum<GS>(pl[i]);
            float w[4];
            #pragma unroll
            for (int i = 0; i < 4; ++i) w[i] = __builtin_amdgcn_exp2f(pl[i]);
            s += (w[0] + w[1]) + (w[2] + w[3]);
            #pragma unroll
            for (int p = 0; p < P; ++p) {
                v2f t = xv[0][p] * w[0] + xv[1][p] * w[1];
                t += xv[2][p] * w[2] + xv[3][p] * w[3];
                acc[p] += t;
            }
        }
        for (; k < r1; ++k) {
            int j0 = esrc[k];
            v2f xv[P];
            load_edge<P>(xl, (size_t)j0 * HD + f0, xv);
            float pl = group_sum<GS>(edge_logit<P>(xv, xrv, attv));
            float w = __builtin_amdgcn_exp2f(pl);
            s += w;
            #pragma unroll
            for (int p = 0; p < P; ++p) acc[p] += xv[p] * w;
        }

        float rs = 1.f / (s + 1e-16f);
        unsigned short o[H];
        float of[H];
        #pragma unroll
        for (int p = 0; p < P; ++p) {
            v2f b2 = *(const v2f*)(bias + f0 + 2 * p);
            v2f v = acc[p] * rs + b2;
            v = __builtin_elementwise_max(v, v * oslope);
            if constexpr (BF16OUT) { o[2 * p] = f2bf(v.x); o[2 * p + 1] = f2bf(v.y); }
            else                   { of[2 * p] = v.x; of[2 * p + 1] = v.y; }
        }
        if constexpr (BF16OUT) {
            unsigned short* ou = (unsigned short*)outv;
            if constexpr (H == 4) *(us4*)(ou + (size_t)wid * HD + f0) = *(us4*)o;
            else                  *(us2*)(ou + (size_t)wid * HD + f0) = *(us2*)o;
        } else {
            float* off_ = (float*)outv;
            #pragma unroll
            for (int i = 0; i < H; ++i) off_[(size_t)wid * HD + f0 + i] = of[i];
        }
    } else {
        // H == 1: scalar feats, GS = 64
        float xrv  = bf2f(xr[(size_t)wid * 64 + lane]);
        float attv = att[lane] * L2E;
        float s = 0.f, acc = 0.f;
        int k = r0;
        for (; k + 4 <= r1; k += 4) {
            int j[4];
            #pragma unroll
            for (int i = 0; i < 4; ++i) j[i] = esrc[k + i];
            float xv[4], pl[4], w[4];
            #pragma unroll
            for (int i = 0; i < 4; ++i) xv[i] = bf2f(xl[(size_t)j[i] * 64 + lane]);
            #pragma unroll
            for (int i = 0; i < 4; ++i) {
                float z = xv[i] + xrv;
                pl[i] = fmaxf(z, 0.2f * z) * attv;
            }
            #pragma unroll
            for (int i = 0; i < 4; ++i) pl[i] = group_sum<64>(pl[i]);
            #pragma unroll
            for (int i = 0; i < 4; ++i) w[i] = __builtin_amdgcn_exp2f(pl[i]);
            s += (w[0] + w[1]) + (w[2] + w[3]);
            acc += (xv[0] * w[0] + xv[1] * w[1]) + (xv[2] * w[2] + xv[3] * w[3]);
        }
        for (; k < r1; ++k) {
            float x0 = bf2f(xl[(size_t)esrc[k] * 64 + lane]);
            float z = x0 + xrv;
            float pl = group_sum<64>(fmaxf(z, 0.2f * z) * attv);
            float w = __builtin_amdgcn_exp2f(pl);
            s += w;
            acc += x0 * w;
        }
        float rs = 1.f / (s + 1e-16f);
        float v = acc * rs + bias[lane];
        v = fmaxf(v, oslope * v);
        if constexpr (BF16OUT)
            ((unsigned short*)outv)[(size_t)wid * 64 + lane] = f2bf(v);
        else
            ((float*)outv)[(size_t)wid * 64 + lane] = v;
    }
}

// ---------------------------------------------------------------------------
// Pooling (batch_index sorted -> run aggregation, atomics at boundaries only)
// ---------------------------------------------------------------------------
__device__ __forceinline__ unsigned fenc(float f) {
    unsigned u = __float_as_uint(f);
    return (u & 0x80000000u) ? ~u : (u | 0x80000000u);
}
__device__ __forceinline__ float fdec(unsigned u) {
    return __uint_as_float((u & 0x80000000u) ? (u & 0x7fffffffu) : ~u);
}

__global__ __launch_bounds__(256) void pool_k(
    const float* __restrict__ h, const int* __restrict__ batch, int N,
    unsigned* __restrict__ gmaxu, float* __restrict__ gsum, float* __restrict__ gcnt)
{
    const int wid  = (blockIdx.x * blockDim.x + threadIdx.x) >> 6;
    const int lane = threadIdx.x & 63;
    const int n0 = wid * 16;
    if (n0 >= N) return;
    int gcur = batch[n0];
    float vmax = -3.4e38f, vsum = 0.f;
    int cnt = 0;
    #pragma unroll 4
    for (int i = 0; i < 16; ++i) {
        int n = n0 + i;
        if (n >= N) break;
        int g = batch[n];
        if (g != gcur) {
            atomicMax(&gmaxu[gcur * 64 + lane], fenc(vmax));
            atomicAdd(&gsum[gcur * 64 + lane], vsum);
            if (lane == 0) atomicAdd(&gcnt[gcur], (float)cnt);
            gcur = g; vmax = -3.4e38f; vsum = 0.f; cnt = 0;
        }
        float v = h[(size_t)n * 64 + lane];
        vmax = fmaxf(vmax, v);
        vsum += v;
        cnt++;
    }
    atomicMax(&gmaxu[gcur * 64 + lane], fenc(vmax));
    atomicAdd(&gsum[gcur * 64 + lane], vsum);
    if (lane == 0) atomicAdd(&gcnt[gcur], (float)cnt);
}

__global__ __launch_bounds__(128) void final_k(
    const unsigned* __restrict__ gmaxu, const float* __restrict__ gsum,
    const float* __restrict__ gcnt, const float* __restrict__ out_w,
    const float* __restrict__ out_b, float* __restrict__ out,
    float* __restrict__ hid_out)
{
    const int g = blockIdx.x;
    const int t = threadIdx.x;
    __shared__ float hid[128];
    float v;
    if (t < 64) {
        v = fdec(gmaxu[g * 64 + t]);
    } else {
        float c = fmaxf(gcnt[g], 1.f);
        v = gsum[g * 64 + (t - 64)] / c;
    }
    hid[t] = v;
    hid_out[(size_t)g * 128 + t] = v;
    __syncthreads();
    const int w = t >> 6, lane = t & 63;
    float p = hid[lane] * out_w[w * 128 + lane] + hid[lane + 64] * out_w[w * 128 + 64 + lane];
    #pragma unroll
    for (int off = 32; off >= 1; off >>= 1) p += __shfl_xor(p, off, 64);
    if (lane == 0) out[g * 2 + w] = p + out_b[w];
}

// ---------------------------------------------------------------------------
extern "C" void kernel_launch(void* const* d_in, const int* in_sizes, int n_in,
                              void* d_out, int out_size, void* d_ws, size_t ws_size,
                              hipStream_t stream)
{
    const float* x    = (const float*)d_in[0];
    const int*   ei   = (const int*)d_in[1];
    const int*   batch= (const int*)d_in[2];
    const float* w1l  = (const float*)d_in[3];
    const float* w1r  = (const float*)d_in[4];
    const float* att1 = (const float*)d_in[5];
    const float* b1   = (const float*)d_in[6];
    const float* w2l  = (const float*)d_in[7];
    const float* w2r  = (const float*)d_in[8];
    const float* att2 = (const float*)d_in[9];
    const float* b2   = (const float*)d_in[10];
    const float* w3l  = (const float*)d_in[11];
    const float* w3r  = (const float*)d_in[12];
    const float* att3 = (const float*)d_in[13];
    const float* b3   = (const float*)d_in[14];
    const float* outw = (const float*)d_in[15];
    const float* outb = (const float*)d_in[16];

    const int N   = in_sizes[2];
    const int E   = in_sizes[1] / 2;
    const int E2  = E + N;
    const int G   = 256;
    const int FIN = in_sizes[0] / N;    // 128
    const int* src = ei;
    const int* dst = ei + E;

    char* ws = (char*)d_ws;
    size_t off = 0;
    auto alloc = [&](size_t bytes) -> void* {
        void* p = ws + off;
        off = (off + bytes + 255) & ~(size_t)255;
        return p;
    };
    unsigned short* xlb   = (unsigned short*)alloc((size_t)N * 256 * 2);
    unsigned short* xrb   = (unsigned short*)alloc((size_t)N * 256 * 2);
    unsigned short* xb    = (unsigned short*)alloc((size_t)N * 128 * 2);
    unsigned short* hAb   = (unsigned short*)alloc((size_t)N * 256 * 2);
    unsigned short* hBb   = (unsigned short*)alloc((size_t)N * 128 * 2);
    float*          h3    = (float*)alloc((size_t)N * 64 * 4);
    int*            rowptr= (int*)alloc((size_t)(N + 1) * 4);
    int*            deg   = (int*)alloc((size_t)N * 4);
    int*            esrc  = (int*)alloc((size_t)E2 * 4);
    int*            bsum  = (int*)alloc(64 * 4);
    unsigned*       gmaxu = (unsigned*)alloc((size_t)G * 64 * 4);
    float*          gsum  = (float*)alloc((size_t)G * 64 * 4);
    float*          gcnt  = (float*)alloc((size_t)G * 4);
    unsigned short* w1lb  = (unsigned short*)alloc(256 * 128 * 2);
    unsigned short* w1rb  = (unsigned short*)alloc(256 * 128 * 2);
    unsigned short* w2lb  = (unsigned short*)alloc(128 * 256 * 2);
    unsigned short* w2rb  = (unsigned short*)alloc(128 * 256 * 2);
    unsigned short* w3lb  = (unsigned short*)alloc(64 * 128 * 2);
    unsigned short* w3rb  = (unsigned short*)alloc(64 * 128 * 2);

    init_k<<<(N + 255) / 256, 256, 0, stream>>>(deg, gsum, gcnt, gmaxu, N, G);

    const int s1 = 256 * 128, s2 = 128 * 256, s3 = 64 * 128;
    prep_k<<<1024, 256, 0, stream>>>(x, xb, N * FIN,
        w1l, w1r, w2l, w2r, w3l, w3r, w1lb, w1rb, w2lb, w2rb, w3lb, w3rb,
        s1, s2, s3, dst, E, N, deg);

    // CSR: 3-phase scan + scatter
    const int nblk = (N + 8191) / 8192;
    scanA_k<<<nblk, 1024, 0, stream>>>(deg, rowptr, bsum, N);
    scanB_k<<<1, 64, 0, stream>>>(bsum, nblk);
    scanC_k<<<nblk, 1024, 0, stream>>>(rowptr, bsum, N);
    scatter_k<<<(E2 + 255) / 256, 256, 0, stream>>>(src, dst, E, N, rowptr, deg, esrc);

    const int gx  = (N + 127) / 128;         // 32-row wave strips, 4 waves/block
    const int nwb = (N * 64 + 255) / 256;    // one wave per node

    // ---- layer 1: K=128 -> H=4, HD=256 (4 n-blocks of 64)
    gemm_mfma<4, 4><<<dim3(gx, 2, 4), 256, 0, stream>>>(
        (const __hip_bfloat16*)xb, (const __hip_bfloat16*)w1lb, (const __hip_bfloat16*)w1rb,
        (__hip_bfloat16*)xlb, (__hip_bfloat16*)xrb, N, 256);
    fused_agg_k<4, true><<<nwb, 256, 0, stream>>>(xlb, xrb, rowptr, esrc, att1, b1, hAb, N, 0.01f);

    // ---- layer 2: K=256 -> H=2, HD=128 (2 n-blocks of 64)
    gemm_mfma<4, 8><<<dim3(gx, 2, 2), 256, 0, stream>>>(
        (const __hip_bfloat16*)hAb, (const __hip_bfloat16*)w2lb, (const __hip_bfloat16*)w2rb,
        (__hip_bfloat16*)xlb, (__hip_bfloat16*)xrb, N, 128);
    fused_agg_k<2, true><<<nwb, 256, 0, stream>>>(xlb, xrb, rowptr, esrc, att2, b2, hBb, N, 0.01f);

    // ---- layer 3: K=128 -> H=1, HD=64 (1 n-block)
    gemm_mfma<4, 4><<<dim3(gx, 2, 1), 256, 0, stream>>>(
        (const __hip_bfloat16*)hBb, (const __hip_bfloat16*)w3lb, (const __hip_bfloat16*)w3rb,
        (__hip_bfloat16*)xlb, (__hip_bfloat16*)xrb, N, 64);
    fused_agg_k<1, false><<<nwb, 256, 0, stream>>>(xlb, xrb, rowptr, esrc, att3, b3, h3, N, 0.01f);

    // ---- pooling + head
    const int pb = (N / 16 + 3) / 4;
    pool_k<<<pb, 256, 0, stream>>>(h3, batch, N, gmaxu, gsum, gcnt);
    final_k<<<G, 128, 0, stream>>>(gmaxu, gsum, gcnt, outw, outb,
                                   (float*)d_out, (float*)d_out + G * 2);
}

// Round 9
// 367.184 us; speedup vs baseline: 3.3523x; 1.0472x over previous
//
#include <hip/hip_runtime.h>
#include <hip/hip_bf16.h>
#include <cfloat>
#include <cstdint>

// ---------------------------------------------------------------------------
// GATv2 x3 + global max/mean pool + linear head.
// Round 8: GEMM epilogue repack — per-wave C tile staged in LDS (padded rows,
// conflict-free) and stored as dwordx4 full-line writes instead of 32 scattered
// 2-byte stores (R7 counters: WRITE 50MB >> FETCH 22MB at 1.5 TB/s => RMW
// write bound).  fused_agg: wave index made explicitly scalar (readfirstlane).
// ---------------------------------------------------------------------------

typedef __attribute__((ext_vector_type(8))) short bf16x8;
typedef __attribute__((ext_vector_type(4))) float f32x4;
typedef __attribute__((ext_vector_type(2))) float v2f;
typedef __attribute__((ext_vector_type(4))) unsigned short us4;
typedef __attribute__((ext_vector_type(2))) unsigned short us2;

#define L2E 1.4426950408889634f

__device__ __forceinline__ float bf2f(unsigned short u) {
    return __uint_as_float((unsigned)u << 16);
}
__device__ __forceinline__ unsigned short f2bf(float f) {   // RNE
    unsigned u = __float_as_uint(f);
    u += 0x7FFFu + ((u >> 16) & 1u);
    return (unsigned short)(u >> 16);
}
__device__ __forceinline__ v2f unpack2(unsigned d) {        // [lo,hi] bf16 -> f32
    v2f r;
    r.x = __uint_as_float(d << 16);
    r.y = __uint_as_float(d & 0xffff0000u);
    return r;
}
__device__ __forceinline__ unsigned pack2(float a, float b) {
    return (unsigned)f2bf(a) | ((unsigned)f2bf(b) << 16);
}

// ---- cross-lane sum helpers -------------------------------------------------
template<int CTRL>
__device__ __forceinline__ float dpp_add_f(float x) {
    int xi = __float_as_int(x);
    int yi = __builtin_amdgcn_update_dpp(xi, xi, CTRL, 0xF, 0xF, false);
    return x + __int_as_float(yi);
}
template<int PAT>
__device__ __forceinline__ float swz_add_f(float x) {
    int yi = __builtin_amdgcn_ds_swizzle(__float_as_int(x), PAT);
    return x + __int_as_float(yi);
}
template<int GS>
__device__ __forceinline__ float group_sum(float p) {
    p = dpp_add_f<0x121>(p);   // row_ror:1
    p = dpp_add_f<0x122>(p);   // row_ror:2
    p = dpp_add_f<0x124>(p);   // row_ror:4
    p = dpp_add_f<0x128>(p);   // row_ror:8
    if constexpr (GS >= 32) p = swz_add_f<0x401F>(p);   // xor 16
    if constexpr (GS >= 64) p += __shfl_xor(p, 32, 64); // cross-half
    return p;
}

// ---------------------------------------------------------------------------
// init: deg=0, gsum=0, gcnt=0, gmaxu=enc(-FLT_MAX)
// ---------------------------------------------------------------------------
__global__ void init_k(int* __restrict__ deg, float* __restrict__ gsum,
                       float* __restrict__ gcnt, unsigned* __restrict__ gmaxu,
                       int N, int G)
{
    int i = blockIdx.x * blockDim.x + threadIdx.x;
    int stride = gridDim.x * blockDim.x;
    for (int k = i; k < N; k += stride) deg[k] = 0;
    for (int k = i; k < G * 64; k += stride) { gsum[k] = 0.f; gmaxu[k] = 0x00800000u; }
    for (int k = i; k < G; k += stride) gcnt[k] = 0.f;
}

// ---------------------------------------------------------------------------
// prep: x->bf16, 6 weights->bf16, dst histogram (deg zeroed by init_k).
// ---------------------------------------------------------------------------
__global__ void prep_k(const float* __restrict__ x, unsigned short* __restrict__ xb, int nx,
                       const float* p0, const float* p1, const float* p2,
                       const float* p3, const float* p4, const float* p5,
                       unsigned short* d0, unsigned short* d1, unsigned short* d2,
                       unsigned short* d3, unsigned short* d4, unsigned short* d5,
                       int s01, int s23, int s45,
                       const int* __restrict__ dste, int E, int N, int* __restrict__ deg)
{
    const int tid = blockIdx.x * blockDim.x + threadIdx.x;
    const int stride = gridDim.x * blockDim.x;

    for (int i = tid; i < nx / 4; i += stride) {
        int idx = i * 4;
        float4 v = *(const float4*)(x + idx);
        uint2 o = { pack2(v.x, v.y), pack2(v.z, v.w) };
        *(uint2*)(xb + idx) = o;
    }
    const int wtot4 = (2 * s01 + 2 * s23 + 2 * s45) / 4;
    const int t0 = 2 * s01, t1 = t0 + 2 * s23;
    for (int i = tid; i < wtot4; i += stride) {
        int e = i * 4;
        const float* s; unsigned short* d; int off;
        if (e < t0)      { int j = e;      s = (j < s01) ? p0 : p1; d = (j < s01) ? d0 : d1; off = j % s01; }
        else if (e < t1) { int j = e - t0; s = (j < s23) ? p2 : p3; d = (j < s23) ? d2 : d3; off = j % s23; }
        else             { int j = e - t1; s = (j < s45) ? p4 : p5; d = (j < s45) ? d4 : d5; off = j % s45; }
        float4 v = *(const float4*)(s + off);
        uint2 o = { pack2(v.x, v.y), pack2(v.z, v.w) };
        *(uint2*)(d + off) = o;
    }
    for (int e = tid; e < E + N; e += stride) {
        int i = (e < E) ? dste[e] : (e - E);
        atomicAdd(&deg[i], 1);
    }
}

// ---------------------------------------------------------------------------
// bf16 MFMA GEMM: C = A @ W^T, bf16 out.  One wave: 32 rows x (NT*16) cols,
// acc[2][NT] (32 AGPR for NT=4 -> ~4 waves/SIMD).  Epilogue: stage tile in
// LDS (row stride NT*16+8 elements -> conflict-free) then dwordx4 row stores.
// ---------------------------------------------------------------------------
template<int NT, int KT>
__global__ __launch_bounds__(256) void gemm_mfma(
    const __hip_bfloat16* __restrict__ A,
    const __hip_bfloat16* __restrict__ Wl, const __hip_bfloat16* __restrict__ Wr,
    __hip_bfloat16* __restrict__ Cl, __hip_bfloat16* __restrict__ Cr,
    int M, int Nout)
{
    constexpr int K = KT * 32;
    constexpr int LSTR = NT * 16 + 8;            // LDS row stride (elements)
    __shared__ unsigned short lds_c[4][32 * LSTR];
    const int wave = threadIdx.x >> 6, lane = threadIdx.x & 63;
    const int m0 = (blockIdx.x * 4 + wave) * 32;
    if (m0 >= M) return;
    const __hip_bfloat16* W = blockIdx.y ? Wr : Wl;
    __hip_bfloat16* C = blockIdx.y ? Cr : Cl;
    const int nbase = blockIdx.z * NT * 16;
    const int r16  = lane & 15;
    const int quad = lane >> 4;
    const int kq = quad * 8;

    f32x4 acc[2][NT];
    #pragma unroll
    for (int mt = 0; mt < 2; ++mt)
        #pragma unroll
        for (int n = 0; n < NT; ++n) acc[mt][n] = (f32x4){0.f, 0.f, 0.f, 0.f};

    const __hip_bfloat16* Arow[2];
    #pragma unroll
    for (int mt = 0; mt < 2; ++mt) {
        int r = m0 + mt * 16 + r16;
        r = (r < M) ? r : (M - 1);
        Arow[mt] = A + (size_t)r * K + kq;
    }
    const __hip_bfloat16* Wbase = W + (size_t)(nbase + r16) * K + kq;

    #pragma unroll
    for (int kt = 0; kt < KT; ++kt) {
        const int k0 = kt * 32;
        bf16x8 a[2];
        #pragma unroll
        for (int mt = 0; mt < 2; ++mt)
            a[mt] = *(const bf16x8*)(Arow[mt] + k0);
        #pragma unroll
        for (int n = 0; n < NT; ++n) {
            bf16x8 b = *(const bf16x8*)(Wbase + (size_t)n * 16 * K + k0);
            #pragma unroll
            for (int mt = 0; mt < 2; ++mt)
                acc[mt][n] = __builtin_amdgcn_mfma_f32_16x16x32_bf16(a[mt], b, acc[mt][n], 0, 0, 0);
        }
    }

    // ---- epilogue: LDS repack -> vectorized stores
    unsigned short* L = &lds_c[wave][0];
    #pragma unroll
    for (int mt = 0; mt < 2; ++mt)
        #pragma unroll
        for (int n = 0; n < NT; ++n)
            #pragma unroll
            for (int r = 0; r < 4; ++r)
                L[(mt * 16 + quad * 4 + r) * LSTR + n * 16 + r16] = f2bf(acc[mt][n][r]);
    // same-wave LDS dependency: compiler inserts lgkmcnt waits (no barrier)
    constexpr int LPR = NT * 2;      // lanes per row (8 bf16 = 16 B each)
    constexpr int RPI = 64 / LPR;    // rows per iteration
    const int il = lane % LPR;
    const int rr = lane / LPR;
    unsigned short* Cu = (unsigned short*)C;
    #pragma unroll
    for (int t = 0; t < 32 / RPI; ++t) {
        int row = t * RPI + rr;
        uint4 v = *(const uint4*)(L + row * LSTR + il * 8);
        int grow = m0 + row;
        if (grow < M)
            *(uint4*)(Cu + (size_t)grow * Nout + nbase + il * 8) = v;
    }
}

// ---------------------------------------------------------------------------
// 3-phase parallel scan
// ---------------------------------------------------------------------------
__global__ __launch_bounds__(1024) void scanA_k(const int* __restrict__ deg,
                                                int* __restrict__ rowptr,
                                                int* __restrict__ bsum, int N)
{
    __shared__ int parts[16];
    const int t = threadIdx.x, lane = t & 63, wv = t >> 6;
    const int base = blockIdx.x * 8192;
    int v[8];
    int run = 0;
    #pragma unroll
    for (int i = 0; i < 8; ++i) {
        int idx = base + t * 8 + i;
        run += (idx < N) ? deg[idx] : 0;
        v[i] = run;
    }
    int x = run;
    #pragma unroll
    for (int off = 1; off < 64; off <<= 1) {
        int y = __shfl_up(x, off, 64);
        if (lane >= off) x += y;
    }
    int excl = x - run;
    if (lane == 63) parts[wv] = x;
    __syncthreads();
    if (wv == 0 && lane < 16) {
        int p = parts[lane];
        int xx = p;
        #pragma unroll
        for (int off = 1; off < 16; off <<= 1) {
            int y = __shfl_up(xx, off, 64);
            if (lane >= off) xx += y;
        }
        parts[lane] = xx - p;   // exclusive
    }
    __syncthreads();
    int pre = parts[wv] + excl;
    #pragma unroll
    for (int i = 0; i < 8; ++i) {
        int idx = base + t * 8 + i;
        if (idx < N) rowptr[idx + 1] = pre + v[i];
    }
    if (t == 1023) bsum[blockIdx.x] = parts[15] + x;   // block total
}

__global__ void scanB_k(int* __restrict__ bsum, int B)
{
    int lane = threadIdx.x;
    int v = (lane < B) ? bsum[lane] : 0;
    int x = v;
    #pragma unroll
    for (int off = 1; off < 64; off <<= 1) {
        int y = __shfl_up(x, off, 64);
        if (lane >= off) x += y;
    }
    if (lane < B) bsum[lane] = x - v;   // exclusive
}

__global__ __launch_bounds__(1024) void scanC_k(int* __restrict__ rowptr,
                                                const int* __restrict__ bsum, int N)
{
    const int b = blockIdx.x, t = threadIdx.x;
    if (b == 0) { if (t == 0) rowptr[0] = 0; return; }
    const int off = bsum[b];
    const int base = b * 8192;
    #pragma unroll
    for (int i = 0; i < 8; ++i) {
        int idx = base + t * 8 + i;
        if (idx < N) rowptr[idx + 1] += off;
    }
}

// scatter consumes deg (atomic countdown) -> no cursor buffer
__global__ void scatter_k(const int* __restrict__ src, const int* __restrict__ dst,
                          int E, int N, const int* __restrict__ rowptr,
                          int* __restrict__ deg, int* __restrict__ esrc)
{
    int e = blockIdx.x * blockDim.x + threadIdx.x;
    if (e >= E + N) return;
    int i = (e < E) ? dst[e] : (e - E);
    int j = (e < E) ? src[e] : (e - E);
    int old = atomicAdd(&deg[i], -1);
    esrc[rowptr[i] + old - 1] = j;
}

// ---------------------------------------------------------------------------
// Fused GATv2 layer (DPP reduce, max-form leaky, exp2; scalar wave index).
// ---------------------------------------------------------------------------
template<int P>
__device__ __forceinline__ float edge_logit(const v2f* xv, const v2f* xrv, const v2f* attv)
{
    v2f d = {0.f, 0.f};
    #pragma unroll
    for (int p = 0; p < P; ++p) {
        v2f z = xv[p] + xrv[p];
        v2f l = __builtin_elementwise_max(z, z * 0.2f);   // leaky = max(z, 0.2z)
        d += l * attv[p];
    }
    return d.x + d.y;
}

template<int P>
__device__ __forceinline__ void load_edge(const unsigned short* __restrict__ xl,
                                          size_t base, v2f* xv)
{
    if constexpr (P == 2) {
        uint2 a = *(const uint2*)(xl + base);
        xv[0] = unpack2(a.x); xv[1] = unpack2(a.y);
    } else {
        unsigned a = *(const unsigned*)(xl + base);
        xv[0] = unpack2(a);
    }
}

template<int H, bool BF16OUT>
__global__ __launch_bounds__(256) void fused_agg_k(
    const unsigned short* __restrict__ xl, const unsigned short* __restrict__ xr,
    const int* __restrict__ rowptr, const int* __restrict__ esrc,
    const float* __restrict__ att, const float* __restrict__ bias,
    void* __restrict__ outv, int N, float oslope)
{
    const int wid  = __builtin_amdgcn_readfirstlane(
                         (blockIdx.x * blockDim.x + threadIdx.x) >> 6);
    const int lane = threadIdx.x & 63;
    if (wid >= N) return;
    constexpr int HD = H * 64;
    constexpr int GS = 64 / H;
    const int f0 = lane * H;
    const int r0 = rowptr[wid];
    const int r1 = rowptr[wid + 1];

    if constexpr (H >= 2) {
        constexpr int P = H / 2;
        v2f xrv[P], attv[P], acc[P];
        load_edge<P>(xr, (size_t)wid * HD + f0, xrv);
        #pragma unroll
        for (int p = 0; p < P; ++p) {
            attv[p] = *(const v2f*)(att + f0 + 2 * p) * L2E;
            acc[p] = (v2f){0.f, 0.f};
        }

        float s = 0.f;
        int k = r0;
        for (; k + 4 <= r1; k += 4) {
            int j[4];
            #pragma unroll
            for (int i = 0; i < 4; ++i) j[i] = esrc[k + i];
            v2f xv[4][P];
            #pragma unroll
            for (int i = 0; i < 4; ++i)
                load_edge<P>(xl, (size_t)j[i] * HD + f0, xv[i]);
            float pl[4];
            #pragma unroll
            for (int i = 0; i < 4; ++i) pl[i] = edge_logit<P>(xv[i], xrv, attv);
            #pragma unroll
            for (int i = 0; i < 4; ++i) pl[i] = group_sum<GS>(pl[i]);
            float w[4];
            #pragma unroll
            for (int i = 0; i < 4; ++i) w[i] = __builtin_amdgcn_exp2f(pl[i]);
            s += (w[0] + w[1]) + (w[2] + w[3]);
            #pragma unroll
            for (int p = 0; p < P; ++p) {
                v2f t = xv[0][p] * w[0] + xv[1][p] * w[1];
                t += xv[2][p] * w[2] + xv[3][p] * w[3];
                acc[p] += t;
            }
        }
        for (; k < r1; ++k) {
            int j0 = esrc[k];
            v2f xv[P];
            load_edge<P>(xl, (size_t)j0 * HD + f0, xv);
            float pl = group_sum<GS>(edge_logit<P>(xv, xrv, attv));
            float w = __builtin_amdgcn_exp2f(pl);
            s += w;
            #pragma unroll
            for (int p = 0; p < P; ++p) acc[p] += xv[p] * w;
        }

        float rs = 1.f / (s + 1e-16f);
        unsigned short o[H];
        float of[H];
        #pragma unroll
        for (int p = 0; p < P; ++p) {
            v2f b2 = *(const v2f*)(bias + f0 + 2 * p);
            v2f v = acc[p] * rs + b2;
            v = __builtin_elementwise_max(v, v * oslope);
            if constexpr (BF16OUT) { o[2 * p] = f2bf(v.x); o[2 * p + 1] = f2bf(v.y); }
            else                   { of[2 * p] = v.x; of[2 * p + 1] = v.y; }
        }
        if constexpr (BF16OUT) {
            unsigned short* ou = (unsigned short*)outv;
            if constexpr (H == 4) *(us4*)(ou + (size_t)wid * HD + f0) = *(us4*)o;
            else                  *(us2*)(ou + (size_t)wid * HD + f0) = *(us2*)o;
        } else {
            float* off_ = (float*)outv;
            #pragma unroll
            for (int i = 0; i < H; ++i) off_[(size_t)wid * HD + f0 + i] = of[i];
        }
    } else {
        // H == 1: scalar feats, GS = 64
        float xrv  = bf2f(xr[(size_t)wid * 64 + lane]);
        float attv = att[lane] * L2E;
        float s = 0.f, acc = 0.f;
        int k = r0;
        for (; k + 4 <= r1; k += 4) {
            int j[4];
            #pragma unroll
            for (int i = 0; i < 4; ++i) j[i] = esrc[k + i];
            float xv[4], pl[4], w[4];
            #pragma unroll
            for (int i = 0; i < 4; ++i) xv[i] = bf2f(xl[(size_t)j[i] * 64 + lane]);
            #pragma unroll
            for (int i = 0; i < 4; ++i) {
                float z = xv[i] + xrv;
                pl[i] = fmaxf(z, 0.2f * z) * attv;
            }
            #pragma unroll
            for (int i = 0; i < 4; ++i) pl[i] = group_sum<64>(pl[i]);
            #pragma unroll
            for (int i = 0; i < 4; ++i) w[i] = __builtin_amdgcn_exp2f(pl[i]);
            s += (w[0] + w[1]) + (w[2] + w[3]);
            acc += (xv[0] * w[0] + xv[1] * w[1]) + (xv[2] * w[2] + xv[3] * w[3]);
        }
        for (; k < r1; ++k) {
            float x0 = bf2f(xl[(size_t)esrc[k] * 64 + lane]);
            float z = x0 + xrv;
            float pl = group_sum<64>(fmaxf(z, 0.2f * z) * attv);
            float w = __builtin_amdgcn_exp2f(pl);
            s += w;
            acc += x0 * w;
        }
        float rs = 1.f / (s + 1e-16f);
        float v = acc * rs + bias[lane];
        v = fmaxf(v, oslope * v);
        if constexpr (BF16OUT)
            ((unsigned short*)outv)[(size_t)wid * 64 + lane] = f2bf(v);
        else
            ((float*)outv)[(size_t)wid * 64 + lane] = v;
    }
}

// ---------------------------------------------------------------------------
// Pooling (batch_index sorted -> run aggregation, atomics at boundaries only)
// ---------------------------------------------------------------------------
__device__ __forceinline__ unsigned fenc(float f) {
    unsigned u = __float_as_uint(f);
    return (u & 0x80000000u) ? ~u : (u | 0x80000000u);
}
__device__ __forceinline__ float fdec(unsigned u) {
    return __uint_as_float((u & 0x80000000u) ? (u & 0x7fffffffu) : ~u);
}

__global__ __launch_bounds__(256) void pool_k(
    const float* __restrict__ h, const int* __restrict__ batch, int N,
    unsigned* __restrict__ gmaxu, float* __restrict__ gsum, float* __restrict__ gcnt)
{
    const int wid  = (blockIdx.x * blockDim.x + threadIdx.x) >> 6;
    const int lane = threadIdx.x & 63;
    const int n0 = wid * 16;
    if (n0 >= N) return;
    int gcur = batch[n0];
    float vmax = -3.4e38f, vsum = 0.f;
    int cnt = 0;
    #pragma unroll 4
    for (int i = 0; i < 16; ++i) {
        int n = n0 + i;
        if (n >= N) break;
        int g = batch[n];
        if (g != gcur) {
            atomicMax(&gmaxu[gcur * 64 + lane], fenc(vmax));
            atomicAdd(&gsum[gcur * 64 + lane], vsum);
            if (lane == 0) atomicAdd(&gcnt[gcur], (float)cnt);
            gcur = g; vmax = -3.4e38f; vsum = 0.f; cnt = 0;
        }
        float v = h[(size_t)n * 64 + lane];
        vmax = fmaxf(vmax, v);
        vsum += v;
        cnt++;
    }
    atomicMax(&gmaxu[gcur * 64 + lane], fenc(vmax));
    atomicAdd(&gsum[gcur * 64 + lane], vsum);
    if (lane == 0) atomicAdd(&gcnt[gcur], (float)cnt);
}

__global__ __launch_bounds__(128) void final_k(
    const unsigned* __restrict__ gmaxu, const float* __restrict__ gsum,
    const float* __restrict__ gcnt, const float* __restrict__ out_w,
    const float* __restrict__ out_b, float* __restrict__ out,
    float* __restrict__ hid_out)
{
    const int g = blockIdx.x;
    const int t = threadIdx.x;
    __shared__ float hid[128];
    float v;
    if (t < 64) {
        v = fdec(gmaxu[g * 64 + t]);
    } else {
        float c = fmaxf(gcnt[g], 1.f);
        v = gsum[g * 64 + (t - 64)] / c;
    }
    hid[t] = v;
    hid_out[(size_t)g * 128 + t] = v;
    __syncthreads();
    const int w = t >> 6, lane = t & 63;
    float p = hid[lane] * out_w[w * 128 + lane] + hid[lane + 64] * out_w[w * 128 + 64 + lane];
    #pragma unroll
    for (int off = 32; off >= 1; off >>= 1) p += __shfl_xor(p, off, 64);
    if (lane == 0) out[g * 2 + w] = p + out_b[w];
}

// ---------------------------------------------------------------------------
extern "C" void kernel_launch(void* const* d_in, const int* in_sizes, int n_in,
                              void* d_out, int out_size, void* d_ws, size_t ws_size,
                              hipStream_t stream)
{
    const float* x    = (const float*)d_in[0];
    const int*   ei   = (const int*)d_in[1];
    const int*   batch= (const int*)d_in[2];
    const float* w1l  = (const float*)d_in[3];
    const float* w1r  = (const float*)d_in[4];
    const float* att1 = (const float*)d_in[5];
    const float* b1   = (const float*)d_in[6];
    const float* w2l  = (const float*)d_in[7];
    const float* w2r  = (const float*)d_in[8];
    const float* att2 = (const float*)d_in[9];
    const float* b2   = (const float*)d_in[10];
    const float* w3l  = (const float*)d_in[11];
    const float* w3r  = (const float*)d_in[12];
    const float* att3 = (const float*)d_in[13];
    const float* b3   = (const float*)d_in[14];
    const float* outw = (const float*)d_in[15];
    const float* outb = (const float*)d_in[16];

    const int N   = in_sizes[2];
    const int E   = in_sizes[1] / 2;
    const int E2  = E + N;
    const int G   = 256;
    const int FIN = in_sizes[0] / N;    // 128
    const int* src = ei;
    const int* dst = ei + E;

    char* ws = (char*)d_ws;
    size_t off = 0;
    auto alloc = [&](size_t bytes) -> void* {
        void* p = ws + off;
        off = (off + bytes + 255) & ~(size_t)255;
        return p;
    };
    unsigned short* xlb   = (unsigned short*)alloc((size_t)N * 256 * 2);
    unsigned short* xrb   = (unsigned short*)alloc((size_t)N * 256 * 2);
    unsigned short* xb    = (unsigned short*)alloc((size_t)N * 128 * 2);
    unsigned short* hAb   = (unsigned short*)alloc((size_t)N * 256 * 2);
    unsigned short* hBb   = (unsigned short*)alloc((size_t)N * 128 * 2);
    float*          h3    = (float*)alloc((size_t)N * 64 * 4);
    int*            rowptr= (int*)alloc((size_t)(N + 1) * 4);
    int*            deg   = (int*)alloc((size_t)N * 4);
    int*            esrc  = (int*)alloc((size_t)E2 * 4);
    int*            bsum  = (int*)alloc(64 * 4);
    unsigned*       gmaxu = (unsigned*)alloc((size_t)G * 64 * 4);
    float*          gsum  = (float*)alloc((size_t)G * 64 * 4);
    float*          gcnt  = (float*)alloc((size_t)G * 4);
    unsigned short* w1lb  = (unsigned short*)alloc(256 * 128 * 2);
    unsigned short* w1rb  = (unsigned short*)alloc(256 * 128 * 2);
    unsigned short* w2lb  = (unsigned short*)alloc(128 * 256 * 2);
    unsigned short* w2rb  = (unsigned short*)alloc(128 * 256 * 2);
    unsigned short* w3lb  = (unsigned short*)alloc(64 * 128 * 2);
    unsigned short* w3rb  = (unsigned short*)alloc(64 * 128 * 2);

    init_k<<<(N + 255) / 256, 256, 0, stream>>>(deg, gsum, gcnt, gmaxu, N, G);

    const int s1 = 256 * 128, s2 = 128 * 256, s3 = 64 * 128;
    prep_k<<<1024, 256, 0, stream>>>(x, xb, N * FIN,
        w1l, w1r, w2l, w2r, w3l, w3r, w1lb, w1rb, w2lb, w2rb, w3lb, w3rb,
        s1, s2, s3, dst, E, N, deg);

    // CSR: 3-phase scan + scatter
    const int nblk = (N + 8191) / 8192;
    scanA_k<<<nblk, 1024, 0, stream>>>(deg, rowptr, bsum, N);
    scanB_k<<<1, 64, 0, stream>>>(bsum, nblk);
    scanC_k<<<nblk, 1024, 0, stream>>>(rowptr, bsum, N);
    scatter_k<<<(E2 + 255) / 256, 256, 0, stream>>>(src, dst, E, N, rowptr, deg, esrc);

    const int gx  = (N + 127) / 128;         // 32-row wave strips, 4 waves/block
    const int nwb = (N * 64 + 255) / 256;    // one wave per node

    // ---- layer 1: K=128 -> H=4, HD=256 (4 n-blocks of 64)
    gemm_mfma<4, 4><<<dim3(gx, 2, 4), 256, 0, stream>>>(
        (const __hip_bfloat16*)xb, (const __hip_bfloat16*)w1lb, (const __hip_bfloat16*)w1rb,
        (__hip_bfloat16*)xlb, (__hip_bfloat16*)xrb, N, 256);
    fused_agg_k<4, true><<<nwb, 256, 0, stream>>>(xlb, xrb, rowptr, esrc, att1, b1, hAb, N, 0.01f);

    // ---- layer 2: K=256 -> H=2, HD=128 (2 n-blocks of 64)
    gemm_mfma<4, 8><<<dim3(gx, 2, 2), 256, 0, stream>>>(
        (const __hip_bfloat16*)hAb, (const __hip_bfloat16*)w2lb, (const __hip_bfloat16*)w2rb,
        (__hip_bfloat16*)xlb, (__hip_bfloat16*)xrb, N, 128);
    fused_agg_k<2, true><<<nwb, 256, 0, stream>>>(xlb, xrb, rowptr, esrc, att2, b2, hBb, N, 0.01f);

    // ---- layer 3: K=128 -> H=1, HD=64 (1 n-block)
    gemm_mfma<4, 4><<<dim3(gx, 2, 1), 256, 0, stream>>>(
        (const __hip_bfloat16*)hBb, (const __hip_bfloat16*)w3lb, (const __hip_bfloat16*)w3rb,
        (__hip_bfloat16*)xlb, (__hip_bfloat16*)xrb, N, 64);
    fused_agg_k<1, false><<<nwb, 256, 0, stream>>>(xlb, xrb, rowptr, esrc, att3, b3, h3, N, 0.01f);

    // ---- pooling + head
    const int pb = (N / 16 + 3) / 4;
    pool_k<<<pb, 256, 0, stream>>>(h3, batch, N, gmaxu, gsum, gcnt);
    final_k<<<G, 128, 0, stream>>>(gmaxu, gsum, gcnt, outw, outb,
                                   (float*)d_out, (float*)d_out + G * 2);
}

// Round 11
// 332.548 us; speedup vs baseline: 3.7014x; 1.1042x over previous
//
#include <hip/hip_runtime.h>
#include <hip/hip_bf16.h>
#include <cfloat>
#include <cstdint>

// ---------------------------------------------------------------------------
// GATv2 x3 + global max/mean pool + linear head.
// Round 10: round-9 LDS-staged GEMM with the compile fix (a[mt][ks] — the
// k-substep index was dropped in the MFMA operand).
// ---------------------------------------------------------------------------

typedef __attribute__((ext_vector_type(8))) short bf16x8;
typedef __attribute__((ext_vector_type(4))) float f32x4;
typedef __attribute__((ext_vector_type(2))) float v2f;
typedef __attribute__((ext_vector_type(4))) unsigned short us4;
typedef __attribute__((ext_vector_type(2))) unsigned short us2;

#define L2E 1.4426950408889634f

__device__ __forceinline__ float bf2f(unsigned short u) {
    return __uint_as_float((unsigned)u << 16);
}
__device__ __forceinline__ unsigned short f2bf(float f) {   // RNE
    unsigned u = __float_as_uint(f);
    u += 0x7FFFu + ((u >> 16) & 1u);
    return (unsigned short)(u >> 16);
}
__device__ __forceinline__ v2f unpack2(unsigned d) {        // [lo,hi] bf16 -> f32
    v2f r;
    r.x = __uint_as_float(d << 16);
    r.y = __uint_as_float(d & 0xffff0000u);
    return r;
}
__device__ __forceinline__ unsigned pack2(float a, float b) {
    return (unsigned)f2bf(a) | ((unsigned)f2bf(b) << 16);
}

// ---- cross-lane sum helpers -------------------------------------------------
template<int CTRL>
__device__ __forceinline__ float dpp_add_f(float x) {
    int xi = __float_as_int(x);
    int yi = __builtin_amdgcn_update_dpp(xi, xi, CTRL, 0xF, 0xF, false);
    return x + __int_as_float(yi);
}
template<int PAT>
__device__ __forceinline__ float swz_add_f(float x) {
    int yi = __builtin_amdgcn_ds_swizzle(__float_as_int(x), PAT);
    return x + __int_as_float(yi);
}
template<int GS>
__device__ __forceinline__ float group_sum(float p) {
    p = dpp_add_f<0x121>(p);   // row_ror:1
    p = dpp_add_f<0x122>(p);   // row_ror:2
    p = dpp_add_f<0x124>(p);   // row_ror:4
    p = dpp_add_f<0x128>(p);   // row_ror:8
    if constexpr (GS >= 32) p = swz_add_f<0x401F>(p);   // xor 16
    if constexpr (GS >= 64) p += __shfl_xor(p, 32, 64); // cross-half
    return p;
}

// ---------------------------------------------------------------------------
// init: deg=0, gsum=0, gcnt=0, gmaxu=enc(-FLT_MAX)
// ---------------------------------------------------------------------------
__global__ void init_k(int* __restrict__ deg, float* __restrict__ gsum,
                       float* __restrict__ gcnt, unsigned* __restrict__ gmaxu,
                       int N, int G)
{
    int i = blockIdx.x * blockDim.x + threadIdx.x;
    int stride = gridDim.x * blockDim.x;
    for (int k = i; k < N; k += stride) deg[k] = 0;
    for (int k = i; k < G * 64; k += stride) { gsum[k] = 0.f; gmaxu[k] = 0x00800000u; }
    for (int k = i; k < G; k += stride) gcnt[k] = 0.f;
}

// ---------------------------------------------------------------------------
// prep: x->bf16, 6 weights->bf16, dst histogram (deg zeroed by init_k).
// ---------------------------------------------------------------------------
__global__ void prep_k(const float* __restrict__ x, unsigned short* __restrict__ xb, int nx,
                       const float* p0, const float* p1, const float* p2,
                       const float* p3, const float* p4, const float* p5,
                       unsigned short* d0, unsigned short* d1, unsigned short* d2,
                       unsigned short* d3, unsigned short* d4, unsigned short* d5,
                       int s01, int s23, int s45,
                       const int* __restrict__ dste, int E, int N, int* __restrict__ deg)
{
    const int tid = blockIdx.x * blockDim.x + threadIdx.x;
    const int stride = gridDim.x * blockDim.x;

    for (int i = tid; i < nx / 4; i += stride) {
        int idx = i * 4;
        float4 v = *(const float4*)(x + idx);
        uint2 o = { pack2(v.x, v.y), pack2(v.z, v.w) };
        *(uint2*)(xb + idx) = o;
    }
    const int wtot4 = (2 * s01 + 2 * s23 + 2 * s45) / 4;
    const int t0 = 2 * s01, t1 = t0 + 2 * s23;
    for (int i = tid; i < wtot4; i += stride) {
        int e = i * 4;
        const float* s; unsigned short* d; int off;
        if (e < t0)      { int j = e;      s = (j < s01) ? p0 : p1; d = (j < s01) ? d0 : d1; off = j % s01; }
        else if (e < t1) { int j = e - t0; s = (j < s23) ? p2 : p3; d = (j < s23) ? d2 : d3; off = j % s23; }
        else             { int j = e - t1; s = (j < s45) ? p4 : p5; d = (j < s45) ? d4 : d5; off = j % s45; }
        float4 v = *(const float4*)(s + off);
        uint2 o = { pack2(v.x, v.y), pack2(v.z, v.w) };
        *(uint2*)(d + off) = o;
    }
    for (int e = tid; e < E + N; e += stride) {
        int i = (e < E) ? dste[e] : (e - E);
        atomicAdd(&deg[i], 1);
    }
}

// ---------------------------------------------------------------------------
// LDS-staged bf16 MFMA GEMM: C{l,r} = A @ W{l,r}^T, bf16 out.
// Block: 64 rows x SLAB cols, 4 waves as 2x2 (32 rows x SLAB/2 cols each).
// Per k-chunk (KC=128): A fragments -> registers (reused for both sides);
// W chunk [SLAB][KC] staged cooperatively into padded LDS; MFMA B from LDS.
// Epilogue: repack C tile through the (now free) Ws buffer, dwordx4 stores.
// grid = (ceil(M/64), Nout/SLAB).
// ---------------------------------------------------------------------------
template<int K, int SLAB>
__global__ __launch_bounds__(256) void gemm_lds(
    const unsigned short* __restrict__ A,
    const unsigned short* __restrict__ Wl, const unsigned short* __restrict__ Wr,
    unsigned short* __restrict__ Cl, unsigned short* __restrict__ Cr,
    int M, int Nout)
{
    constexpr int KC   = 128;
    constexpr int WPAD = KC + 8;           // +8 elems -> conflict-free rows
    constexpr int NT   = SLAB / 32;        // n-tiles per wave
    __shared__ unsigned short Ws[SLAB * WPAD];

    const int tid = threadIdx.x, wv = tid >> 6, lane = tid & 63;
    const int r16 = lane & 15, quad = lane >> 4;
    const int m0 = blockIdx.x * 64;
    const int mh = (wv >> 1) * 32;             // wave row half
    const int nh = (wv & 1) * (SLAB / 2);      // wave col half
    const int ncol0 = blockIdx.y * SLAB;

    f32x4 acc[2][2][NT] = {};                  // [side][mt][n]

    const unsigned short* Arow[2];
    #pragma unroll
    for (int mt = 0; mt < 2; ++mt) {
        int r = m0 + mh + mt * 16 + r16;
        r = (r < M) ? r : (M - 1);
        Arow[mt] = A + (size_t)r * K + quad * 8;
    }

    for (int kc = 0; kc < K / KC; ++kc) {
        const int k0 = kc * KC;
        // A fragments for this chunk -> registers (reused across both sides)
        bf16x8 a[2][4];
        #pragma unroll
        for (int mt = 0; mt < 2; ++mt)
            #pragma unroll
            for (int ks = 0; ks < 4; ++ks)
                a[mt][ks] = *(const bf16x8*)(Arow[mt] + k0 + ks * 32);

        #pragma unroll
        for (int side = 0; side < 2; ++side) {
            const unsigned short* W = side ? Wr : Wl;
            __syncthreads();                               // Ws free
            #pragma unroll
            for (int it = 0; it < SLAB * KC / 2048; ++it) {
                int idx8 = (it * 256 + tid) * 8;
                int row = idx8 >> 7, col = idx8 & 127;     // KC = 128
                bf16x8 v = *(const bf16x8*)(W + (size_t)(ncol0 + row) * K + k0 + col);
                *(bf16x8*)(&Ws[row * WPAD + col]) = v;
            }
            __syncthreads();
            #pragma unroll
            for (int ks = 0; ks < 4; ++ks) {
                #pragma unroll
                for (int n = 0; n < NT; ++n) {
                    bf16x8 b = *(const bf16x8*)(&Ws[(nh + n * 16 + r16) * WPAD + ks * 32 + quad * 8]);
                    #pragma unroll
                    for (int mt = 0; mt < 2; ++mt)
                        acc[side][mt][n] = __builtin_amdgcn_mfma_f32_16x16x32_bf16(
                            a[mt][ks], b, acc[side][mt][n], 0, 0, 0);
                }
            }
        }
    }

    // ---- epilogue: per side, repack through Ws then vectorized stores
    constexpr int RP  = SLAB / 2 + 8;
    constexpr int LPR = SLAB / 16;     // lanes per row (8 elems = 16 B each)
    constexpr int RPI = 64 / LPR;
    const int il = lane % LPR, rr = lane / LPR;
    #pragma unroll
    for (int side = 0; side < 2; ++side) {
        unsigned short* C = side ? Cr : Cl;
        __syncthreads();                                   // all reads of Ws done
        unsigned short* L = &Ws[wv * 32 * RP];
        #pragma unroll
        for (int mt = 0; mt < 2; ++mt)
            #pragma unroll
            for (int n = 0; n < NT; ++n)
                #pragma unroll
                for (int r = 0; r < 4; ++r)
                    L[(mt * 16 + quad * 4 + r) * RP + n * 16 + r16] = f2bf(acc[side][mt][n][r]);
        #pragma unroll
        for (int t = 0; t < 32 / RPI; ++t) {
            int row = t * RPI + rr;
            uint4 v = *(const uint4*)(&L[row * RP + il * 8]);
            int gr = m0 + mh + row;
            if (gr < M)
                *(uint4*)(C + (size_t)gr * Nout + ncol0 + nh + il * 8) = v;
        }
    }
}

// ---------------------------------------------------------------------------
// 3-phase parallel scan
// ---------------------------------------------------------------------------
__global__ __launch_bounds__(1024) void scanA_k(const int* __restrict__ deg,
                                                int* __restrict__ rowptr,
                                                int* __restrict__ bsum, int N)
{
    __shared__ int parts[16];
    const int t = threadIdx.x, lane = t & 63, wv = t >> 6;
    const int base = blockIdx.x * 8192;
    int v[8];
    int run = 0;
    #pragma unroll
    for (int i = 0; i < 8; ++i) {
        int idx = base + t * 8 + i;
        run += (idx < N) ? deg[idx] : 0;
        v[i] = run;
    }
    int x = run;
    #pragma unroll
    for (int off = 1; off < 64; off <<= 1) {
        int y = __shfl_up(x, off, 64);
        if (lane >= off) x += y;
    }
    int excl = x - run;
    if (lane == 63) parts[wv] = x;
    __syncthreads();
    if (wv == 0 && lane < 16) {
        int p = parts[lane];
        int xx = p;
        #pragma unroll
        for (int off = 1; off < 16; off <<= 1) {
            int y = __shfl_up(xx, off, 64);
            if (lane >= off) xx += y;
        }
        parts[lane] = xx - p;   // exclusive
    }
    __syncthreads();
    int pre = parts[wv] + excl;
    #pragma unroll
    for (int i = 0; i < 8; ++i) {
        int idx = base + t * 8 + i;
        if (idx < N) rowptr[idx + 1] = pre + v[i];
    }
    if (t == 1023) bsum[blockIdx.x] = parts[15] + x;   // block total
}

__global__ void scanB_k(int* __restrict__ bsum, int B)
{
    int lane = threadIdx.x;
    int v = (lane < B) ? bsum[lane] : 0;
    int x = v;
    #pragma unroll
    for (int off = 1; off < 64; off <<= 1) {
        int y = __shfl_up(x, off, 64);
        if (lane >= off) x += y;
    }
    if (lane < B) bsum[lane] = x - v;   // exclusive
}

__global__ __launch_bounds__(1024) void scanC_k(int* __restrict__ rowptr,
                                                const int* __restrict__ bsum, int N)
{
    const int b = blockIdx.x, t = threadIdx.x;
    if (b == 0) { if (t == 0) rowptr[0] = 0; return; }
    const int off = bsum[b];
    const int base = b * 8192;
    #pragma unroll
    for (int i = 0; i < 8; ++i) {
        int idx = base + t * 8 + i;
        if (idx < N) rowptr[idx + 1] += off;
    }
}

// scatter consumes deg (atomic countdown) -> no cursor buffer
__global__ void scatter_k(const int* __restrict__ src, const int* __restrict__ dst,
                          int E, int N, const int* __restrict__ rowptr,
                          int* __restrict__ deg, int* __restrict__ esrc)
{
    int e = blockIdx.x * blockDim.x + threadIdx.x;
    if (e >= E + N) return;
    int i = (e < E) ? dst[e] : (e - E);
    int j = (e < E) ? src[e] : (e - E);
    int old = atomicAdd(&deg[i], -1);
    esrc[rowptr[i] + old - 1] = j;
}

// ---------------------------------------------------------------------------
// Fused GATv2 layer (DPP reduce, max-form leaky, exp2; scalar wave index).
// ---------------------------------------------------------------------------
template<int P>
__device__ __forceinline__ float edge_logit(const v2f* xv, const v2f* xrv, const v2f* attv)
{
    v2f d = {0.f, 0.f};
    #pragma unroll
    for (int p = 0; p < P; ++p) {
        v2f z = xv[p] + xrv[p];
        v2f l = __builtin_elementwise_max(z, z * 0.2f);   // leaky = max(z, 0.2z)
        d += l * attv[p];
    }
    return d.x + d.y;
}

template<int P>
__device__ __forceinline__ void load_edge(const unsigned short* __restrict__ xl,
                                          size_t base, v2f* xv)
{
    if constexpr (P == 2) {
        uint2 a = *(const uint2*)(xl + base);
        xv[0] = unpack2(a.x); xv[1] = unpack2(a.y);
    } else {
        unsigned a = *(const unsigned*)(xl + base);
        xv[0] = unpack2(a);
    }
}

template<int H, bool BF16OUT>
__global__ __launch_bounds__(256) void fused_agg_k(
    const unsigned short* __restrict__ xl, const unsigned short* __restrict__ xr,
    const int* __restrict__ rowptr, const int* __restrict__ esrc,
    const float* __restrict__ att, const float* __restrict__ bias,
    void* __restrict__ outv, int N, float oslope)
{
    const int wid  = __builtin_amdgcn_readfirstlane(
                         (blockIdx.x * blockDim.x + threadIdx.x) >> 6);
    const int lane = threadIdx.x & 63;
    if (wid >= N) return;
    constexpr int HD = H * 64;
    constexpr int GS = 64 / H;
    const int f0 = lane * H;
    const int r0 = rowptr[wid];
    const int r1 = rowptr[wid + 1];

    if constexpr (H >= 2) {
        constexpr int P = H / 2;
        v2f xrv[P], attv[P], acc[P];
        load_edge<P>(xr, (size_t)wid * HD + f0, xrv);
        #pragma unroll
        for (int p = 0; p < P; ++p) {
            attv[p] = *(const v2f*)(att + f0 + 2 * p) * L2E;
            acc[p] = (v2f){0.f, 0.f};
        }

        float s = 0.f;
        int k = r0;
        for (; k + 4 <= r1; k += 4) {
            int j[4];
            #pragma unroll
            for (int i = 0; i < 4; ++i) j[i] = esrc[k + i];
            v2f xv[4][P];
            #pragma unroll
            for (int i = 0; i < 4; ++i)
                load_edge<P>(xl, (size_t)j[i] * HD + f0, xv[i]);
            float pl[4];
            #pragma unroll
            for (int i = 0; i < 4; ++i) pl[i] = edge_logit<P>(xv[i], xrv, attv);
            #pragma unroll
            for (int i = 0; i < 4; ++i) pl[i] = group_sum<GS>(pl[i]);
            float w[4];
            #pragma unroll
            for (int i = 0; i < 4; ++i) w[i] = __builtin_amdgcn_exp2f(pl[i]);
            s += (w[0] + w[1]) + (w[2] + w[3]);
            #pragma unroll
            for (int p = 0; p < P; ++p) {
                v2f t = xv[0][p] * w[0] + xv[1][p] * w[1];
                t += xv[2][p] * w[2] + xv[3][p] * w[3];
                acc[p] += t;
            }
        }
        for (; k < r1; ++k) {
            int j0 = esrc[k];
            v2f xv[P];
            load_edge<P>(xl, (size_t)j0 * HD + f0, xv);
            float pl = group_sum<GS>(edge_logit<P>(xv, xrv, attv));
            float w = __builtin_amdgcn_exp2f(pl);
            s += w;
            #pragma unroll
            for (int p = 0; p < P; ++p) acc[p] += xv[p] * w;
        }

        float rs = 1.f / (s + 1e-16f);
        unsigned short o[H];
        float of[H];
        #pragma unroll
        for (int p = 0; p < P; ++p) {
            v2f b2 = *(const v2f*)(bias + f0 + 2 * p);
            v2f v = acc[p] * rs + b2;
            v = __builtin_elementwise_max(v, v * oslope);
            if constexpr (BF16OUT) { o[2 * p] = f2bf(v.x); o[2 * p + 1] = f2bf(v.y); }
            else                   { of[2 * p] = v.x; of[2 * p + 1] = v.y; }
        }
        if constexpr (BF16OUT) {
            unsigned short* ou = (unsigned short*)outv;
            if constexpr (H == 4) *(us4*)(ou + (size_t)wid * HD + f0) = *(us4*)o;
            else                  *(us2*)(ou + (size_t)wid * HD + f0) = *(us2*)o;
        } else {
            float* off_ = (float*)outv;
            #pragma unroll
            for (int i = 0; i < H; ++i) off_[(size_t)wid * HD + f0 + i] = of[i];
        }
    } else {
        // H == 1: scalar feats, GS = 64
        float xrv  = bf2f(xr[(size_t)wid * 64 + lane]);
        float attv = att[lane] * L2E;
        float s = 0.f, acc = 0.f;
        int k = r0;
        for (; k + 4 <= r1; k += 4) {
            int j[4];
            #pragma unroll
            for (int i = 0; i < 4; ++i) j[i] = esrc[k + i];
            float xv[4], pl[4], w[4];
            #pragma unroll
            for (int i = 0; i < 4; ++i) xv[i] = bf2f(xl[(size_t)j[i] * 64 + lane]);
            #pragma unroll
            for (int i = 0; i < 4; ++i) {
                float z = xv[i] + xrv;
                pl[i] = fmaxf(z, 0.2f * z) * attv;
            }
            #pragma unroll
            for (int i = 0; i < 4; ++i) pl[i] = group_sum<64>(pl[i]);
            #pragma unroll
            for (int i = 0; i < 4; ++i) w[i] = __builtin_amdgcn_exp2f(pl[i]);
            s += (w[0] + w[1]) + (w[2] + w[3]);
            acc += (xv[0] * w[0] + xv[1] * w[1]) + (xv[2] * w[2] + xv[3] * w[3]);
        }
        for (; k < r1; ++k) {
            float x0 = bf2f(xl[(size_t)esrc[k] * 64 + lane]);
            float z = x0 + xrv;
            float pl = group_sum<64>(fmaxf(z, 0.2f * z) * attv);
            float w = __builtin_amdgcn_exp2f(pl);
            s += w;
            acc += x0 * w;
        }
        float rs = 1.f / (s + 1e-16f);
        float v = acc * rs + bias[lane];
        v = fmaxf(v, oslope * v);
        if constexpr (BF16OUT)
            ((unsigned short*)outv)[(size_t)wid * 64 + lane] = f2bf(v);
        else
            ((float*)outv)[(size_t)wid * 64 + lane] = v;
    }
}

// ---------------------------------------------------------------------------
// Pooling (batch_index sorted -> run aggregation, atomics at boundaries only)
// ---------------------------------------------------------------------------
__device__ __forceinline__ unsigned fenc(float f) {
    unsigned u = __float_as_uint(f);
    return (u & 0x80000000u) ? ~u : (u | 0x80000000u);
}
__device__ __forceinline__ float fdec(unsigned u) {
    return __uint_as_float((u & 0x80000000u) ? (u & 0x7fffffffu) : ~u);
}

__global__ __launch_bounds__(256) void pool_k(
    const float* __restrict__ h, const int* __restrict__ batch, int N,
    unsigned* __restrict__ gmaxu, float* __restrict__ gsum, float* __restrict__ gcnt)
{
    const int wid  = (blockIdx.x * blockDim.x + threadIdx.x) >> 6;
    const int lane = threadIdx.x & 63;
    const int n0 = wid * 16;
    if (n0 >= N) return;
    int gcur = batch[n0];
    float vmax = -3.4e38f, vsum = 0.f;
    int cnt = 0;
    #pragma unroll 4
    for (int i = 0; i < 16; ++i) {
        int n = n0 + i;
        if (n >= N) break;
        int g = batch[n];
        if (g != gcur) {
            atomicMax(&gmaxu[gcur * 64 + lane], fenc(vmax));
            atomicAdd(&gsum[gcur * 64 + lane], vsum);
            if (lane == 0) atomicAdd(&gcnt[gcur], (float)cnt);
            gcur = g; vmax = -3.4e38f; vsum = 0.f; cnt = 0;
        }
        float v = h[(size_t)n * 64 + lane];
        vmax = fmaxf(vmax, v);
        vsum += v;
        cnt++;
    }
    atomicMax(&gmaxu[gcur * 64 + lane], fenc(vmax));
    atomicAdd(&gsum[gcur * 64 + lane], vsum);
    if (lane == 0) atomicAdd(&gcnt[gcur], (float)cnt);
}

__global__ __launch_bounds__(128) void final_k(
    const unsigned* __restrict__ gmaxu, const float* __restrict__ gsum,
    const float* __restrict__ gcnt, const float* __restrict__ out_w,
    const float* __restrict__ out_b, float* __restrict__ out,
    float* __restrict__ hid_out)
{
    const int g = blockIdx.x;
    const int t = threadIdx.x;
    __shared__ float hid[128];
    float v;
    if (t < 64) {
        v = fdec(gmaxu[g * 64 + t]);
    } else {
        float c = fmaxf(gcnt[g], 1.f);
        v = gsum[g * 64 + (t - 64)] / c;
    }
    hid[t] = v;
    hid_out[(size_t)g * 128 + t] = v;
    __syncthreads();
    const int w = t >> 6, lane = t & 63;
    float p = hid[lane] * out_w[w * 128 + lane] + hid[lane + 64] * out_w[w * 128 + 64 + lane];
    #pragma unroll
    for (int off = 32; off >= 1; off >>= 1) p += __shfl_xor(p, off, 64);
    if (lane == 0) out[g * 2 + w] = p + out_b[w];
}

// ---------------------------------------------------------------------------
extern "C" void kernel_launch(void* const* d_in, const int* in_sizes, int n_in,
                              void* d_out, int out_size, void* d_ws, size_t ws_size,
                              hipStream_t stream)
{
    const float* x    = (const float*)d_in[0];
    const int*   ei   = (const int*)d_in[1];
    const int*   batch= (const int*)d_in[2];
    const float* w1l  = (const float*)d_in[3];
    const float* w1r  = (const float*)d_in[4];
    const float* att1 = (const float*)d_in[5];
    const float* b1   = (const float*)d_in[6];
    const float* w2l  = (const float*)d_in[7];
    const float* w2r  = (const float*)d_in[8];
    const float* att2 = (const float*)d_in[9];
    const float* b2   = (const float*)d_in[10];
    const float* w3l  = (const float*)d_in[11];
    const float* w3r  = (const float*)d_in[12];
    const float* att3 = (const float*)d_in[13];
    const float* b3   = (const float*)d_in[14];
    const float* outw = (const float*)d_in[15];
    const float* outb = (const float*)d_in[16];

    const int N   = in_sizes[2];
    const int E   = in_sizes[1] / 2;
    const int E2  = E + N;
    const int G   = 256;
    const int FIN = in_sizes[0] / N;    // 128
    const int* src = ei;
    const int* dst = ei + E;

    char* ws = (char*)d_ws;
    size_t off = 0;
    auto alloc = [&](size_t bytes) -> void* {
        void* p = ws + off;
        off = (off + bytes + 255) & ~(size_t)255;
        return p;
    };
    unsigned short* xlb   = (unsigned short*)alloc((size_t)N * 256 * 2);
    unsigned short* xrb   = (unsigned short*)alloc((size_t)N * 256 * 2);
    unsigned short* xb    = (unsigned short*)alloc((size_t)N * 128 * 2);
    unsigned short* hAb   = (unsigned short*)alloc((size_t)N * 256 * 2);
    unsigned short* hBb   = (unsigned short*)alloc((size_t)N * 128 * 2);
    float*          h3    = (float*)alloc((size_t)N * 64 * 4);
    int*            rowptr= (int*)alloc((size_t)(N + 1) * 4);
    int*            deg   = (int*)alloc((size_t)N * 4);
    int*            esrc  = (int*)alloc((size_t)E2 * 4);
    int*            bsum  = (int*)alloc(64 * 4);
    unsigned*       gmaxu = (unsigned*)alloc((size_t)G * 64 * 4);
    float*          gsum  = (float*)alloc((size_t)G * 64 * 4);
    float*          gcnt  = (float*)alloc((size_t)G * 4);
    unsigned short* w1lb  = (unsigned short*)alloc(256 * 128 * 2);
    unsigned short* w1rb  = (unsigned short*)alloc(256 * 128 * 2);
    unsigned short* w2lb  = (unsigned short*)alloc(128 * 256 * 2);
    unsigned short* w2rb  = (unsigned short*)alloc(128 * 256 * 2);
    unsigned short* w3lb  = (unsigned short*)alloc(64 * 128 * 2);
    unsigned short* w3rb  = (unsigned short*)alloc(64 * 128 * 2);

    init_k<<<(N + 255) / 256, 256, 0, stream>>>(deg, gsum, gcnt, gmaxu, N, G);

    const int s1 = 256 * 128, s2 = 128 * 256, s3 = 64 * 128;
    prep_k<<<1024, 256, 0, stream>>>(x, xb, N * FIN,
        w1l, w1r, w2l, w2r, w3l, w3r, w1lb, w1rb, w2lb, w2rb, w3lb, w3rb,
        s1, s2, s3, dst, E, N, deg);

    // CSR: 3-phase scan + scatter
    const int nblk = (N + 8191) / 8192;
    scanA_k<<<nblk, 1024, 0, stream>>>(deg, rowptr, bsum, N);
    scanB_k<<<1, 64, 0, stream>>>(bsum, nblk);
    scanC_k<<<nblk, 1024, 0, stream>>>(rowptr, bsum, N);
    scatter_k<<<(E2 + 255) / 256, 256, 0, stream>>>(src, dst, E, N, rowptr, deg, esrc);

    const int gx  = (N + 63) / 64;           // 64-row blocks
    const int nwb = (N * 64 + 255) / 256;    // one wave per node

    // ---- layer 1: K=128 -> H=4, HD=256 (SLAB=128, 2 col-blocks)
    gemm_lds<128, 128><<<dim3(gx, 2), 256, 0, stream>>>(
        xb, w1lb, w1rb, xlb, xrb, N, 256);
    fused_agg_k<4, true><<<nwb, 256, 0, stream>>>(xlb, xrb, rowptr, esrc, att1, b1, hAb, N, 0.01f);

    // ---- layer 2: K=256 -> H=2, HD=128 (SLAB=128, 1 col-block)
    gemm_lds<256, 128><<<dim3(gx, 1), 256, 0, stream>>>(
        hAb, w2lb, w2rb, xlb, xrb, N, 128);
    fused_agg_k<2, true><<<nwb, 256, 0, stream>>>(xlb, xrb, rowptr, esrc, att2, b2, hBb, N, 0.01f);

    // ---- layer 3: K=128 -> H=1, HD=64 (SLAB=64)
    gemm_lds<128, 64><<<dim3(gx, 1), 256, 0, stream>>>(
        hBb, w3lb, w3rb, xlb, xrb, N, 64);
    fused_agg_k<1, false><<<nwb, 256, 0, stream>>>(xlb, xrb, rowptr, esrc, att3, b3, h3, N, 0.01f);

    // ---- pooling + head
    const int pb = (N / 16 + 3) / 4;
    pool_k<<<pb, 256, 0, stream>>>(h3, batch, N, gmaxu, gsum, gcnt);
    final_k<<<G, 128, 0, stream>>>(gmaxu, gsum, gcnt, outw, outb,
                                   (float*)d_out, (float*)d_out + G * 2);
}